// Round 1
// baseline (7224.371 us; speedup 1.0000x reference)
//
#include <hip/hip_runtime.h>
#include <hip/hip_bf16.h>
#include <math.h>

#define H_DIM   128
#define NF_DIM  128
#define G_DIM   50
#define L_LAYERS 6
#define TBL     2048
#define DMAX    12.8f
#define CUTOFF_C 10.0f
// -0.5 / (CUTOFF/(G-1))^2 = -0.5 * (49/10)^2
#define COEFF_C (-0.5f * 49.0f * 49.0f / 100.0f)

__device__ __forceinline__ float sspf(float x) {
    // shifted softplus: log(1+exp(x)) - log(2), numerically stable
    return fmaxf(x, 0.0f) + log1pf(expf(-fabsf(x))) - 0.69314718055994530942f;
}

// ---------------------------------------------------------------- edge geometry
__global__ __launch_bounds__(256) void edge_geom(
        const float* __restrict__ pos, const int* __restrict__ er,
        const int* __restrict__ ec, float* __restrict__ dbuf,
        float* __restrict__ cbuf, int E) {
    int e = blockIdx.x * blockDim.x + threadIdx.x;
    if (e >= E) return;
    int r = er[e], c = ec[e];
    float dx = pos[r * 3 + 0] - pos[c * 3 + 0];
    float dy = pos[r * 3 + 1] - pos[c * 3 + 1];
    float dz = pos[r * 3 + 2] - pos[c * 3 + 2];
    float d = sqrtf(dx * dx + dy * dy + dz * dz);
    dbuf[e] = d;
    cbuf[e] = 0.5f * (cosf(d * (3.14159265358979323846f / CUTOFF_C)) + 1.0f);
}

// ---------------------------------------------------------------- filter tables
// tab[l][t][f] = (ssp(g(d_t)@w1 + b1) @ w2 + b2)[f],  d_t = t * DMAX/(TBL-1)
__global__ __launch_bounds__(128) void build_tables(
        const float* __restrict__ w1, const float* __restrict__ b1,
        const float* __restrict__ w2, const float* __restrict__ b2,
        float* __restrict__ tab) {
    int l = blockIdx.x / TBL;
    int t = blockIdx.x % TBL;
    int f = threadIdx.x;  // 128
    float dt = t * (DMAX / (TBL - 1));
    __shared__ float gs[G_DIM];
    __shared__ float sy[NF_DIM];
    if (f < G_DIM) {
        float o = f * (CUTOFF_C / (G_DIM - 1));
        float dd = dt - o;
        gs[f] = expf(COEFF_C * dd * dd);
    }
    __syncthreads();
    const float* W1 = w1 + (size_t)l * G_DIM * NF_DIM;
    float y = b1[l * NF_DIM + f];
#pragma unroll 10
    for (int g = 0; g < G_DIM; ++g) y += gs[g] * W1[g * NF_DIM + f];
    sy[f] = sspf(y);
    __syncthreads();
    const float* W2 = w2 + (size_t)l * NF_DIM * NF_DIM;
    float y2 = b2[l * NF_DIM + f];
#pragma unroll 16
    for (int k = 0; k < NF_DIM; ++k) y2 += sy[k] * W2[k * NF_DIM + f];
    tab[((size_t)l * TBL + t) * NF_DIM + f] = y2;
}

// ---------------------------------------------------------------- embedding
__global__ __launch_bounds__(256) void embed_kernel(
        const int* __restrict__ z, const float* __restrict__ emb,
        float* __restrict__ h, int N) {
    int idx = blockIdx.x * blockDim.x + threadIdx.x;
    if (idx >= N * H_DIM) return;
    int n = idx >> 7, f = idx & 127;
    h[idx] = emb[z[n] * H_DIM + f];
}

// ---------------------------------------------------------------- edge message
// agg[col] += xf[row] * lerp(tab, d) * C     (32 threads/edge, float4/thread)
__global__ __launch_bounds__(256) void edge_msg(
        const int* __restrict__ er, const int* __restrict__ ec,
        const float* __restrict__ dbuf, const float* __restrict__ cbuf,
        const float* __restrict__ xf, const float* __restrict__ tab_l,
        float* __restrict__ agg, int E) {
    int tid = threadIdx.x;
    int e = blockIdx.x * 8 + (tid >> 5);
    if (e >= E) return;
    int f4 = (tid & 31) * 4;
    int r = er[e], c = ec[e];
    float d = dbuf[e], C = cbuf[e];
    float t = fminf(d, DMAX) * ((TBL - 1) / DMAX);
    int i0 = (int)t;
    if (i0 > TBL - 2) i0 = TBL - 2;
    float fr = t - (float)i0;
    const float4 w0 = *(const float4*)(tab_l + (size_t)i0 * NF_DIM + f4);
    const float4 w1v = *(const float4*)(tab_l + (size_t)(i0 + 1) * NF_DIM + f4);
    const float4 xv = *(const float4*)(xf + (size_t)r * NF_DIM + f4);
    float* ap = agg + (size_t)c * NF_DIM + f4;
    unsafeAtomicAdd(ap + 0, xv.x * (w0.x + fr * (w1v.x - w0.x)) * C);
    unsafeAtomicAdd(ap + 1, xv.y * (w0.y + fr * (w1v.y - w0.y)) * C);
    unsafeAtomicAdd(ap + 2, xv.z * (w0.z + fr * (w1v.z - w0.z)) * C);
    unsafeAtomicAdd(ap + 3, xv.w * (w0.w + fr * (w1v.w - w0.w)) * C);
}

// ---------------------------------------------------------------- node GEMM
// Out(M x 128) = op(A)(M x 128) @ B(128 x 128) [+bias] [ssp] [+=]
// mode bits: 1 = ssp applied to A elements, 2 = add bias, 4 = ssp on output,
//            8 = accumulate into Out (residual)
#define MODE_SSP_A  1
#define MODE_BIAS   2
#define MODE_SSP_OUT 4
#define MODE_ACCUM  8

__global__ __launch_bounds__(256, 3) void gemm128(
        const float* __restrict__ A, const float* __restrict__ B,
        const float* __restrict__ bias, float* __restrict__ Out,
        int M, int mode) {
    __shared__ float As[64 * 132];   // 64 rows x K=128, stride 132 (33.8 KB)
    __shared__ float Bs[32 * 132];   // 32 K-rows x 128 cols, stride 132 (16.9 KB)
    int tid = threadIdx.x;
    int m0 = blockIdx.x * 64;

    // stage A (full K): 64x128 floats, float4 per thread iter, ssp optional
    for (int i = tid; i < 64 * 32; i += 256) {
        int r = i >> 5, c4 = (i & 31) * 4;
        float4 v = make_float4(0.f, 0.f, 0.f, 0.f);
        if (m0 + r < M) v = *(const float4*)(A + (size_t)(m0 + r) * 128 + c4);
        if (mode & MODE_SSP_A) { v.x = sspf(v.x); v.y = sspf(v.y); v.z = sspf(v.z); v.w = sspf(v.w); }
        *(float4*)(As + r * 132 + c4) = v;
    }

    int tr = tid >> 4, tc = tid & 15;       // 16x16 threads; 4 rows x 8 cols each
    float acc[4][8];
#pragma unroll
    for (int i = 0; i < 4; ++i)
#pragma unroll
        for (int j = 0; j < 8; ++j) acc[i][j] = 0.f;

    for (int kc = 0; kc < 4; ++kc) {        // K in 4 chunks of 32
        // stage B chunk: 32x128 floats
        for (int i = tid; i < 32 * 32; i += 256) {
            int r = i >> 5, c4 = (i & 31) * 4;
            *(float4*)(Bs + r * 132 + c4) =
                *(const float4*)(B + (size_t)(kc * 32 + r) * 128 + c4);
        }
        __syncthreads();
        for (int k = 0; k < 32; k += 4) {
            float a_[4][4];
#pragma unroll
            for (int i = 0; i < 4; ++i) {
                float4 t4 = *(const float4*)(As + (tr * 4 + i) * 132 + kc * 32 + k);
                a_[i][0] = t4.x; a_[i][1] = t4.y; a_[i][2] = t4.z; a_[i][3] = t4.w;
            }
            float b_[4][8];
#pragma unroll
            for (int kk = 0; kk < 4; ++kk) {
                float4 t0 = *(const float4*)(Bs + (k + kk) * 132 + tc * 8);
                float4 t1 = *(const float4*)(Bs + (k + kk) * 132 + tc * 8 + 4);
                b_[kk][0] = t0.x; b_[kk][1] = t0.y; b_[kk][2] = t0.z; b_[kk][3] = t0.w;
                b_[kk][4] = t1.x; b_[kk][5] = t1.y; b_[kk][6] = t1.z; b_[kk][7] = t1.w;
            }
#pragma unroll
            for (int kk = 0; kk < 4; ++kk)
#pragma unroll
                for (int i = 0; i < 4; ++i)
#pragma unroll
                    for (int j = 0; j < 8; ++j)
                        acc[i][j] += a_[i][kk] * b_[kk][j];
        }
        __syncthreads();
    }

    // epilogue
    float bv[8];
#pragma unroll
    for (int j = 0; j < 8; ++j) bv[j] = (mode & MODE_BIAS) ? bias[tc * 8 + j] : 0.f;
#pragma unroll
    for (int i = 0; i < 4; ++i) {
        int r = m0 + tr * 4 + i;
        if (r >= M) continue;
        float* op = Out + (size_t)r * 128 + tc * 8;
        float vals[8];
#pragma unroll
        for (int j = 0; j < 8; ++j) {
            float v = acc[i][j] + bv[j];
            if (mode & MODE_SSP_OUT) v = sspf(v);
            vals[j] = v;
        }
        if (mode & MODE_ACCUM) {
            float4 o0 = *(float4*)(op);
            float4 o1 = *(float4*)(op + 4);
            o0.x += vals[0]; o0.y += vals[1]; o0.z += vals[2]; o0.w += vals[3];
            o1.x += vals[4]; o1.y += vals[5]; o1.z += vals[6]; o1.w += vals[7];
            *(float4*)(op) = o0;
            *(float4*)(op + 4) = o1;
        } else {
            *(float4*)(op) = make_float4(vals[0], vals[1], vals[2], vals[3]);
            *(float4*)(op + 4) = make_float4(vals[4], vals[5], vals[6], vals[7]);
        }
    }
}

// ---------------------------------------------------------------- atom -> mol sum
// mols[mol][f] += sum of s rows; cnt[mol] += atom count. atom->mol is monotone
// (both index arrays sorted), so run-length accumulate, few atomics.
__global__ __launch_bounds__(128) void mol_reduce(
        const float* __restrict__ s, const int* __restrict__ a2c,
        const int* __restrict__ c2m, float* __restrict__ mols,
        int* __restrict__ cnt, int N) {
    int f = threadIdx.x;  // 128
    int a0 = blockIdx.x * 256;
    int a1 = min(a0 + 256, N);
    float sum = 0.f;
    int cur = -1, run = 0;
    for (int a = a0; a < a1; ++a) {
        int m = c2m[a2c[a]];
        if (m != cur) {
            if (cur >= 0) {
                unsafeAtomicAdd(&mols[(size_t)cur * H_DIM + f], sum);
                if (f == 0) atomicAdd(&cnt[cur], run);
            }
            cur = m; sum = 0.f; run = 0;
        }
        sum += s[(size_t)a * H_DIM + f];
        ++run;
    }
    if (cur >= 0) {
        unsafeAtomicAdd(&mols[(size_t)cur * H_DIM + f], sum);
        if (f == 0) atomicAdd(&cnt[cur], run);
    }
}

// ---------------------------------------------------------------- head
// out[m] = ssp((mols[m]@lin2 + cnt*b2) @ hw1 + hb1) @ hw2 + hb2
__global__ __launch_bounds__(128) void head_kernel(
        const float* __restrict__ mols, const int* __restrict__ cnt,
        const float* __restrict__ l2w, const float* __restrict__ l2b,
        const float* __restrict__ hw1, const float* __restrict__ hb1,
        const float* __restrict__ hw2, const float* __restrict__ hb2,
        float* __restrict__ out) {
    int m = blockIdx.x, f = threadIdx.x;
    __shared__ float me[H_DIM];
    __shared__ float u[H_DIM / 2];
    const float* ms = mols + (size_t)m * H_DIM;
    float acc = l2b[f] * (float)cnt[m];
#pragma unroll 16
    for (int k = 0; k < H_DIM; ++k) acc += ms[k] * l2w[k * H_DIM + f];
    me[f] = acc;
    __syncthreads();
    if (f < 64) {
        float a2 = hb1[f];
#pragma unroll 16
        for (int k = 0; k < H_DIM; ++k) a2 += me[k] * hw1[k * 64 + f];
        u[f] = sspf(a2);
    }
    __syncthreads();
    if (f == 0) {
        float o = hb2[0];
#pragma unroll 16
        for (int j = 0; j < 64; ++j) o += u[j] * hw2[j];
        out[m] = o;
    }
}

// ---------------------------------------------------------------- launch
extern "C" void kernel_launch(void* const* d_in, const int* in_sizes, int n_in,
                              void* d_out, int out_size, void* d_ws, size_t ws_size,
                              hipStream_t stream) {
    const int*   z   = (const int*)d_in[0];
    const float* pos = (const float*)d_in[1];
    const int*   er  = (const int*)d_in[2];
    const int*   ec  = (const int*)d_in[3];
    const int*   a2c = (const int*)d_in[4];
    const int*   c2m = (const int*)d_in[5];
    const float* emb = (const float*)d_in[6];
    const float* w1  = (const float*)d_in[7];
    const float* b1  = (const float*)d_in[8];
    const float* w2  = (const float*)d_in[9];
    const float* b2  = (const float*)d_in[10];
    const float* c1w = (const float*)d_in[11];
    const float* c2w = (const float*)d_in[12];
    const float* c2b = (const float*)d_in[13];
    const float* iw  = (const float*)d_in[14];
    const float* ib  = (const float*)d_in[15];
    const float* l1w = (const float*)d_in[16];
    const float* l1b = (const float*)d_in[17];
    const float* l2w = (const float*)d_in[18];
    const float* l2b = (const float*)d_in[19];
    const float* hw1 = (const float*)d_in[20];
    const float* hb1 = (const float*)d_in[21];
    const float* hw2 = (const float*)d_in[22];
    const float* hb2 = (const float*)d_in[23];

    const int N  = in_sizes[0];
    const int E  = in_sizes[2];
    const int NM = out_size;
    float* out = (float*)d_out;

    // workspace layout (~88 MB)
    float* dbuf = (float*)d_ws;
    float* cbuf = dbuf + E;
    float* tab  = cbuf + E;
    float* h    = tab + (size_t)L_LAYERS * TBL * NF_DIM;
    float* xf   = h + (size_t)N * H_DIM;   // also reused for t1 and s
    float* agg  = xf + (size_t)N * H_DIM;
    float* mols = agg + (size_t)N * H_DIM;
    int*   cnt  = (int*)(mols + (size_t)NM * H_DIM);

    edge_geom<<<(E + 255) / 256, 256, 0, stream>>>(pos, er, ec, dbuf, cbuf, E);
    build_tables<<<L_LAYERS * TBL, 128, 0, stream>>>(w1, b1, w2, b2, tab);
    embed_kernel<<<(N * H_DIM + 255) / 256, 256, 0, stream>>>(z, emb, h, N);

    int gblocks = (N + 63) / 64;
    for (int l = 0; l < L_LAYERS; ++l) {
        hipMemsetAsync(agg, 0, (size_t)N * H_DIM * sizeof(float), stream);
        // xf = h @ conv_lin1_w[l]
        gemm128<<<gblocks, 256, 0, stream>>>(
            h, c1w + (size_t)l * H_DIM * NF_DIM, nullptr, xf, N, 0);
        // agg = scatter_add(xf[row] * W(d) * C, col)
        edge_msg<<<(E + 7) / 8, 256, 0, stream>>>(
            er, ec, dbuf, cbuf, xf, tab + (size_t)l * TBL * NF_DIM, agg, E);
        // t1 = agg @ conv_lin2_w[l] + b   (t1 lives in xf)
        gemm128<<<gblocks, 256, 0, stream>>>(
            agg, c2w + (size_t)l * NF_DIM * H_DIM, c2b + (size_t)l * H_DIM, xf, N,
            MODE_BIAS);
        // h += ssp(t1) @ int_lin_w[l] + b
        gemm128<<<gblocks, 256, 0, stream>>>(
            xf, iw + (size_t)l * H_DIM * H_DIM, ib + (size_t)l * H_DIM, h, N,
            MODE_SSP_A | MODE_BIAS | MODE_ACCUM);
    }
    // s = ssp(h @ lin1_w + b1)   (s lives in xf)
    gemm128<<<gblocks, 256, 0, stream>>>(
        h, l1w, l1b, xf, N, MODE_BIAS | MODE_SSP_OUT);

    hipMemsetAsync(mols, 0, (size_t)NM * H_DIM * sizeof(float) + NM * sizeof(int), stream);
    mol_reduce<<<(N + 255) / 256, 128, 0, stream>>>(xf, a2c, c2m, mols, cnt, N);
    head_kernel<<<NM, 128, 0, stream>>>(mols, cnt, l2w, l2b, hw1, hb1, hw2, hb2, out);
}

// Round 2
// 1491.193 us; speedup vs baseline: 4.8447x; 4.8447x over previous
//
#include <hip/hip_runtime.h>
#include <hip/hip_bf16.h>
#include <math.h>

#define H_DIM   128
#define NF_DIM  128
#define G_DIM   50
#define L_LAYERS 6
#define TBL     2048
#define DMAX    12.8f
#define CUTOFF_C 10.0f
// -0.5 / (CUTOFF/(G-1))^2 = -0.5 * (49/10)^2
#define COEFF_C (-0.5f * 49.0f * 49.0f / 100.0f)
#define SCAN_B  256

__device__ __forceinline__ float sspf(float x) {
    // shifted softplus: log(1+exp(x)) - log(2), numerically stable
    return fmaxf(x, 0.0f) + log1pf(expf(-fabsf(x))) - 0.69314718055994530942f;
}

// ---------------------------------------------------------------- filter tables
// tab[l][t][f] = (ssp(g(d_t)@w1 + b1) @ w2 + b2)[f],  d_t = t * DMAX/(TBL-1)
__global__ __launch_bounds__(128) void build_tables(
        const float* __restrict__ w1, const float* __restrict__ b1,
        const float* __restrict__ w2, const float* __restrict__ b2,
        float* __restrict__ tab) {
    int l = blockIdx.x / TBL;
    int t = blockIdx.x % TBL;
    int f = threadIdx.x;  // 128
    float dt = t * (DMAX / (TBL - 1));
    __shared__ float gs[G_DIM];
    __shared__ float sy[NF_DIM];
    if (f < G_DIM) {
        float o = f * (CUTOFF_C / (G_DIM - 1));
        float dd = dt - o;
        gs[f] = expf(COEFF_C * dd * dd);
    }
    __syncthreads();
    const float* W1 = w1 + (size_t)l * G_DIM * NF_DIM;
    float y = b1[l * NF_DIM + f];
#pragma unroll 10
    for (int g = 0; g < G_DIM; ++g) y += gs[g] * W1[g * NF_DIM + f];
    sy[f] = sspf(y);
    __syncthreads();
    const float* W2 = w2 + (size_t)l * NF_DIM * NF_DIM;
    float y2 = b2[l * NF_DIM + f];
#pragma unroll 16
    for (int k = 0; k < NF_DIM; ++k) y2 += sy[k] * W2[k * NF_DIM + f];
    tab[((size_t)l * TBL + t) * NF_DIM + f] = y2;
}

// ---------------------------------------------------------------- embedding
__global__ __launch_bounds__(256) void embed_kernel(
        const int* __restrict__ z, const float* __restrict__ emb,
        float* __restrict__ h, int N) {
    int idx = blockIdx.x * blockDim.x + threadIdx.x;
    if (idx >= N * H_DIM) return;
    int n = idx >> 7, f = idx & 127;
    h[idx] = emb[z[n] * H_DIM + f];
}

// ---------------------------------------------------------------- CSR build
__global__ __launch_bounds__(256) void count_kernel(
        const int* __restrict__ ec, int* __restrict__ cnt, int E) {
    int e = blockIdx.x * blockDim.x + threadIdx.x;
    if (e < E) atomicAdd(&cnt[ec[e]], 1);
}

__global__ __launch_bounds__(SCAN_B) void scan1(
        const int* __restrict__ cnt, int* __restrict__ excl,
        int* __restrict__ bsums, int N) {
    __shared__ int s[SCAN_B];
    int i = blockIdx.x * SCAN_B + threadIdx.x;
    int v = (i < N) ? cnt[i] : 0;
    s[threadIdx.x] = v;
    __syncthreads();
    for (int off = 1; off < SCAN_B; off <<= 1) {
        int t = (threadIdx.x >= off) ? s[threadIdx.x - off] : 0;
        __syncthreads();
        s[threadIdx.x] += t;
        __syncthreads();
    }
    if (i < N) excl[i] = s[threadIdx.x] - v;
    if (threadIdx.x == SCAN_B - 1) bsums[blockIdx.x] = s[SCAN_B - 1];
}

__global__ __launch_bounds__(SCAN_B) void scan2(int* __restrict__ bsums, int nb) {
    __shared__ int s[SCAN_B];
    int v = (threadIdx.x < nb) ? bsums[threadIdx.x] : 0;
    s[threadIdx.x] = v;
    __syncthreads();
    for (int off = 1; off < SCAN_B; off <<= 1) {
        int t = (threadIdx.x >= off) ? s[threadIdx.x - off] : 0;
        __syncthreads();
        s[threadIdx.x] += t;
        __syncthreads();
    }
    if (threadIdx.x < nb) bsums[threadIdx.x] = s[threadIdx.x] - v;  // exclusive
}

__global__ __launch_bounds__(SCAN_B) void scan3(
        const int* __restrict__ excl, const int* __restrict__ bsums,
        int* __restrict__ row_start, int* __restrict__ cursor, int N, int E) {
    int i = blockIdx.x * SCAN_B + threadIdx.x;
    if (i < N) {
        int v = excl[i] + bsums[blockIdx.x];
        row_start[i] = v;
        cursor[i] = v;
    }
    if (i == 0) row_start[N] = E;
}

// per-edge record, written to its CSR slot:  {row, i0, C*(1-fr), C*fr}
__global__ __launch_bounds__(256) void build_edges(
        const int* __restrict__ er, const int* __restrict__ ec,
        const float* __restrict__ pos, int* __restrict__ cursor,
        int4* __restrict__ edges, int E) {
    int e = blockIdx.x * blockDim.x + threadIdx.x;
    if (e >= E) return;
    int r = er[e], c = ec[e];
    float dx = pos[r * 3 + 0] - pos[c * 3 + 0];
    float dy = pos[r * 3 + 1] - pos[c * 3 + 1];
    float dz = pos[r * 3 + 2] - pos[c * 3 + 2];
    float d = sqrtf(dx * dx + dy * dy + dz * dz);
    float C = 0.5f * (cosf(d * (3.14159265358979323846f / CUTOFF_C)) + 1.0f);
    float t = fminf(d, DMAX) * ((TBL - 1) / DMAX);
    int i0 = (int)t;
    if (i0 > TBL - 2) i0 = TBL - 2;
    float fr = t - (float)i0;
    int pos_ = atomicAdd(&cursor[c], 1);
    edges[pos_] = make_int4(r, i0, __float_as_int(C * (1.0f - fr)),
                            __float_as_int(C * fr));
}

// ---------------------------------------------------------------- edge gather
// agg[i] = sum over incident edges of xf[row] * (a*tab[i0] + b*tab[i0+1])
// 32 threads per atom (float4 per thread), 8 atoms per 256-block. No atomics.
__global__ __launch_bounds__(256) void edge_agg(
        const int4* __restrict__ edges, const int* __restrict__ row_start,
        const float* __restrict__ xf, const float* __restrict__ tab_l,
        float* __restrict__ agg, int N) {
    int tid = threadIdx.x;
    int atom = blockIdx.x * 8 + (tid >> 5);
    if (atom >= N) return;
    int f4 = (tid & 31) * 4;
    float4 acc = make_float4(0.f, 0.f, 0.f, 0.f);
    int j0 = row_start[atom], j1 = row_start[atom + 1];
    for (int j = j0; j < j1; ++j) {
        int4 ed = edges[j];
        int r = ed.x, i0 = ed.y;
        float a = __int_as_float(ed.z), b = __int_as_float(ed.w);
        const float4 w0 = *(const float4*)(tab_l + (size_t)i0 * NF_DIM + f4);
        const float4 w1 = *(const float4*)(tab_l + (size_t)(i0 + 1) * NF_DIM + f4);
        const float4 xv = *(const float4*)(xf + (size_t)r * NF_DIM + f4);
        acc.x += xv.x * (a * w0.x + b * w1.x);
        acc.y += xv.y * (a * w0.y + b * w1.y);
        acc.z += xv.z * (a * w0.z + b * w1.z);
        acc.w += xv.w * (a * w0.w + b * w1.w);
    }
    *(float4*)(agg + (size_t)atom * NF_DIM + f4) = acc;
}

// ---------------------------------------------------------------- node GEMM
// Out(M x 128) = op(A)(M x 128) @ B(128 x 128) [+bias] [ssp] [+=]
#define MODE_SSP_A   1
#define MODE_BIAS    2
#define MODE_SSP_OUT 4
#define MODE_ACCUM   8

__global__ __launch_bounds__(256, 3) void gemm128(
        const float* __restrict__ A, const float* __restrict__ B,
        const float* __restrict__ bias, float* __restrict__ Out,
        int M, int mode) {
    __shared__ float As[64 * 132];
    __shared__ float Bs[32 * 132];
    int tid = threadIdx.x;
    int m0 = blockIdx.x * 64;

    for (int i = tid; i < 64 * 32; i += 256) {
        int r = i >> 5, c4 = (i & 31) * 4;
        float4 v = make_float4(0.f, 0.f, 0.f, 0.f);
        if (m0 + r < M) v = *(const float4*)(A + (size_t)(m0 + r) * 128 + c4);
        if (mode & MODE_SSP_A) { v.x = sspf(v.x); v.y = sspf(v.y); v.z = sspf(v.z); v.w = sspf(v.w); }
        *(float4*)(As + r * 132 + c4) = v;
    }

    int tr = tid >> 4, tc = tid & 15;
    float acc[4][8];
#pragma unroll
    for (int i = 0; i < 4; ++i)
#pragma unroll
        for (int j = 0; j < 8; ++j) acc[i][j] = 0.f;

    for (int kc = 0; kc < 4; ++kc) {
        for (int i = tid; i < 32 * 32; i += 256) {
            int r = i >> 5, c4 = (i & 31) * 4;
            *(float4*)(Bs + r * 132 + c4) =
                *(const float4*)(B + (size_t)(kc * 32 + r) * 128 + c4);
        }
        __syncthreads();
        for (int k = 0; k < 32; k += 4) {
            float a_[4][4];
#pragma unroll
            for (int i = 0; i < 4; ++i) {
                float4 t4 = *(const float4*)(As + (tr * 4 + i) * 132 + kc * 32 + k);
                a_[i][0] = t4.x; a_[i][1] = t4.y; a_[i][2] = t4.z; a_[i][3] = t4.w;
            }
            float b_[4][8];
#pragma unroll
            for (int kk = 0; kk < 4; ++kk) {
                float4 t0 = *(const float4*)(Bs + (k + kk) * 132 + tc * 8);
                float4 t1 = *(const float4*)(Bs + (k + kk) * 132 + tc * 8 + 4);
                b_[kk][0] = t0.x; b_[kk][1] = t0.y; b_[kk][2] = t0.z; b_[kk][3] = t0.w;
                b_[kk][4] = t1.x; b_[kk][5] = t1.y; b_[kk][6] = t1.z; b_[kk][7] = t1.w;
            }
#pragma unroll
            for (int kk = 0; kk < 4; ++kk)
#pragma unroll
                for (int i = 0; i < 4; ++i)
#pragma unroll
                    for (int j = 0; j < 8; ++j)
                        acc[i][j] += a_[i][kk] * b_[kk][j];
        }
        __syncthreads();
    }

    float bv[8];
#pragma unroll
    for (int j = 0; j < 8; ++j) bv[j] = (mode & MODE_BIAS) ? bias[tc * 8 + j] : 0.f;
#pragma unroll
    for (int i = 0; i < 4; ++i) {
        int r = m0 + tr * 4 + i;
        if (r >= M) continue;
        float* op = Out + (size_t)r * 128 + tc * 8;
        float vals[8];
#pragma unroll
        for (int j = 0; j < 8; ++j) {
            float v = acc[i][j] + bv[j];
            if (mode & MODE_SSP_OUT) v = sspf(v);
            vals[j] = v;
        }
        if (mode & MODE_ACCUM) {
            float4 o0 = *(float4*)(op);
            float4 o1 = *(float4*)(op + 4);
            o0.x += vals[0]; o0.y += vals[1]; o0.z += vals[2]; o0.w += vals[3];
            o1.x += vals[4]; o1.y += vals[5]; o1.z += vals[6]; o1.w += vals[7];
            *(float4*)(op) = o0;
            *(float4*)(op + 4) = o1;
        } else {
            *(float4*)(op) = make_float4(vals[0], vals[1], vals[2], vals[3]);
            *(float4*)(op + 4) = make_float4(vals[4], vals[5], vals[6], vals[7]);
        }
    }
}

// ---------------------------------------------------------------- atom -> mol sum
__global__ __launch_bounds__(128) void mol_reduce(
        const float* __restrict__ s, const int* __restrict__ a2c,
        const int* __restrict__ c2m, float* __restrict__ mols,
        int* __restrict__ cnt, int N) {
    int f = threadIdx.x;
    int a0 = blockIdx.x * 256;
    int a1 = min(a0 + 256, N);
    float sum = 0.f;
    int cur = -1, run = 0;
    for (int a = a0; a < a1; ++a) {
        int m = c2m[a2c[a]];
        if (m != cur) {
            if (cur >= 0) {
                unsafeAtomicAdd(&mols[(size_t)cur * H_DIM + f], sum);
                if (f == 0) atomicAdd(&cnt[cur], run);
            }
            cur = m; sum = 0.f; run = 0;
        }
        sum += s[(size_t)a * H_DIM + f];
        ++run;
    }
    if (cur >= 0) {
        unsafeAtomicAdd(&mols[(size_t)cur * H_DIM + f], sum);
        if (f == 0) atomicAdd(&cnt[cur], run);
    }
}

// ---------------------------------------------------------------- head
__global__ __launch_bounds__(128) void head_kernel(
        const float* __restrict__ mols, const int* __restrict__ cnt,
        const float* __restrict__ l2w, const float* __restrict__ l2b,
        const float* __restrict__ hw1, const float* __restrict__ hb1,
        const float* __restrict__ hw2, const float* __restrict__ hb2,
        float* __restrict__ out) {
    int m = blockIdx.x, f = threadIdx.x;
    __shared__ float me[H_DIM];
    __shared__ float u[H_DIM / 2];
    const float* ms = mols + (size_t)m * H_DIM;
    float acc = l2b[f] * (float)cnt[m];
#pragma unroll 16
    for (int k = 0; k < H_DIM; ++k) acc += ms[k] * l2w[k * H_DIM + f];
    me[f] = acc;
    __syncthreads();
    if (f < 64) {
        float a2 = hb1[f];
#pragma unroll 16
        for (int k = 0; k < H_DIM; ++k) a2 += me[k] * hw1[k * 64 + f];
        u[f] = sspf(a2);
    }
    __syncthreads();
    if (f == 0) {
        float o = hb2[0];
#pragma unroll 16
        for (int j = 0; j < 64; ++j) o += u[j] * hw2[j];
        out[m] = o;
    }
}

// ---------------------------------------------------------------- launch
extern "C" void kernel_launch(void* const* d_in, const int* in_sizes, int n_in,
                              void* d_out, int out_size, void* d_ws, size_t ws_size,
                              hipStream_t stream) {
    const int*   z   = (const int*)d_in[0];
    const float* pos = (const float*)d_in[1];
    const int*   er  = (const int*)d_in[2];
    const int*   ec  = (const int*)d_in[3];
    const int*   a2c = (const int*)d_in[4];
    const int*   c2m = (const int*)d_in[5];
    const float* emb = (const float*)d_in[6];
    const float* w1  = (const float*)d_in[7];
    const float* b1  = (const float*)d_in[8];
    const float* w2  = (const float*)d_in[9];
    const float* b2  = (const float*)d_in[10];
    const float* c1w = (const float*)d_in[11];
    const float* c2w = (const float*)d_in[12];
    const float* c2b = (const float*)d_in[13];
    const float* iw  = (const float*)d_in[14];
    const float* ib  = (const float*)d_in[15];
    const float* l1w = (const float*)d_in[16];
    const float* l1b = (const float*)d_in[17];
    const float* l2w = (const float*)d_in[18];
    const float* l2b = (const float*)d_in[19];
    const float* hw1 = (const float*)d_in[20];
    const float* hb1 = (const float*)d_in[21];
    const float* hw2 = (const float*)d_in[22];
    const float* hb2 = (const float*)d_in[23];

    const int N  = in_sizes[0];
    const int E  = in_sizes[2];
    const int NM = out_size;
    float* out = (float*)d_out;

    // workspace layout (~93 MB); edges first for 16B alignment
    int4*  edges = (int4*)d_ws;
    float* tab   = (float*)(edges + E);
    float* h     = tab + (size_t)L_LAYERS * TBL * NF_DIM;
    float* xf    = h + (size_t)N * H_DIM;
    float* agg   = xf + (size_t)N * H_DIM;
    float* mols  = agg + (size_t)N * H_DIM;
    int*   cnt_m = (int*)(mols + (size_t)NM * H_DIM);
    int*   ccnt  = cnt_m + NM;
    int*   row_start = ccnt + N;            // N+1
    int*   cursor = row_start + N + 1;
    int*   bsums  = cursor + N;             // 256
    int*   excl   = bsums + 256;            // N

    // --- CSR build (once per launch; edges fixed across layers) ---
    hipMemsetAsync(ccnt, 0, (size_t)N * sizeof(int), stream);
    count_kernel<<<(E + 255) / 256, 256, 0, stream>>>(ec, ccnt, E);
    int nb = (N + SCAN_B - 1) / SCAN_B;
    scan1<<<nb, SCAN_B, 0, stream>>>(ccnt, excl, bsums, N);
    scan2<<<1, SCAN_B, 0, stream>>>(bsums, nb);
    scan3<<<nb, SCAN_B, 0, stream>>>(excl, bsums, row_start, cursor, N, E);
    build_edges<<<(E + 255) / 256, 256, 0, stream>>>(er, ec, pos, cursor, edges, E);

    build_tables<<<L_LAYERS * TBL, 128, 0, stream>>>(w1, b1, w2, b2, tab);
    embed_kernel<<<(N * H_DIM + 255) / 256, 256, 0, stream>>>(z, emb, h, N);

    int gblocks = (N + 63) / 64;
    for (int l = 0; l < L_LAYERS; ++l) {
        // xf = h @ conv_lin1_w[l]
        gemm128<<<gblocks, 256, 0, stream>>>(
            h, c1w + (size_t)l * H_DIM * NF_DIM, nullptr, xf, N, 0);
        // agg[i] = sum_j xf[row_j] * W(d_j) * C_j   (gather, no atomics)
        edge_agg<<<(N + 7) / 8, 256, 0, stream>>>(
            edges, row_start, xf, tab + (size_t)l * TBL * NF_DIM, agg, N);
        // t1 = agg @ conv_lin2_w[l] + b   (t1 lives in xf)
        gemm128<<<gblocks, 256, 0, stream>>>(
            agg, c2w + (size_t)l * NF_DIM * H_DIM, c2b + (size_t)l * H_DIM, xf, N,
            MODE_BIAS);
        // h += ssp(t1) @ int_lin_w[l] + b
        gemm128<<<gblocks, 256, 0, stream>>>(
            xf, iw + (size_t)l * H_DIM * H_DIM, ib + (size_t)l * H_DIM, h, N,
            MODE_SSP_A | MODE_BIAS | MODE_ACCUM);
    }
    // s = ssp(h @ lin1_w + b1)   (s lives in xf)
    gemm128<<<gblocks, 256, 0, stream>>>(
        h, l1w, l1b, xf, N, MODE_BIAS | MODE_SSP_OUT);

    hipMemsetAsync(mols, 0, (size_t)NM * H_DIM * sizeof(float) + NM * sizeof(int), stream);
    mol_reduce<<<(N + 255) / 256, 128, 0, stream>>>(xf, a2c, c2m, mols, cnt_m, N);
    head_kernel<<<NM, 128, 0, stream>>>(mols, cnt_m, l2w, l2b, hw1, hb1, hw2, hb2, out);
}

// Round 3
// 1408.876 us; speedup vs baseline: 5.1278x; 1.0584x over previous
//
#include <hip/hip_runtime.h>
#include <hip/hip_bf16.h>
#include <math.h>

#define H_DIM   128
#define NF_DIM  128
#define G_DIM   50
#define L_LAYERS 6
#define TBL     2048
#define DMAX    12.8f
#define CUTOFF_C 10.0f
#define COEFF_C (-0.5f * 49.0f * 49.0f / 100.0f)
#define SCAN_B  256

typedef __bf16 bf16x8 __attribute__((ext_vector_type(8)));
typedef float  f32x4  __attribute__((ext_vector_type(4)));

__device__ __forceinline__ float sspf(float x) {
    return fmaxf(x, 0.0f) + log1pf(expf(-fabsf(x))) - 0.69314718055994530942f;
}

__device__ __forceinline__ unsigned short f2bf(float f) {
    unsigned int u = __float_as_uint(f);
    u = (u + 0x7fffu + ((u >> 16) & 1u)) >> 16;   // round-to-nearest-even
    return (unsigned short)u;
}

// ---------------------------------------------------------------- filter tables
__global__ __launch_bounds__(128) void build_tables(
        const float* __restrict__ w1, const float* __restrict__ b1,
        const float* __restrict__ w2, const float* __restrict__ b2,
        float* __restrict__ tab) {
    int l = blockIdx.x / TBL;
    int t = blockIdx.x % TBL;
    int f = threadIdx.x;  // 128
    float dt = t * (DMAX / (TBL - 1));
    __shared__ float gs[G_DIM];
    __shared__ float sy[NF_DIM];
    if (f < G_DIM) {
        float o = f * (CUTOFF_C / (G_DIM - 1));
        float dd = dt - o;
        gs[f] = expf(COEFF_C * dd * dd);
    }
    __syncthreads();
    const float* W1 = w1 + (size_t)l * G_DIM * NF_DIM;
    float y = b1[l * NF_DIM + f];
#pragma unroll 10
    for (int g = 0; g < G_DIM; ++g) y += gs[g] * W1[g * NF_DIM + f];
    sy[f] = sspf(y);
    __syncthreads();
    const float* W2 = w2 + (size_t)l * NF_DIM * NF_DIM;
    float y2 = b2[l * NF_DIM + f];
#pragma unroll 16
    for (int k = 0; k < NF_DIM; ++k) y2 += sy[k] * W2[k * NF_DIM + f];
    tab[((size_t)l * TBL + t) * NF_DIM + f] = y2;
}

// ---------------------------------------------------------------- embedding
__global__ __launch_bounds__(256) void embed_kernel(
        const int* __restrict__ z, const float* __restrict__ emb,
        float* __restrict__ h, int N) {
    int idx = blockIdx.x * blockDim.x + threadIdx.x;
    if (idx >= N * H_DIM) return;
    int n = idx >> 7, f = idx & 127;
    h[idx] = emb[z[n] * H_DIM + f];
}

// ---------------------------------------------------------------- weight prep
// Bt[n][k] = bf16(W[k][n]) per 128x128 matrix (blockIdx = matrix index)
__global__ __launch_bounds__(256) void prep_wt(
        const float* __restrict__ W, unsigned short* __restrict__ Bt) {
    int m = blockIdx.x;
    const float* src = W + (size_t)m * 128 * 128;
    unsigned short* dst = Bt + (size_t)m * 128 * 128;
    for (int i = threadIdx.x; i < 128 * 128; i += 256) {
        int n = i & 127, k = i >> 7;
        dst[n * 128 + k] = f2bf(src[k * 128 + n]);
    }
}

// ---------------------------------------------------------------- CSR build
__global__ __launch_bounds__(256) void count_kernel(
        const int* __restrict__ ec, int* __restrict__ cnt, int E) {
    int e = blockIdx.x * blockDim.x + threadIdx.x;
    if (e < E) atomicAdd(&cnt[ec[e]], 1);
}

__global__ __launch_bounds__(SCAN_B) void scan1(
        const int* __restrict__ cnt, int* __restrict__ excl,
        int* __restrict__ bsums, int N) {
    __shared__ int s[SCAN_B];
    int i = blockIdx.x * SCAN_B + threadIdx.x;
    int v = (i < N) ? cnt[i] : 0;
    s[threadIdx.x] = v;
    __syncthreads();
    for (int off = 1; off < SCAN_B; off <<= 1) {
        int t = (threadIdx.x >= off) ? s[threadIdx.x - off] : 0;
        __syncthreads();
        s[threadIdx.x] += t;
        __syncthreads();
    }
    if (i < N) excl[i] = s[threadIdx.x] - v;
    if (threadIdx.x == SCAN_B - 1) bsums[blockIdx.x] = s[SCAN_B - 1];
}

__global__ __launch_bounds__(SCAN_B) void scan2(int* __restrict__ bsums, int nb) {
    __shared__ int s[SCAN_B];
    int v = (threadIdx.x < nb) ? bsums[threadIdx.x] : 0;
    s[threadIdx.x] = v;
    __syncthreads();
    for (int off = 1; off < SCAN_B; off <<= 1) {
        int t = (threadIdx.x >= off) ? s[threadIdx.x - off] : 0;
        __syncthreads();
        s[threadIdx.x] += t;
        __syncthreads();
    }
    if (threadIdx.x < nb) bsums[threadIdx.x] = s[threadIdx.x] - v;
}

__global__ __launch_bounds__(SCAN_B) void scan3(
        const int* __restrict__ excl, const int* __restrict__ bsums,
        int* __restrict__ row_start, int* __restrict__ cursor, int N, int E) {
    int i = blockIdx.x * SCAN_B + threadIdx.x;
    if (i < N) {
        int v = excl[i] + bsums[blockIdx.x];
        row_start[i] = v;
        cursor[i] = v;
    }
    if (i == 0) row_start[N] = E;
}

__global__ __launch_bounds__(256) void build_edges(
        const int* __restrict__ er, const int* __restrict__ ec,
        const float* __restrict__ pos, int* __restrict__ cursor,
        int4* __restrict__ edges, int E) {
    int e = blockIdx.x * blockDim.x + threadIdx.x;
    if (e >= E) return;
    int r = er[e], c = ec[e];
    float dx = pos[r * 3 + 0] - pos[c * 3 + 0];
    float dy = pos[r * 3 + 1] - pos[c * 3 + 1];
    float dz = pos[r * 3 + 2] - pos[c * 3 + 2];
    float d = sqrtf(dx * dx + dy * dy + dz * dz);
    float C = 0.5f * (cosf(d * (3.14159265358979323846f / CUTOFF_C)) + 1.0f);
    float t = fminf(d, DMAX) * ((TBL - 1) / DMAX);
    int i0 = (int)t;
    if (i0 > TBL - 2) i0 = TBL - 2;
    float fr = t - (float)i0;
    int pos_ = atomicAdd(&cursor[c], 1);
    edges[pos_] = make_int4(r, i0, __float_as_int(C * (1.0f - fr)),
                            __float_as_int(C * fr));
}

// ---------------------------------------------------------------- edge gather
__global__ __launch_bounds__(256) void edge_agg(
        const int4* __restrict__ edges, const int* __restrict__ row_start,
        const float* __restrict__ xf, const float* __restrict__ tab_l,
        float* __restrict__ agg, int N) {
    int tid = threadIdx.x;
    int atom = blockIdx.x * 8 + (tid >> 5);
    if (atom >= N) return;
    int f4 = (tid & 31) * 4;
    float4 acc = make_float4(0.f, 0.f, 0.f, 0.f);
    int j0 = row_start[atom], j1 = row_start[atom + 1];
    for (int j = j0; j < j1; ++j) {
        int4 ed = edges[j];
        int r = ed.x, i0 = ed.y;
        float a = __int_as_float(ed.z), b = __int_as_float(ed.w);
        const float4 w0 = *(const float4*)(tab_l + (size_t)i0 * NF_DIM + f4);
        const float4 w1 = *(const float4*)(tab_l + (size_t)(i0 + 1) * NF_DIM + f4);
        const float4 xv = *(const float4*)(xf + (size_t)r * NF_DIM + f4);
        acc.x += xv.x * (a * w0.x + b * w1.x);
        acc.y += xv.y * (a * w0.y + b * w1.y);
        acc.z += xv.z * (a * w0.z + b * w1.z);
        acc.w += xv.w * (a * w0.w + b * w1.w);
    }
    *(float4*)(agg + (size_t)atom * NF_DIM + f4) = acc;
}

// ---------------------------------------------------------------- MFMA GEMM
// Out(M x 128) = op(A)(M x 128) @ W(128 x 128) [+bias] [ssp] [+=]
// Wt is prepped bf16 [n][k]. A staged fp32->bf16, fp32 accumulate.
#define MODE_SSP_A   1
#define MODE_BIAS    2
#define MODE_SSP_OUT 4
#define MODE_ACCUM   8
#define AS_STR 136   // 64x128 bf16 tile, +8 pad: 2-way LDS conflicts only (free)
#define BS_STR 136

__global__ __launch_bounds__(256, 3) void gemm_mfma(
        const float* __restrict__ A, const unsigned short* __restrict__ Wt,
        const float* __restrict__ bias, float* __restrict__ Out,
        int M, int mode) {
    __shared__ __align__(16) unsigned short As[64 * AS_STR];
    __shared__ __align__(16) unsigned short Bs[128 * BS_STR];
    int tid = threadIdx.x;
    int m0 = blockIdx.x * 64;

    // stage Wt (bf16 [n][k]) -> Bs
    for (int i = tid; i < 128 * 16; i += 256) {
        int n = i >> 4, k8 = (i & 15) * 8;
        *(uint4*)(&Bs[n * BS_STR + k8]) = *(const uint4*)(Wt + n * 128 + k8);
    }
    // stage A fp32 -> bf16 (+optional ssp)
    for (int i = tid; i < 64 * 16; i += 256) {
        int r = i >> 4, k8 = (i & 15) * 8;
        int row = m0 + r;
        unsigned short tmp[8];
        if (row < M) {
            const float* ap = A + (size_t)row * 128 + k8;
#pragma unroll
            for (int j = 0; j < 8; ++j) {
                float v = ap[j];
                if (mode & MODE_SSP_A) v = sspf(v);
                tmp[j] = f2bf(v);
            }
        } else {
#pragma unroll
            for (int j = 0; j < 8; ++j) tmp[j] = 0;
        }
        *(uint4*)(&As[r * AS_STR + k8]) = *(const uint4*)tmp;
    }
    __syncthreads();

    int wave = tid >> 6;
    int lane = tid & 63;
    int quad = lane >> 4;
    int l15  = lane & 15;
    int arow = wave * 16 + l15;   // A-frag row within block tile

    f32x4 acc[8] = {};
    for (int ks = 0; ks < 4; ++ks) {
        int k0 = ks * 32 + quad * 8;
        bf16x8 af = *(const bf16x8*)&As[arow * AS_STR + k0];
#pragma unroll
        for (int j = 0; j < 8; ++j) {
            bf16x8 bf = *(const bf16x8*)&Bs[(j * 16 + l15) * BS_STR + k0];
            acc[j] = __builtin_amdgcn_mfma_f32_16x16x32_bf16(af, bf, acc[j], 0, 0, 0);
        }
    }

    // epilogue: C/D layout col=lane&15, row=quad*4+reg
#pragma unroll
    for (int j = 0; j < 8; ++j) {
        int col = j * 16 + l15;
        float bv = (mode & MODE_BIAS) ? bias[col] : 0.f;
#pragma unroll
        for (int r = 0; r < 4; ++r) {
            int row = m0 + wave * 16 + quad * 4 + r;
            if (row < M) {
                float v = acc[j][r] + bv;
                if (mode & MODE_SSP_OUT) v = sspf(v);
                float* op = Out + (size_t)row * 128 + col;
                if (mode & MODE_ACCUM) v += *op;
                *op = v;
            }
        }
    }
}

// ---------------------------------------------------------------- atom -> mol sum
#define MR_ATOMS 32
__global__ __launch_bounds__(128) void mol_reduce(
        const float* __restrict__ s, const int* __restrict__ a2c,
        const int* __restrict__ c2m, float* __restrict__ mols,
        int* __restrict__ cnt, int N) {
    int f = threadIdx.x;
    int a0 = blockIdx.x * MR_ATOMS;
    int a1 = min(a0 + MR_ATOMS, N);
    float sum = 0.f;
    int cur = -1, run = 0;
    for (int a = a0; a < a1; ++a) {
        int m = c2m[a2c[a]];
        if (m != cur) {
            if (cur >= 0) {
                unsafeAtomicAdd(&mols[(size_t)cur * H_DIM + f], sum);
                if (f == 0) atomicAdd(&cnt[cur], run);
            }
            cur = m; sum = 0.f; run = 0;
        }
        sum += s[(size_t)a * H_DIM + f];
        ++run;
    }
    if (cur >= 0) {
        unsafeAtomicAdd(&mols[(size_t)cur * H_DIM + f], sum);
        if (f == 0) atomicAdd(&cnt[cur], run);
    }
}

// ---------------------------------------------------------------- head
__global__ __launch_bounds__(128) void head_kernel(
        const float* __restrict__ mols, const int* __restrict__ cnt,
        const float* __restrict__ l2w, const float* __restrict__ l2b,
        const float* __restrict__ hw1, const float* __restrict__ hb1,
        const float* __restrict__ hw2, const float* __restrict__ hb2,
        float* __restrict__ out) {
    int m = blockIdx.x, f = threadIdx.x;
    __shared__ float me[H_DIM];
    __shared__ float u[H_DIM / 2];
    const float* ms = mols + (size_t)m * H_DIM;
    float acc = l2b[f] * (float)cnt[m];
#pragma unroll 16
    for (int k = 0; k < H_DIM; ++k) acc += ms[k] * l2w[k * H_DIM + f];
    me[f] = acc;
    __syncthreads();
    if (f < 64) {
        float a2 = hb1[f];
#pragma unroll 16
        for (int k = 0; k < H_DIM; ++k) a2 += me[k] * hw1[k * 64 + f];
        u[f] = sspf(a2);
    }
    __syncthreads();
    if (f == 0) {
        float o = hb2[0];
#pragma unroll 16
        for (int j = 0; j < 64; ++j) o += u[j] * hw2[j];
        out[m] = o;
    }
}

// ---------------------------------------------------------------- launch
extern "C" void kernel_launch(void* const* d_in, const int* in_sizes, int n_in,
                              void* d_out, int out_size, void* d_ws, size_t ws_size,
                              hipStream_t stream) {
    const int*   z   = (const int*)d_in[0];
    const float* pos = (const float*)d_in[1];
    const int*   er  = (const int*)d_in[2];
    const int*   ec  = (const int*)d_in[3];
    const int*   a2c = (const int*)d_in[4];
    const int*   c2m = (const int*)d_in[5];
    const float* emb = (const float*)d_in[6];
    const float* w1  = (const float*)d_in[7];
    const float* b1  = (const float*)d_in[8];
    const float* w2  = (const float*)d_in[9];
    const float* b2  = (const float*)d_in[10];
    const float* c1w = (const float*)d_in[11];
    const float* c2w = (const float*)d_in[12];
    const float* c2b = (const float*)d_in[13];
    const float* iw  = (const float*)d_in[14];
    const float* ib  = (const float*)d_in[15];
    const float* l1w = (const float*)d_in[16];
    const float* l1b = (const float*)d_in[17];
    const float* l2w = (const float*)d_in[18];
    const float* l2b = (const float*)d_in[19];
    const float* hw1 = (const float*)d_in[20];
    const float* hb1 = (const float*)d_in[21];
    const float* hw2 = (const float*)d_in[22];
    const float* hb2 = (const float*)d_in[23];

    const int N  = in_sizes[0];
    const int E  = in_sizes[2];
    const int NM = out_size;
    float* out = (float*)d_out;

    // workspace layout
    char* wsp = (char*)d_ws;
    int4*  edges = (int4*)wsp;            wsp += (size_t)E * sizeof(int4);
    float* tab   = (float*)wsp;           wsp += (size_t)L_LAYERS * TBL * NF_DIM * 4;
    unsigned short* wbt = (unsigned short*)wsp;  wsp += (size_t)19 * 16384 * 2;
    float* h     = (float*)wsp;           wsp += (size_t)N * H_DIM * 4;
    float* xf    = (float*)wsp;           wsp += (size_t)N * H_DIM * 4;
    float* agg   = (float*)wsp;           wsp += (size_t)N * H_DIM * 4;
    float* mols  = (float*)wsp;           wsp += (size_t)NM * H_DIM * 4;
    int*   cnt_m = (int*)wsp;             wsp += (size_t)NM * 4;
    int*   ccnt  = (int*)wsp;             wsp += (size_t)N * 4;
    int*   row_start = (int*)wsp;         wsp += (size_t)(N + 1) * 4;
    int*   cursor = (int*)wsp;            wsp += (size_t)N * 4;
    int*   bsums  = (int*)wsp;            wsp += 256 * 4;
    int*   excl   = (int*)wsp;

    // --- CSR build (edges fixed across layers) ---
    hipMemsetAsync(ccnt, 0, (size_t)N * sizeof(int), stream);
    count_kernel<<<(E + 255) / 256, 256, 0, stream>>>(ec, ccnt, E);
    int nb = (N + SCAN_B - 1) / SCAN_B;
    scan1<<<nb, SCAN_B, 0, stream>>>(ccnt, excl, bsums, N);
    scan2<<<1, SCAN_B, 0, stream>>>(bsums, nb);
    scan3<<<nb, SCAN_B, 0, stream>>>(excl, bsums, row_start, cursor, N, E);
    build_edges<<<(E + 255) / 256, 256, 0, stream>>>(er, ec, pos, cursor, edges, E);

    build_tables<<<L_LAYERS * TBL, 128, 0, stream>>>(w1, b1, w2, b2, tab);
    embed_kernel<<<(N * H_DIM + 255) / 256, 256, 0, stream>>>(z, emb, h, N);

    // --- weight prep: bf16 transposed [n][k] ---
    prep_wt<<<L_LAYERS, 256, 0, stream>>>(c1w, wbt);
    prep_wt<<<L_LAYERS, 256, 0, stream>>>(c2w, wbt + (size_t)6 * 16384);
    prep_wt<<<L_LAYERS, 256, 0, stream>>>(iw,  wbt + (size_t)12 * 16384);
    prep_wt<<<1,        256, 0, stream>>>(l1w, wbt + (size_t)18 * 16384);

    int gblocks = (N + 63) / 64;
    for (int l = 0; l < L_LAYERS; ++l) {
        gemm_mfma<<<gblocks, 256, 0, stream>>>(
            h, wbt + (size_t)l * 16384, nullptr, xf, N, 0);
        edge_agg<<<(N + 7) / 8, 256, 0, stream>>>(
            edges, row_start, xf, tab + (size_t)l * TBL * NF_DIM, agg, N);
        gemm_mfma<<<gblocks, 256, 0, stream>>>(
            agg, wbt + (size_t)(6 + l) * 16384, c2b + (size_t)l * H_DIM, xf, N,
            MODE_BIAS);
        gemm_mfma<<<gblocks, 256, 0, stream>>>(
            xf, wbt + (size_t)(12 + l) * 16384, ib + (size_t)l * H_DIM, h, N,
            MODE_SSP_A | MODE_BIAS | MODE_ACCUM);
    }
    gemm_mfma<<<gblocks, 256, 0, stream>>>(
        h, wbt + (size_t)18 * 16384, l1b, xf, N, MODE_BIAS | MODE_SSP_OUT);

    hipMemsetAsync(mols, 0, (size_t)NM * H_DIM * sizeof(float) + NM * sizeof(int), stream);
    mol_reduce<<<(N + MR_ATOMS - 1) / MR_ATOMS, 128, 0, stream>>>(
        xf, a2c, c2m, mols, cnt_m, N);
    head_kernel<<<NM, 128, 0, stream>>>(mols, cnt_m, l2w, l2b, hw1, hb1, hw2, hb2, out);
}

// Round 4
// 927.799 us; speedup vs baseline: 7.7866x; 1.5185x over previous
//
#include <hip/hip_runtime.h>
#include <hip/hip_bf16.h>
#include <math.h>

#define H_DIM   128
#define NF_DIM  128
#define G_DIM   50
#define L_LAYERS 6
#define TBL     2048
#define DMAX    12.8f
#define CUTOFF_C 10.0f
#define COEFF_C (-0.5f * 49.0f * 49.0f / 100.0f)
#define SCAN_B  256

typedef __bf16 bf16x8 __attribute__((ext_vector_type(8)));
typedef float  f32x4  __attribute__((ext_vector_type(4)));

__device__ __forceinline__ float sspf(float x) {
    return fmaxf(x, 0.0f) + log1pf(expf(-fabsf(x))) - 0.69314718055994530942f;
}

__device__ __forceinline__ unsigned short f2bf(float f) {
    unsigned int u = __float_as_uint(f);
    u = (u + 0x7fffu + ((u >> 16) & 1u)) >> 16;   // RNE
    return (unsigned short)u;
}

__device__ __forceinline__ float bf2f(unsigned short u) {
    return __uint_as_float(((unsigned int)u) << 16);
}

// ---------------------------------------------------------------- filter tables
__global__ __launch_bounds__(128) void build_tables(
        const float* __restrict__ w1, const float* __restrict__ b1,
        const float* __restrict__ w2, const float* __restrict__ b2,
        float* __restrict__ tab) {
    int l = blockIdx.x / TBL;
    int t = blockIdx.x % TBL;
    int f = threadIdx.x;  // 128
    float dt = t * (DMAX / (TBL - 1));
    __shared__ float gs[G_DIM];
    __shared__ float sy[NF_DIM];
    if (f < G_DIM) {
        float o = f * (CUTOFF_C / (G_DIM - 1));
        float dd = dt - o;
        gs[f] = expf(COEFF_C * dd * dd);
    }
    __syncthreads();
    const float* W1 = w1 + (size_t)l * G_DIM * NF_DIM;
    float y = b1[l * NF_DIM + f];
#pragma unroll 10
    for (int g = 0; g < G_DIM; ++g) y += gs[g] * W1[g * NF_DIM + f];
    sy[f] = sspf(y);
    __syncthreads();
    const float* W2 = w2 + (size_t)l * NF_DIM * NF_DIM;
    float y2 = b2[l * NF_DIM + f];
#pragma unroll 16
    for (int k = 0; k < NF_DIM; ++k) y2 += sy[k] * W2[k * NF_DIM + f];
    tab[((size_t)l * TBL + t) * NF_DIM + f] = y2;
}

// ---------------------------------------------------------------- embedding
__global__ __launch_bounds__(256) void embed_kernel(
        const int* __restrict__ z, const float* __restrict__ emb,
        float* __restrict__ h, int N) {
    int idx = blockIdx.x * blockDim.x + threadIdx.x;
    if (idx >= N * H_DIM) return;
    int n = idx >> 7, f = idx & 127;
    h[idx] = emb[z[n] * H_DIM + f];
}

// ---------------------------------------------------------------- weight prep
// MFMA B-fragment order: Bsw[((ks*8 + j)*64 + lane)*8 + jj] =
//   bf16( W[k = ks*32 + (lane>>4)*8 + jj][n = j*16 + (lane&15)] )
__global__ __launch_bounds__(256) void prep_wt_sw(
        const float* __restrict__ W, unsigned short* __restrict__ Bsw) {
    int m = blockIdx.x;
    const float* src = W + (size_t)m * 16384;
    unsigned short* dst = Bsw + (size_t)m * 16384;
    for (int i = threadIdx.x; i < 16384; i += 256) {
        int jj = i & 7, lane = (i >> 3) & 63, j = (i >> 9) & 7, ks = i >> 12;
        int n = j * 16 + (lane & 15);
        int k = ks * 32 + ((lane >> 4) & 3) * 8 + jj;
        dst[i] = f2bf(src[k * 128 + n]);
    }
}

// ---------------------------------------------------------------- CSR build
__global__ __launch_bounds__(256) void count_kernel(
        const int* __restrict__ ec, int* __restrict__ cnt, int E) {
    int e = blockIdx.x * blockDim.x + threadIdx.x;
    if (e < E) atomicAdd(&cnt[ec[e]], 1);
}

__global__ __launch_bounds__(SCAN_B) void scan1(
        const int* __restrict__ cnt, int* __restrict__ excl,
        int* __restrict__ bsums, int N) {
    __shared__ int s[SCAN_B];
    int i = blockIdx.x * SCAN_B + threadIdx.x;
    int v = (i < N) ? cnt[i] : 0;
    s[threadIdx.x] = v;
    __syncthreads();
    for (int off = 1; off < SCAN_B; off <<= 1) {
        int t = (threadIdx.x >= off) ? s[threadIdx.x - off] : 0;
        __syncthreads();
        s[threadIdx.x] += t;
        __syncthreads();
    }
    if (i < N) excl[i] = s[threadIdx.x] - v;
    if (threadIdx.x == SCAN_B - 1) bsums[blockIdx.x] = s[SCAN_B - 1];
}

__global__ __launch_bounds__(SCAN_B) void scan2(int* __restrict__ bsums, int nb) {
    __shared__ int s[SCAN_B];
    int v = (threadIdx.x < nb) ? bsums[threadIdx.x] : 0;
    s[threadIdx.x] = v;
    __syncthreads();
    for (int off = 1; off < SCAN_B; off <<= 1) {
        int t = (threadIdx.x >= off) ? s[threadIdx.x - off] : 0;
        __syncthreads();
        s[threadIdx.x] += t;
        __syncthreads();
    }
    if (threadIdx.x < nb) bsums[threadIdx.x] = s[threadIdx.x] - v;
}

__global__ __launch_bounds__(SCAN_B) void scan3(
        const int* __restrict__ excl, const int* __restrict__ bsums,
        int* __restrict__ row_start, int* __restrict__ cursor, int N, int E) {
    int i = blockIdx.x * SCAN_B + threadIdx.x;
    if (i < N) {
        int v = excl[i] + bsums[blockIdx.x];
        row_start[i] = v;
        cursor[i] = v;
    }
    if (i == 0) row_start[N] = E;
}

__global__ __launch_bounds__(256) void build_edges(
        const int* __restrict__ er, const int* __restrict__ ec,
        const float* __restrict__ pos, int* __restrict__ cursor,
        int4* __restrict__ edges, int E) {
    int e = blockIdx.x * blockDim.x + threadIdx.x;
    if (e >= E) return;
    int r = er[e], c = ec[e];
    float dx = pos[r * 3 + 0] - pos[c * 3 + 0];
    float dy = pos[r * 3 + 1] - pos[c * 3 + 1];
    float dz = pos[r * 3 + 2] - pos[c * 3 + 2];
    float d = sqrtf(dx * dx + dy * dy + dz * dz);
    float C = 0.5f * (cosf(d * (3.14159265358979323846f / CUTOFF_C)) + 1.0f);
    float t = fminf(d, DMAX) * ((TBL - 1) / DMAX);
    int i0 = (int)t;
    if (i0 > TBL - 2) i0 = TBL - 2;
    float fr = t - (float)i0;
    int pos_ = atomicAdd(&cursor[c], 1);
    edges[pos_] = make_int4(r, i0, __float_as_int(C * (1.0f - fr)),
                            __float_as_int(C * fr));
}

// ---------------------------------------------------------------- edge gather
// agg[i] = sum_j bf2f(xfb[row_j]) * (a*tab[i0] + b*tab[i0+1]); 32 lanes/atom
__global__ __launch_bounds__(256) void edge_agg(
        const int4* __restrict__ edges, const int* __restrict__ row_start,
        const unsigned short* __restrict__ xfb, const float* __restrict__ tab_l,
        float* __restrict__ agg, int N) {
    int tid = threadIdx.x;
    int atom = blockIdx.x * 8 + (tid >> 5);
    if (atom >= N) return;
    int f4 = (tid & 31) * 4;
    float4 acc = make_float4(0.f, 0.f, 0.f, 0.f);
    int j0 = row_start[atom], j1 = row_start[atom + 1];
    for (int j = j0; j < j1; ++j) {
        int4 ed = edges[j];
        int r = ed.x, i0 = ed.y;
        float a = __int_as_float(ed.z), b = __int_as_float(ed.w);
        const float4 w0 = *(const float4*)(tab_l + (size_t)i0 * NF_DIM + f4);
        const float4 w1 = *(const float4*)(tab_l + (size_t)(i0 + 1) * NF_DIM + f4);
        const ushort4 xu = *(const ushort4*)(xfb + (size_t)r * NF_DIM + f4);
        acc.x += bf2f(xu.x) * (a * w0.x + b * w1.x);
        acc.y += bf2f(xu.y) * (a * w0.y + b * w1.y);
        acc.z += bf2f(xu.z) * (a * w0.z + b * w1.z);
        acc.w += bf2f(xu.w) * (a * w0.w + b * w1.w);
    }
    *(float4*)(agg + (size_t)atom * NF_DIM + f4) = acc;
}

// ---------------------------------------------------------------- GEMM v2
// Out(M x 128) = A(M x 128) @ W(128x128); Bsw in MFMA-frag order (global).
// A staged fp32->bf16 into LDS in A-frag order (conflict-free both ways).
// Epilogue: fp32 transpose through LDS (stride 132) -> coalesced stores.
#define MODE_BIAS    1
#define MODE_SSP_OUT 2
#define MODE_OUT_BF16 4

__global__ __launch_bounds__(256, 4) void gemm_v2(
        const float* __restrict__ A, const unsigned short* __restrict__ Bsw,
        const float* __restrict__ bias, float* __restrict__ OutF,
        unsigned short* __restrict__ OutB, int M, int mode) {
    __shared__ __align__(16) float smem[64 * 132];     // 33.8 KB
    unsigned short* asw = (unsigned short*)smem;        // first 16 KB: A frags
    int tid = threadIdx.x;
    int m0 = blockIdx.x * 64;

    // stage A -> bf16 frags: group i = (ks, w, ln)
    for (int i = tid; i < 1024; i += 256) {
        int ks = i >> 8, w = (i >> 6) & 3, ln = i & 63;
        int row = m0 + w * 16 + (ln & 15);
        int kb = ks * 32 + (ln >> 4) * 8;
        unsigned short tmp[8];
        if (row < M) {
            const float* ap = A + (size_t)row * 128 + kb;
            float4 v0 = *(const float4*)ap;
            float4 v1 = *(const float4*)(ap + 4);
            tmp[0] = f2bf(v0.x); tmp[1] = f2bf(v0.y);
            tmp[2] = f2bf(v0.z); tmp[3] = f2bf(v0.w);
            tmp[4] = f2bf(v1.x); tmp[5] = f2bf(v1.y);
            tmp[6] = f2bf(v1.z); tmp[7] = f2bf(v1.w);
        } else {
#pragma unroll
            for (int j = 0; j < 8; ++j) tmp[j] = 0;
        }
        *(uint4*)(asw + (size_t)i * 8) = *(const uint4*)tmp;
    }
    __syncthreads();

    int w = tid >> 6, ln = tid & 63;
    int quad = ln >> 4, l15 = ln & 15;
    f32x4 acc[8] = {};
#pragma unroll
    for (int ks = 0; ks < 4; ++ks) {
        bf16x8 af = *(const bf16x8*)(asw + ((ks * 4 + w) * 64 + ln) * 8);
#pragma unroll
        for (int j = 0; j < 8; ++j) {
            bf16x8 bf = *(const bf16x8*)(Bsw + (((ks * 8 + j) * 64) + ln) * 8);
            acc[j] = __builtin_amdgcn_mfma_f32_16x16x32_bf16(af, bf, acc[j], 0, 0, 0);
        }
    }
    __syncthreads();

    // C-layout -> row-major fp32 staging (+bias)
#pragma unroll
    for (int j = 0; j < 8; ++j) {
        int col = j * 16 + l15;
        float bv = (mode & MODE_BIAS) ? bias[col] : 0.f;
#pragma unroll
        for (int r = 0; r < 4; ++r)
            smem[(w * 16 + quad * 4 + r) * 132 + col] = acc[j][r] + bv;
    }
    __syncthreads();

    for (int i = tid; i < 2048; i += 256) {
        int row = i >> 5, c4 = (i & 31) * 4;
        int grow = m0 + row;
        if (grow >= M) continue;
        float4 v = *(const float4*)(smem + row * 132 + c4);
        if (mode & MODE_SSP_OUT) {
            v.x = sspf(v.x); v.y = sspf(v.y); v.z = sspf(v.z); v.w = sspf(v.w);
        }
        if (mode & MODE_OUT_BF16) {
            unsigned short o[4] = {f2bf(v.x), f2bf(v.y), f2bf(v.z), f2bf(v.w)};
            *(uint2*)(OutB + (size_t)grow * 128 + c4) = *(const uint2*)o;
        } else {
            *(float4*)(OutF + (size_t)grow * 128 + c4) = v;
        }
    }
}

// ---------------------------------------------------------------- fused conv2+int
// t1 = agg @ c2w + c2b;  h += ssp(t1) @ iw + ib   (t1 never leaves the block)
__global__ __launch_bounds__(256, 3) void fused23(
        const float* __restrict__ agg, const unsigned short* __restrict__ B1sw,
        const float* __restrict__ b1v, const unsigned short* __restrict__ B2sw,
        const float* __restrict__ b2v, float* __restrict__ h, int M) {
    __shared__ __align__(16) float smem[64 * 132];
    unsigned short* asw = (unsigned short*)smem;
    int tid = threadIdx.x;
    int m0 = blockIdx.x * 64;

    for (int i = tid; i < 1024; i += 256) {
        int ks = i >> 8, w = (i >> 6) & 3, ln = i & 63;
        int row = m0 + w * 16 + (ln & 15);
        int kb = ks * 32 + (ln >> 4) * 8;
        unsigned short tmp[8];
        if (row < M) {
            const float* ap = agg + (size_t)row * 128 + kb;
            float4 v0 = *(const float4*)ap;
            float4 v1 = *(const float4*)(ap + 4);
            tmp[0] = f2bf(v0.x); tmp[1] = f2bf(v0.y);
            tmp[2] = f2bf(v0.z); tmp[3] = f2bf(v0.w);
            tmp[4] = f2bf(v1.x); tmp[5] = f2bf(v1.y);
            tmp[6] = f2bf(v1.z); tmp[7] = f2bf(v1.w);
        } else {
#pragma unroll
            for (int j = 0; j < 8; ++j) tmp[j] = 0;
        }
        *(uint4*)(asw + (size_t)i * 8) = *(const uint4*)tmp;
    }
    __syncthreads();

    int w = tid >> 6, ln = tid & 63;
    int quad = ln >> 4, l15 = ln & 15;
    f32x4 acc[8] = {};
#pragma unroll
    for (int ks = 0; ks < 4; ++ks) {
        bf16x8 af = *(const bf16x8*)(asw + ((ks * 4 + w) * 64 + ln) * 8);
#pragma unroll
        for (int j = 0; j < 8; ++j) {
            bf16x8 bf = *(const bf16x8*)(B1sw + (((ks * 8 + j) * 64) + ln) * 8);
            acc[j] = __builtin_amdgcn_mfma_f32_16x16x32_bf16(af, bf, acc[j], 0, 0, 0);
        }
    }
    __syncthreads();   // done reading agg frags

    // repack: ssp(t1) -> bf16 A-frags (C-layout -> A-frag layout, in-wave rows)
#pragma unroll
    for (int j = 0; j < 8; ++j) {
        int col = j * 16 + l15;
        float bv = b1v[col];
        int ks2 = j >> 1;
        int quad2 = (col >> 3) & 3;
        int jj = col & 7;
#pragma unroll
        for (int r = 0; r < 4; ++r) {
            float s = sspf(acc[j][r] + bv);
            int lane2 = quad2 * 16 + quad * 4 + r;
            asw[((ks2 * 4 + w) * 64 + lane2) * 8 + jj] = f2bf(s);
        }
    }
    __syncthreads();

    f32x4 acc2[8] = {};
#pragma unroll
    for (int ks = 0; ks < 4; ++ks) {
        bf16x8 af = *(const bf16x8*)(asw + ((ks * 4 + w) * 64 + ln) * 8);
#pragma unroll
        for (int j = 0; j < 8; ++j) {
            bf16x8 bf = *(const bf16x8*)(B2sw + (((ks * 8 + j) * 64) + ln) * 8);
            acc2[j] = __builtin_amdgcn_mfma_f32_16x16x32_bf16(af, bf, acc2[j], 0, 0, 0);
        }
    }
    __syncthreads();

#pragma unroll
    for (int j = 0; j < 8; ++j) {
        int col = j * 16 + l15;
        float bv = b2v[col];
#pragma unroll
        for (int r = 0; r < 4; ++r)
            smem[(w * 16 + quad * 4 + r) * 132 + col] = acc2[j][r] + bv;
    }
    __syncthreads();

    for (int i = tid; i < 2048; i += 256) {
        int row = i >> 5, c4 = (i & 31) * 4;
        int grow = m0 + row;
        if (grow >= M) continue;
        float* hp = h + (size_t)grow * 128 + c4;
        float4 v = *(const float4*)(smem + row * 132 + c4);
        float4 o = *(const float4*)hp;
        v.x += o.x; v.y += o.y; v.z += o.z; v.w += o.w;
        *(float4*)hp = v;
    }
}

// ---------------------------------------------------------------- atom -> mol sum
#define MR_ATOMS 32
__global__ __launch_bounds__(128) void mol_reduce(
        const float* __restrict__ s, const int* __restrict__ a2c,
        const int* __restrict__ c2m, float* __restrict__ mols,
        int* __restrict__ cnt, int N) {
    int f = threadIdx.x;
    int a0 = blockIdx.x * MR_ATOMS;
    int a1 = min(a0 + MR_ATOMS, N);
    float sum = 0.f;
    int cur = -1, run = 0;
    for (int a = a0; a < a1; ++a) {
        int m = c2m[a2c[a]];
        if (m != cur) {
            if (cur >= 0) {
                unsafeAtomicAdd(&mols[(size_t)cur * H_DIM + f], sum);
                if (f == 0) atomicAdd(&cnt[cur], run);
            }
            cur = m; sum = 0.f; run = 0;
        }
        sum += s[(size_t)a * H_DIM + f];
        ++run;
    }
    if (cur >= 0) {
        unsafeAtomicAdd(&mols[(size_t)cur * H_DIM + f], sum);
        if (f == 0) atomicAdd(&cnt[cur], run);
    }
}

// ---------------------------------------------------------------- head
__global__ __launch_bounds__(128) void head_kernel(
        const float* __restrict__ mols, const int* __restrict__ cnt,
        const float* __restrict__ l2w, const float* __restrict__ l2b,
        const float* __restrict__ hw1, const float* __restrict__ hb1,
        const float* __restrict__ hw2, const float* __restrict__ hb2,
        float* __restrict__ out) {
    int m = blockIdx.x, f = threadIdx.x;
    __shared__ float me[H_DIM];
    __shared__ float u[H_DIM / 2];
    const float* ms = mols + (size_t)m * H_DIM;
    float acc = l2b[f] * (float)cnt[m];
#pragma unroll 16
    for (int k = 0; k < H_DIM; ++k) acc += ms[k] * l2w[k * H_DIM + f];
    me[f] = acc;
    __syncthreads();
    if (f < 64) {
        float a2 = hb1[f];
#pragma unroll 16
        for (int k = 0; k < H_DIM; ++k) a2 += me[k] * hw1[k * 64 + f];
        u[f] = sspf(a2);
    }
    __syncthreads();
    if (f == 0) {
        float o = hb2[0];
#pragma unroll 16
        for (int j = 0; j < 64; ++j) o += u[j] * hw2[j];
        out[m] = o;
    }
}

// ---------------------------------------------------------------- launch
extern "C" void kernel_launch(void* const* d_in, const int* in_sizes, int n_in,
                              void* d_out, int out_size, void* d_ws, size_t ws_size,
                              hipStream_t stream) {
    const int*   z   = (const int*)d_in[0];
    const float* pos = (const float*)d_in[1];
    const int*   er  = (const int*)d_in[2];
    const int*   ec  = (const int*)d_in[3];
    const int*   a2c = (const int*)d_in[4];
    const int*   c2m = (const int*)d_in[5];
    const float* emb = (const float*)d_in[6];
    const float* w1  = (const float*)d_in[7];
    const float* b1  = (const float*)d_in[8];
    const float* w2  = (const float*)d_in[9];
    const float* b2  = (const float*)d_in[10];
    const float* c1w = (const float*)d_in[11];
    const float* c2w = (const float*)d_in[12];
    const float* c2b = (const float*)d_in[13];
    const float* iw  = (const float*)d_in[14];
    const float* ib  = (const float*)d_in[15];
    const float* l1w = (const float*)d_in[16];
    const float* l1b = (const float*)d_in[17];
    const float* l2w = (const float*)d_in[18];
    const float* l2b = (const float*)d_in[19];
    const float* hw1 = (const float*)d_in[20];
    const float* hb1 = (const float*)d_in[21];
    const float* hw2 = (const float*)d_in[22];
    const float* hb2 = (const float*)d_in[23];

    const int N  = in_sizes[0];
    const int E  = in_sizes[2];
    const int NM = out_size;
    float* out = (float*)d_out;

    // workspace layout (~94 MB)
    char* wsp = (char*)d_ws;
    int4*  edges = (int4*)wsp;            wsp += (size_t)E * sizeof(int4);
    float* tab   = (float*)wsp;           wsp += (size_t)L_LAYERS * TBL * NF_DIM * 4;
    unsigned short* wbt = (unsigned short*)wsp;  wsp += (size_t)19 * 16384 * 2;
    float* h     = (float*)wsp;           wsp += (size_t)N * H_DIM * 4;
    float* xf    = (float*)wsp;           wsp += (size_t)N * H_DIM * 4;  // fp32 alias
    float* agg   = (float*)wsp;           wsp += (size_t)N * H_DIM * 4;
    float* mols  = (float*)wsp;           wsp += (size_t)NM * H_DIM * 4;
    int*   cnt_m = (int*)wsp;             wsp += (size_t)NM * 4;
    int*   ccnt  = (int*)wsp;             wsp += (size_t)N * 4;
    int*   row_start = (int*)wsp;         wsp += (size_t)(N + 1) * 4;
    int*   cursor = (int*)wsp;            wsp += (size_t)N * 4;
    int*   bsums  = (int*)wsp;            wsp += 256 * 4;
    int*   excl   = (int*)wsp;
    unsigned short* xfb = (unsigned short*)xf;   // bf16 view for layer xf

    // --- CSR build (edges fixed across layers) ---
    hipMemsetAsync(ccnt, 0, (size_t)N * sizeof(int), stream);
    count_kernel<<<(E + 255) / 256, 256, 0, stream>>>(ec, ccnt, E);
    int nb = (N + SCAN_B - 1) / SCAN_B;
    scan1<<<nb, SCAN_B, 0, stream>>>(ccnt, excl, bsums, N);
    scan2<<<1, SCAN_B, 0, stream>>>(bsums, nb);
    scan3<<<nb, SCAN_B, 0, stream>>>(excl, bsums, row_start, cursor, N, E);
    build_edges<<<(E + 255) / 256, 256, 0, stream>>>(er, ec, pos, cursor, edges, E);

    build_tables<<<L_LAYERS * TBL, 128, 0, stream>>>(w1, b1, w2, b2, tab);
    embed_kernel<<<(N * H_DIM + 255) / 256, 256, 0, stream>>>(z, emb, h, N);

    // --- weight prep: bf16 in MFMA B-fragment order ---
    prep_wt_sw<<<L_LAYERS, 256, 0, stream>>>(c1w, wbt);
    prep_wt_sw<<<L_LAYERS, 256, 0, stream>>>(c2w, wbt + (size_t)6 * 16384);
    prep_wt_sw<<<L_LAYERS, 256, 0, stream>>>(iw,  wbt + (size_t)12 * 16384);
    prep_wt_sw<<<1,        256, 0, stream>>>(l1w, wbt + (size_t)18 * 16384);

    int gblocks = (N + 63) / 64;
    for (int l = 0; l < L_LAYERS; ++l) {
        // xf(bf16) = h @ conv_lin1_w[l]
        gemm_v2<<<gblocks, 256, 0, stream>>>(
            h, wbt + (size_t)l * 16384, nullptr, nullptr, xfb, N, MODE_OUT_BF16);
        // agg = gather(xf * W(d) * C)
        edge_agg<<<(N + 7) / 8, 256, 0, stream>>>(
            edges, row_start, xfb, tab + (size_t)l * TBL * NF_DIM, agg, N);
        // h += ssp(agg @ c2w + c2b) @ iw + ib   (fused, t1 on-chip)
        fused23<<<gblocks, 256, 0, stream>>>(
            agg, wbt + (size_t)(6 + l) * 16384, c2b + (size_t)l * H_DIM,
            wbt + (size_t)(12 + l) * 16384, ib + (size_t)l * H_DIM, h, N);
    }
    // s = ssp(h @ lin1_w + b1)  (fp32, into xf buffer)
    gemm_v2<<<gblocks, 256, 0, stream>>>(
        h, wbt + (size_t)18 * 16384, l1b, xf, nullptr, N,
        MODE_BIAS | MODE_SSP_OUT);

    hipMemsetAsync(mols, 0, (size_t)NM * H_DIM * sizeof(float) + NM * sizeof(int), stream);
    mol_reduce<<<(N + MR_ATOMS - 1) / MR_ATOMS, 128, 0, stream>>>(
        xf, a2c, c2m, mols, cnt_m, N);
    head_kernel<<<NM, 128, 0, stream>>>(mols, cnt_m, l2w, l2b, hw1, hb1, hw2, hb2, out);
}

// Round 5
// 898.578 us; speedup vs baseline: 8.0398x; 1.0325x over previous
//
#include <hip/hip_runtime.h>
#include <hip/hip_bf16.h>
#include <hip/hip_fp16.h>
#include <math.h>

#define H_DIM   128
#define NF_DIM  128
#define G_DIM   50
#define L_LAYERS 6
#define TBL     2048
#define DMAX    12.8f
#define CUTOFF_C 10.0f
#define COEFF_C (-0.5f * 49.0f * 49.0f / 100.0f)
#define SCAN_B  256
#define T_PER   16

typedef __bf16 bf16x8 __attribute__((ext_vector_type(8)));
typedef float  f32x4  __attribute__((ext_vector_type(4)));

__device__ __forceinline__ float sspf(float x) {
    return fmaxf(x, 0.0f) + log1pf(expf(-fabsf(x))) - 0.69314718055994530942f;
}

__device__ __forceinline__ unsigned short f2bf(float f) {
    unsigned int u = __float_as_uint(f);
    u = (u + 0x7fffu + ((u >> 16) & 1u)) >> 16;   // RNE
    return (unsigned short)u;
}

__device__ __forceinline__ float bf2f(unsigned short u) {
    return __uint_as_float(((unsigned int)u) << 16);
}

// ---------------------------------------------------------------- filter tables
// 16 table rows per block; W1 staged to LDS, W2 rows broadcast across 16 accums.
__global__ __launch_bounds__(128) void build_tables(
        const float* __restrict__ w1, const float* __restrict__ b1,
        const float* __restrict__ w2, const float* __restrict__ b2,
        float* __restrict__ tab) {
    int l  = blockIdx.x / (TBL / T_PER);
    int t0 = (blockIdx.x % (TBL / T_PER)) * T_PER;
    int f  = threadIdx.x;  // 128
    __shared__ float sW1[G_DIM * 128];        // 25.6 KB
    __shared__ float gs[T_PER][G_DIM + 2];    // 3.3 KB
    __shared__ float sy[T_PER][130];          // 8.3 KB
    for (int i = f; i < G_DIM * 128; i += 128)
        sW1[i] = w1[(size_t)l * G_DIM * 128 + i];
    if (f < G_DIM) {
        float o = f * (CUTOFF_C / (G_DIM - 1));
#pragma unroll
        for (int u = 0; u < T_PER; ++u) {
            float dt = (t0 + u) * (DMAX / (TBL - 1));
            float dd = dt - o;
            gs[u][f] = expf(COEFF_C * dd * dd);
        }
    }
    __syncthreads();
    float y[T_PER];
    float bb = b1[l * 128 + f];
#pragma unroll
    for (int u = 0; u < T_PER; ++u) y[u] = bb;
    for (int g = 0; g < G_DIM; ++g) {
        float wv = sW1[g * 128 + f];
#pragma unroll
        for (int u = 0; u < T_PER; ++u) y[u] += gs[u][g] * wv;
    }
#pragma unroll
    for (int u = 0; u < T_PER; ++u) sy[u][f] = sspf(y[u]);
    __syncthreads();
    float acc[T_PER];
    float b2v = b2[l * 128 + f];
#pragma unroll
    for (int u = 0; u < T_PER; ++u) acc[u] = b2v;
    const float* W2 = w2 + (size_t)l * 16384;
    for (int k = 0; k < 128; ++k) {
        float wv = W2[k * 128 + f];
#pragma unroll
        for (int u = 0; u < T_PER; ++u) acc[u] += sy[u][k] * wv;
    }
#pragma unroll
    for (int u = 0; u < T_PER; ++u)
        tab[((size_t)l * TBL + t0 + u) * 128 + f] = acc[u];
}

// ---------------------------------------------------------------- embedding
__global__ __launch_bounds__(256) void embed_kernel(
        const int* __restrict__ z, const float* __restrict__ emb,
        float* __restrict__ h, int N) {
    int idx = blockIdx.x * blockDim.x + threadIdx.x;
    if (idx >= N * H_DIM) return;
    int n = idx >> 7, f = idx & 127;
    h[idx] = emb[z[n] * H_DIM + f];
}

// ---------------------------------------------------------------- weight prep
// MFMA B-fragment order: Bsw[((ks*8 + j)*64 + lane)*8 + jj] =
//   bf16( W[k = ks*32 + (lane>>4)*8 + jj][n = j*16 + (lane&15)] )
__global__ __launch_bounds__(256) void prep_wt_sw(
        const float* __restrict__ W, unsigned short* __restrict__ Bsw) {
    int m = blockIdx.x;
    const float* src = W + (size_t)m * 16384;
    unsigned short* dst = Bsw + (size_t)m * 16384;
    for (int i = threadIdx.x; i < 16384; i += 256) {
        int jj = i & 7, lane = (i >> 3) & 63, j = (i >> 9) & 7, ks = i >> 12;
        int n = j * 16 + (lane & 15);
        int k = ks * 32 + ((lane >> 4) & 3) * 8 + jj;
        dst[i] = f2bf(src[k * 128 + n]);
    }
}

// ---------------------------------------------------------------- CSR build
__global__ __launch_bounds__(256) void count_kernel(
        const int* __restrict__ ec, int* __restrict__ cnt, int E) {
    int e = blockIdx.x * blockDim.x + threadIdx.x;
    if (e < E) atomicAdd(&cnt[ec[e]], 1);
}

__global__ __launch_bounds__(SCAN_B) void scan1(
        const int* __restrict__ cnt, int* __restrict__ excl,
        int* __restrict__ bsums, int N) {
    __shared__ int s[SCAN_B];
    int i = blockIdx.x * SCAN_B + threadIdx.x;
    int v = (i < N) ? cnt[i] : 0;
    s[threadIdx.x] = v;
    __syncthreads();
    for (int off = 1; off < SCAN_B; off <<= 1) {
        int t = (threadIdx.x >= off) ? s[threadIdx.x - off] : 0;
        __syncthreads();
        s[threadIdx.x] += t;
        __syncthreads();
    }
    if (i < N) excl[i] = s[threadIdx.x] - v;
    if (threadIdx.x == SCAN_B - 1) bsums[blockIdx.x] = s[SCAN_B - 1];
}

__global__ __launch_bounds__(SCAN_B) void scan2(int* __restrict__ bsums, int nb) {
    __shared__ int s[SCAN_B];
    int v = (threadIdx.x < nb) ? bsums[threadIdx.x] : 0;
    s[threadIdx.x] = v;
    __syncthreads();
    for (int off = 1; off < SCAN_B; off <<= 1) {
        int t = (threadIdx.x >= off) ? s[threadIdx.x - off] : 0;
        __syncthreads();
        s[threadIdx.x] += t;
        __syncthreads();
    }
    if (threadIdx.x < nb) bsums[threadIdx.x] = s[threadIdx.x] - v;
}

__global__ __launch_bounds__(SCAN_B) void scan3(
        const int* __restrict__ excl, const int* __restrict__ bsums,
        int* __restrict__ row_start, int* __restrict__ cursor, int N, int E) {
    int i = blockIdx.x * SCAN_B + threadIdx.x;
    if (i < N) {
        int v = excl[i] + bsums[blockIdx.x];
        row_start[i] = v;
        cursor[i] = v;
    }
    if (i == 0) row_start[N] = E;
}

// 8-byte edge record: {row | (i0<<17), half2(C*(1-fr), C*fr)}
__global__ __launch_bounds__(256) void build_edges(
        const int* __restrict__ er, const int* __restrict__ ec,
        const float* __restrict__ pos, int* __restrict__ cursor,
        uint2* __restrict__ ebuf, int E) {
    int e = blockIdx.x * blockDim.x + threadIdx.x;
    if (e >= E) return;
    int r = er[e], c = ec[e];
    float dx = pos[r * 3 + 0] - pos[c * 3 + 0];
    float dy = pos[r * 3 + 1] - pos[c * 3 + 1];
    float dz = pos[r * 3 + 2] - pos[c * 3 + 2];
    float d = sqrtf(dx * dx + dy * dy + dz * dz);
    float C = 0.5f * (cosf(d * (3.14159265358979323846f / CUTOFF_C)) + 1.0f);
    float t = fminf(d, DMAX) * ((TBL - 1) / DMAX);
    int i0 = (int)t;
    if (i0 > TBL - 2) i0 = TBL - 2;
    float fr = t - (float)i0;
    __half2 abh = __floats2half2_rn(C * (1.0f - fr), C * fr);
    int pos_ = atomicAdd(&cursor[c], 1);
    ebuf[pos_] = make_uint2((unsigned)r | ((unsigned)i0 << 17),
                            *(unsigned*)&abh);
}

// ---------------------------------------------------------------- edge gather
// aggb[i] = bf16( sum_j xfb[row_j] * (a*tab[i0] + b*tab[i0+1]) ); 32 lanes/atom
__global__ __launch_bounds__(256) void edge_agg(
        const uint2* __restrict__ ebuf, const int* __restrict__ row_start,
        const unsigned short* __restrict__ xfb, const float* __restrict__ tab_l,
        unsigned short* __restrict__ aggb, int N) {
    int tid = threadIdx.x;
    int atom = blockIdx.x * 8 + (tid >> 5);
    if (atom >= N) return;
    int f4 = (tid & 31) * 4;
    float4 acc = make_float4(0.f, 0.f, 0.f, 0.f);
    int j0 = row_start[atom], j1 = row_start[atom + 1];
    if (j0 < j1) {
        uint2 ed = ebuf[j0];
        for (int j = j0; j < j1; ++j) {
            uint2 edn = ebuf[(j + 1 < j1) ? (j + 1) : j];  // prefetch next
            int r  = ed.x & 0x1ffff;
            int i0 = ed.x >> 17;
            __half2 abh = *(__half2*)&ed.y;
            float2 ab = __half22float2(abh);
            const float4 w0 = *(const float4*)(tab_l + (size_t)i0 * 128 + f4);
            const float4 w1 = *(const float4*)(tab_l + ((size_t)i0 + 1) * 128 + f4);
            const ushort4 xu = *(const ushort4*)(xfb + (size_t)r * 128 + f4);
            acc.x += bf2f(xu.x) * (ab.x * w0.x + ab.y * w1.x);
            acc.y += bf2f(xu.y) * (ab.x * w0.y + ab.y * w1.y);
            acc.z += bf2f(xu.z) * (ab.x * w0.z + ab.y * w1.z);
            acc.w += bf2f(xu.w) * (ab.x * w0.w + ab.y * w1.w);
            ed = edn;
        }
    }
    unsigned short o[4] = {f2bf(acc.x), f2bf(acc.y), f2bf(acc.z), f2bf(acc.w)};
    *(uint2*)(aggb + (size_t)atom * 128 + f4) = *(const uint2*)o;
}

// ---------------------------------------------------------------- GEMM v2 (layer-0 xf)
#define MODE_BIAS     1
#define MODE_SSP_OUT  2
#define MODE_OUT_BF16 4

__global__ __launch_bounds__(256, 4) void gemm_v2(
        const float* __restrict__ A, const unsigned short* __restrict__ Bsw,
        const float* __restrict__ bias, float* __restrict__ OutF,
        unsigned short* __restrict__ OutB, int M, int mode) {
    __shared__ __align__(16) float smem[64 * 132];
    unsigned short* asw = (unsigned short*)smem;
    int tid = threadIdx.x;
    int m0 = blockIdx.x * 64;

    for (int i = tid; i < 1024; i += 256) {
        int ks = i >> 8, w = (i >> 6) & 3, ln = i & 63;
        int row = m0 + w * 16 + (ln & 15);
        int kb = ks * 32 + (ln >> 4) * 8;
        unsigned short tmp[8];
        if (row < M) {
            const float* ap = A + (size_t)row * 128 + kb;
            float4 v0 = *(const float4*)ap;
            float4 v1 = *(const float4*)(ap + 4);
            tmp[0] = f2bf(v0.x); tmp[1] = f2bf(v0.y);
            tmp[2] = f2bf(v0.z); tmp[3] = f2bf(v0.w);
            tmp[4] = f2bf(v1.x); tmp[5] = f2bf(v1.y);
            tmp[6] = f2bf(v1.z); tmp[7] = f2bf(v1.w);
        } else {
#pragma unroll
            for (int j = 0; j < 8; ++j) tmp[j] = 0;
        }
        *(uint4*)(asw + (size_t)i * 8) = *(const uint4*)tmp;
    }
    __syncthreads();

    int w = tid >> 6, ln = tid & 63;
    int quad = ln >> 4, l15 = ln & 15;
    f32x4 acc[8] = {};
#pragma unroll
    for (int ks = 0; ks < 4; ++ks) {
        bf16x8 af = *(const bf16x8*)(asw + ((ks * 4 + w) * 64 + ln) * 8);
#pragma unroll
        for (int j = 0; j < 8; ++j) {
            bf16x8 bf = *(const bf16x8*)(Bsw + (((ks * 8 + j) * 64) + ln) * 8);
            acc[j] = __builtin_amdgcn_mfma_f32_16x16x32_bf16(af, bf, acc[j], 0, 0, 0);
        }
    }
    __syncthreads();

#pragma unroll
    for (int j = 0; j < 8; ++j) {
        int col = j * 16 + l15;
        float bv = (mode & MODE_BIAS) ? bias[col] : 0.f;
#pragma unroll
        for (int r = 0; r < 4; ++r)
            smem[(w * 16 + quad * 4 + r) * 132 + col] = acc[j][r] + bv;
    }
    __syncthreads();

    for (int i = tid; i < 2048; i += 256) {
        int row = i >> 5, c4 = (i & 31) * 4;
        int grow = m0 + row;
        if (grow >= M) continue;
        float4 v = *(const float4*)(smem + row * 132 + c4);
        if (mode & MODE_SSP_OUT) {
            v.x = sspf(v.x); v.y = sspf(v.y); v.z = sspf(v.z); v.w = sspf(v.w);
        }
        if (mode & MODE_OUT_BF16) {
            unsigned short o[4] = {f2bf(v.x), f2bf(v.y), f2bf(v.z), f2bf(v.w)};
            *(uint2*)(OutB + (size_t)grow * 128 + c4) = *(const uint2*)o;
        } else {
            *(float4*)(OutF + (size_t)grow * 128 + c4) = v;
        }
    }
}

// ---------------------------------------------------------------- fused layer
// t1 = aggb @ c2w + c2b;  x = ssp(t1) @ iw + ib;  h += x;
// then: xfb_next = bf16(h @ B3)          (mid layers, B3 = next conv1, no bias)
//   or: s_out   = ssp(h @ B3 + b3)       (last layer, B3 = lin1)
__global__ __launch_bounds__(256, 3) void fused_layer(
        const unsigned short* __restrict__ aggb,
        const unsigned short* __restrict__ B1sw, const float* __restrict__ b1v,
        const unsigned short* __restrict__ B2sw, const float* __restrict__ b2v,
        const unsigned short* __restrict__ B3sw, const float* __restrict__ b3v,
        float* __restrict__ h, unsigned short* __restrict__ xfb_next,
        float* __restrict__ s_out, int M, int last) {
    __shared__ __align__(16) float smem[64 * 132];        // 33.8 KB
    __shared__ __align__(16) unsigned short asw2[8192];   // 16 KB
    unsigned short* asw = (unsigned short*)smem;
    int tid = threadIdx.x;
    int m0 = blockIdx.x * 64;

    // 1. stage aggb rows (already bf16, A-frag chunks are contiguous 16B)
    for (int i = tid; i < 1024; i += 256) {
        int ks = i >> 8, w_ = (i >> 6) & 3, ln_ = i & 63;
        int row = m0 + w_ * 16 + (ln_ & 15);
        int kb = ks * 32 + (ln_ >> 4) * 8;
        uint4 v = make_uint4(0, 0, 0, 0);
        if (row < M) v = *(const uint4*)(aggb + (size_t)row * 128 + kb);
        *(uint4*)(asw + (size_t)i * 8) = v;
    }
    __syncthreads();

    int w = tid >> 6, ln = tid & 63;
    int quad = ln >> 4, l15 = ln & 15;

    // 2. conv2 MFMA
    f32x4 acc[8] = {};
#pragma unroll
    for (int ks = 0; ks < 4; ++ks) {
        bf16x8 af = *(const bf16x8*)(asw + ((ks * 4 + w) * 64 + ln) * 8);
#pragma unroll
        for (int j = 0; j < 8; ++j) {
            bf16x8 bf = *(const bf16x8*)(B1sw + (((ks * 8 + j) * 64) + ln) * 8);
            acc[j] = __builtin_amdgcn_mfma_f32_16x16x32_bf16(af, bf, acc[j], 0, 0, 0);
        }
    }
    __syncthreads();

    // 3. repack ssp(t1 + b1) -> A-frags
#pragma unroll
    for (int j = 0; j < 8; ++j) {
        int col = j * 16 + l15;
        float bv = b1v[col];
        int ks2 = j >> 1;
        int quad2 = (col >> 3) & 3;
        int jj = col & 7;
#pragma unroll
        for (int r = 0; r < 4; ++r) {
            float s = sspf(acc[j][r] + bv);
            int lane2 = quad2 * 16 + quad * 4 + r;
            asw[((ks2 * 4 + w) * 64 + lane2) * 8 + jj] = f2bf(s);
        }
    }
    __syncthreads();

    // 4. int_lin MFMA
    f32x4 acc2[8] = {};
#pragma unroll
    for (int ks = 0; ks < 4; ++ks) {
        bf16x8 af = *(const bf16x8*)(asw + ((ks * 4 + w) * 64 + ln) * 8);
#pragma unroll
        for (int j = 0; j < 8; ++j) {
            bf16x8 bf = *(const bf16x8*)(B2sw + (((ks * 8 + j) * 64) + ln) * 8);
            acc2[j] = __builtin_amdgcn_mfma_f32_16x16x32_bf16(af, bf, acc2[j], 0, 0, 0);
        }
    }
    __syncthreads();   // asw (smem) reads done

    // 5. stage x = acc2 + b2 (fp32, stride 132)
#pragma unroll
    for (int j = 0; j < 8; ++j) {
        int col = j * 16 + l15;
        float bv = b2v[col];
#pragma unroll
        for (int r = 0; r < 4; ++r)
            smem[(w * 16 + quad * 4 + r) * 132 + col] = acc2[j][r] + bv;
    }
    __syncthreads();

    // 6. h += x (coalesced), and write bf16(h_new) into asw2 A-frags
    for (int i = tid; i < 2048; i += 256) {
        int row = i >> 5, c4 = (i & 31) * 4;
        int grow = m0 + row;
        float4 v = *(const float4*)(smem + row * 132 + c4);
        if (grow < M) {
            float* hp = h + (size_t)grow * 128 + c4;
            float4 o = *(const float4*)hp;
            v.x += o.x; v.y += o.y; v.z += o.z; v.w += o.w;
            *(float4*)hp = v;
        } else {
            v = make_float4(0.f, 0.f, 0.f, 0.f);
        }
        unsigned short t4[4] = {f2bf(v.x), f2bf(v.y), f2bf(v.z), f2bf(v.w)};
        int w_ = row >> 4, l15_ = row & 15;
        int ks = c4 >> 5, q_ = (c4 >> 3) & 3, jj = c4 & 7;
        *(uint2*)(asw2 + ((size_t)((ks * 4 + w_) * 64 + q_ * 16 + l15_)) * 8 + jj) =
            *(const uint2*)t4;
    }
    __syncthreads();

    // 7. next-layer conv1 (or lin1) MFMA
    f32x4 acc3[8] = {};
#pragma unroll
    for (int ks = 0; ks < 4; ++ks) {
        bf16x8 af = *(const bf16x8*)(asw2 + ((ks * 4 + w) * 64 + ln) * 8);
#pragma unroll
        for (int j = 0; j < 8; ++j) {
            bf16x8 bf = *(const bf16x8*)(B3sw + (((ks * 8 + j) * 64) + ln) * 8);
            acc3[j] = __builtin_amdgcn_mfma_f32_16x16x32_bf16(af, bf, acc3[j], 0, 0, 0);
        }
    }

    // 8. stage acc3 (+bias if last); smem free since step-6 sync
#pragma unroll
    for (int j = 0; j < 8; ++j) {
        int col = j * 16 + l15;
        float bv = last ? b3v[col] : 0.f;
#pragma unroll
        for (int r = 0; r < 4; ++r)
            smem[(w * 16 + quad * 4 + r) * 132 + col] = acc3[j][r] + bv;
    }
    __syncthreads();

    // 9. write xfb_next (bf16) or s_out (ssp, fp32)
    for (int i = tid; i < 2048; i += 256) {
        int row = i >> 5, c4 = (i & 31) * 4;
        int grow = m0 + row;
        if (grow >= M) continue;
        float4 v = *(const float4*)(smem + row * 132 + c4);
        if (last) {
            v.x = sspf(v.x); v.y = sspf(v.y); v.z = sspf(v.z); v.w = sspf(v.w);
            *(float4*)(s_out + (size_t)grow * 128 + c4) = v;
        } else {
            unsigned short o[4] = {f2bf(v.x), f2bf(v.y), f2bf(v.z), f2bf(v.w)};
            *(uint2*)(xfb_next + (size_t)grow * 128 + c4) = *(const uint2*)o;
        }
    }
}

// ---------------------------------------------------------------- atom -> mol sum
#define MR_ATOMS 32
__global__ __launch_bounds__(128) void mol_reduce(
        const float* __restrict__ s, const int* __restrict__ a2c,
        const int* __restrict__ c2m, float* __restrict__ mols,
        int* __restrict__ cnt, int N) {
    int f = threadIdx.x;
    int a0 = blockIdx.x * MR_ATOMS;
    int a1 = min(a0 + MR_ATOMS, N);
    float sum = 0.f;
    int cur = -1, run = 0;
    for (int a = a0; a < a1; ++a) {
        int m = c2m[a2c[a]];
        if (m != cur) {
            if (cur >= 0) {
                unsafeAtomicAdd(&mols[(size_t)cur * H_DIM + f], sum);
                if (f == 0) atomicAdd(&cnt[cur], run);
            }
            cur = m; sum = 0.f; run = 0;
        }
        sum += s[(size_t)a * H_DIM + f];
        ++run;
    }
    if (cur >= 0) {
        unsafeAtomicAdd(&mols[(size_t)cur * H_DIM + f], sum);
        if (f == 0) atomicAdd(&cnt[cur], run);
    }
}

// ---------------------------------------------------------------- head
__global__ __launch_bounds__(128) void head_kernel(
        const float* __restrict__ mols, const int* __restrict__ cnt,
        const float* __restrict__ l2w, const float* __restrict__ l2b,
        const float* __restrict__ hw1, const float* __restrict__ hb1,
        const float* __restrict__ hw2, const float* __restrict__ hb2,
        float* __restrict__ out) {
    int m = blockIdx.x, f = threadIdx.x;
    __shared__ float me[H_DIM];
    __shared__ float u[H_DIM / 2];
    const float* ms = mols + (size_t)m * H_DIM;
    float acc = l2b[f] * (float)cnt[m];
#pragma unroll 16
    for (int k = 0; k < H_DIM; ++k) acc += ms[k] * l2w[k * H_DIM + f];
    me[f] = acc;
    __syncthreads();
    if (f < 64) {
        float a2 = hb1[f];
#pragma unroll 16
        for (int k = 0; k < H_DIM; ++k) a2 += me[k] * hw1[k * 64 + f];
        u[f] = sspf(a2);
    }
    __syncthreads();
    if (f == 0) {
        float o = hb2[0];
#pragma unroll 16
        for (int j = 0; j < 64; ++j) o += u[j] * hw2[j];
        out[m] = o;
    }
}

// ---------------------------------------------------------------- launch
extern "C" void kernel_launch(void* const* d_in, const int* in_sizes, int n_in,
                              void* d_out, int out_size, void* d_ws, size_t ws_size,
                              hipStream_t stream) {
    const int*   z   = (const int*)d_in[0];
    const float* pos = (const float*)d_in[1];
    const int*   er  = (const int*)d_in[2];
    const int*   ec  = (const int*)d_in[3];
    const int*   a2c = (const int*)d_in[4];
    const int*   c2m = (const int*)d_in[5];
    const float* emb = (const float*)d_in[6];
    const float* w1  = (const float*)d_in[7];
    const float* b1  = (const float*)d_in[8];
    const float* w2  = (const float*)d_in[9];
    const float* b2  = (const float*)d_in[10];
    const float* c1w = (const float*)d_in[11];
    const float* c2w = (const float*)d_in[12];
    const float* c2b = (const float*)d_in[13];
    const float* iw  = (const float*)d_in[14];
    const float* ib  = (const float*)d_in[15];
    const float* l1w = (const float*)d_in[16];
    const float* l1b = (const float*)d_in[17];
    const float* l2w = (const float*)d_in[18];
    const float* l2b = (const float*)d_in[19];
    const float* hw1 = (const float*)d_in[20];
    const float* hb1 = (const float*)d_in[21];
    const float* hw2 = (const float*)d_in[22];
    const float* hb2 = (const float*)d_in[23];

    const int N  = in_sizes[0];
    const int E  = in_sizes[2];
    const int NM = out_size;
    float* out = (float*)d_out;

    // workspace layout (~89 MB)
    char* wsp = (char*)d_ws;
    uint2* ebuf = (uint2*)wsp;            wsp += (size_t)E * 8;
    float* tab  = (float*)wsp;            wsp += (size_t)L_LAYERS * TBL * NF_DIM * 4;
    unsigned short* wbt = (unsigned short*)wsp;  wsp += (size_t)19 * 16384 * 2;
    float* h    = (float*)wsp;            wsp += (size_t)N * H_DIM * 4;
    unsigned short* xfb = (unsigned short*)wsp;  wsp += (size_t)N * H_DIM * 2;
    unsigned short* aggb = (unsigned short*)wsp; wsp += (size_t)N * H_DIM * 2;
    float* sbuf = (float*)wsp;            wsp += (size_t)N * H_DIM * 4;
    float* mols = (float*)wsp;            wsp += (size_t)NM * H_DIM * 4;
    int*   cnt_m = (int*)wsp;             wsp += (size_t)NM * 4;
    int*   ccnt  = (int*)wsp;             wsp += (size_t)N * 4;
    int*   row_start = (int*)wsp;         wsp += (size_t)(N + 1) * 4;
    int*   cursor = (int*)wsp;            wsp += (size_t)N * 4;
    int*   bsums  = (int*)wsp;            wsp += 256 * 4;
    int*   excl   = (int*)wsp;

    // --- CSR build (edges fixed across layers) ---
    hipMemsetAsync(ccnt, 0, (size_t)N * sizeof(int), stream);
    count_kernel<<<(E + 255) / 256, 256, 0, stream>>>(ec, ccnt, E);
    int nb = (N + SCAN_B - 1) / SCAN_B;
    scan1<<<nb, SCAN_B, 0, stream>>>(ccnt, excl, bsums, N);
    scan2<<<1, SCAN_B, 0, stream>>>(bsums, nb);
    scan3<<<nb, SCAN_B, 0, stream>>>(excl, bsums, row_start, cursor, N, E);
    build_edges<<<(E + 255) / 256, 256, 0, stream>>>(er, ec, pos, cursor, ebuf, E);

    build_tables<<<L_LAYERS * (TBL / T_PER), 128, 0, stream>>>(w1, b1, w2, b2, tab);
    embed_kernel<<<(N * H_DIM + 255) / 256, 256, 0, stream>>>(z, emb, h, N);

    // --- weight prep: bf16 in MFMA B-fragment order ---
    prep_wt_sw<<<L_LAYERS, 256, 0, stream>>>(c1w, wbt);
    prep_wt_sw<<<L_LAYERS, 256, 0, stream>>>(c2w, wbt + (size_t)6 * 16384);
    prep_wt_sw<<<L_LAYERS, 256, 0, stream>>>(iw,  wbt + (size_t)12 * 16384);
    prep_wt_sw<<<1,        256, 0, stream>>>(l1w, wbt + (size_t)18 * 16384);

    int gblocks = (N + 63) / 64;
    // xf0 = bf16(h @ conv_lin1_w[0])
    gemm_v2<<<gblocks, 256, 0, stream>>>(
        h, wbt, nullptr, nullptr, xfb, N, MODE_OUT_BF16);

    for (int l = 0; l < L_LAYERS; ++l) {
        edge_agg<<<(N + 7) / 8, 256, 0, stream>>>(
            ebuf, row_start, xfb, tab + (size_t)l * TBL * NF_DIM, aggb, N);
        int last = (l == L_LAYERS - 1);
        const unsigned short* B3 = last ? wbt + (size_t)18 * 16384
                                        : wbt + (size_t)(l + 1) * 16384;
        fused_layer<<<gblocks, 256, 0, stream>>>(
            aggb,
            wbt + (size_t)(6 + l) * 16384,  c2b + (size_t)l * H_DIM,
            wbt + (size_t)(12 + l) * 16384, ib + (size_t)l * H_DIM,
            B3, l1b, h, xfb, sbuf, N, last);
    }

    hipMemsetAsync(mols, 0, (size_t)NM * H_DIM * sizeof(float) + NM * sizeof(int), stream);
    mol_reduce<<<(N + MR_ATOMS - 1) / MR_ATOMS, 128, 0, stream>>>(
        sbuf, a2c, c2m, mols, cnt_m, N);
    head_kernel<<<NM, 128, 0, stream>>>(mols, cnt_m, l2w, l2b, hw1, hb1, hw2, hb2, out);
}

// Round 6
// 740.124 us; speedup vs baseline: 9.7610x; 1.2141x over previous
//
#include <hip/hip_runtime.h>
#include <hip/hip_bf16.h>
#include <hip/hip_fp16.h>
#include <math.h>

#define H_DIM   128
#define NF_DIM  128
#define G_DIM   50
#define L_LAYERS 6
#define TBL     2048
#define DMAX    12.8f
#define CUTOFF_C 10.0f
#define COEFF_C (-0.5f * 49.0f * 49.0f / 100.0f)
#define SCAN_B  256
#define T_PER   16
#define STG_STR 140   // shorts per staging row: banks 24q-pattern -> conflict-free b16 writes

typedef __bf16 bf16x8 __attribute__((ext_vector_type(8)));
typedef float  f32x4  __attribute__((ext_vector_type(4)));

__device__ __forceinline__ float sspf(float x) {
    // shifted softplus via fast exp/log (rel err ~1e-6, output path is bf16-bound)
    float e = __expf(-fabsf(x));
    return fmaxf(x, 0.0f) + __logf(1.0f + e) - 0.69314718055994530942f;
}

__device__ __forceinline__ unsigned short f2bf(float f) {
    unsigned int u = __float_as_uint(f);
    u = (u + 0x7fffu + ((u >> 16) & 1u)) >> 16;   // RNE
    return (unsigned short)u;
}

__device__ __forceinline__ float bf2f(unsigned short u) {
    return __uint_as_float(((unsigned int)u) << 16);
}

// XOR bank-swizzle for 16B A-frag chunks (c < 1024). Injects lane2>>3 and ks
// into the bank-relevant low bits; bijective within each 64-chunk group.
__device__ __forceinline__ int swz(int c) {
    return c ^ ((c >> 3) & 7) ^ ((c >> 8) & 3);
}

// ---------------------------------------------------------------- filter tables
__global__ __launch_bounds__(128) void build_tables(
        const float* __restrict__ w1, const float* __restrict__ b1,
        const float* __restrict__ w2, const float* __restrict__ b2,
        float* __restrict__ tab) {
    int l  = blockIdx.x / (TBL / T_PER);
    int t0 = (blockIdx.x % (TBL / T_PER)) * T_PER;
    int f  = threadIdx.x;  // 128
    __shared__ float sW1[G_DIM * 128];
    __shared__ float gs[T_PER][G_DIM + 2];
    __shared__ float sy[T_PER][130];
    for (int i = f; i < G_DIM * 128; i += 128)
        sW1[i] = w1[(size_t)l * G_DIM * 128 + i];
    if (f < G_DIM) {
        float o = f * (CUTOFF_C / (G_DIM - 1));
#pragma unroll
        for (int u = 0; u < T_PER; ++u) {
            float dt = (t0 + u) * (DMAX / (TBL - 1));
            float dd = dt - o;
            gs[u][f] = __expf(COEFF_C * dd * dd);
        }
    }
    __syncthreads();
    float y[T_PER];
    float bb = b1[l * 128 + f];
#pragma unroll
    for (int u = 0; u < T_PER; ++u) y[u] = bb;
    for (int g = 0; g < G_DIM; ++g) {
        float wv = sW1[g * 128 + f];
#pragma unroll
        for (int u = 0; u < T_PER; ++u) y[u] += gs[u][g] * wv;
    }
#pragma unroll
    for (int u = 0; u < T_PER; ++u) sy[u][f] = sspf(y[u]);
    __syncthreads();
    float acc[T_PER];
    float b2v = b2[l * 128 + f];
#pragma unroll
    for (int u = 0; u < T_PER; ++u) acc[u] = b2v;
    const float* W2 = w2 + (size_t)l * 16384;
    for (int k = 0; k < 128; ++k) {
        float wv = W2[k * 128 + f];
#pragma unroll
        for (int u = 0; u < T_PER; ++u) acc[u] += sy[u][k] * wv;
    }
#pragma unroll
    for (int u = 0; u < T_PER; ++u)
        tab[((size_t)l * TBL + t0 + u) * 128 + f] = acc[u];
}

// ---------------------------------------------------------------- embedding
__global__ __launch_bounds__(256) void embed_kernel(
        const int* __restrict__ z, const float* __restrict__ emb,
        float* __restrict__ h, int N) {
    int idx = blockIdx.x * blockDim.x + threadIdx.x;
    if (idx >= N * H_DIM) return;
    int n = idx >> 7, f = idx & 127;
    h[idx] = emb[z[n] * H_DIM + f];
}

// ---------------------------------------------------------------- weight prep
// MFMA B-fragment order: Bsw[((ks*8 + j)*64 + lane)*8 + jj] =
//   bf16( W[k = ks*32 + (lane>>4)*8 + jj][n = j*16 + (lane&15)] )
__global__ __launch_bounds__(256) void prep_wt_sw(
        const float* __restrict__ W, unsigned short* __restrict__ Bsw) {
    int m = blockIdx.x;
    const float* src = W + (size_t)m * 16384;
    unsigned short* dst = Bsw + (size_t)m * 16384;
    for (int i = threadIdx.x; i < 16384; i += 256) {
        int jj = i & 7, lane = (i >> 3) & 63, j = (i >> 9) & 7, ks = i >> 12;
        int n = j * 16 + (lane & 15);
        int k = ks * 32 + ((lane >> 4) & 3) * 8 + jj;
        dst[i] = f2bf(src[k * 128 + n]);
    }
}

// ---------------------------------------------------------------- CSR build
__global__ __launch_bounds__(256) void count_kernel(
        const int* __restrict__ ec, int* __restrict__ cnt, int E) {
    int e = blockIdx.x * blockDim.x + threadIdx.x;
    if (e < E) atomicAdd(&cnt[ec[e]], 1);
}

__global__ __launch_bounds__(SCAN_B) void scan1(
        const int* __restrict__ cnt, int* __restrict__ excl,
        int* __restrict__ bsums, int N) {
    __shared__ int s[SCAN_B];
    int i = blockIdx.x * SCAN_B + threadIdx.x;
    int v = (i < N) ? cnt[i] : 0;
    s[threadIdx.x] = v;
    __syncthreads();
    for (int off = 1; off < SCAN_B; off <<= 1) {
        int t = (threadIdx.x >= off) ? s[threadIdx.x - off] : 0;
        __syncthreads();
        s[threadIdx.x] += t;
        __syncthreads();
    }
    if (i < N) excl[i] = s[threadIdx.x] - v;
    if (threadIdx.x == SCAN_B - 1) bsums[blockIdx.x] = s[SCAN_B - 1];
}

__global__ __launch_bounds__(SCAN_B) void scan2(int* __restrict__ bsums, int nb) {
    __shared__ int s[SCAN_B];
    int v = (threadIdx.x < nb) ? bsums[threadIdx.x] : 0;
    s[threadIdx.x] = v;
    __syncthreads();
    for (int off = 1; off < SCAN_B; off <<= 1) {
        int t = (threadIdx.x >= off) ? s[threadIdx.x - off] : 0;
        __syncthreads();
        s[threadIdx.x] += t;
        __syncthreads();
    }
    if (threadIdx.x < nb) bsums[threadIdx.x] = s[threadIdx.x] - v;
}

__global__ __launch_bounds__(SCAN_B) void scan3(
        const int* __restrict__ excl, const int* __restrict__ bsums,
        int* __restrict__ row_start, int* __restrict__ cursor, int N, int E) {
    int i = blockIdx.x * SCAN_B + threadIdx.x;
    if (i < N) {
        int v = excl[i] + bsums[blockIdx.x];
        row_start[i] = v;
        cursor[i] = v;
    }
    if (i == 0) row_start[N] = E;
}

// 8-byte edge record: {row | (i0<<17), half2(C*(1-fr), C*fr)}
__global__ __launch_bounds__(256) void build_edges(
        const int* __restrict__ er, const int* __restrict__ ec,
        const float* __restrict__ pos, int* __restrict__ cursor,
        uint2* __restrict__ ebuf, int E) {
    int e = blockIdx.x * blockDim.x + threadIdx.x;
    if (e >= E) return;
    int r = er[e], c = ec[e];
    float dx = pos[r * 3 + 0] - pos[c * 3 + 0];
    float dy = pos[r * 3 + 1] - pos[c * 3 + 1];
    float dz = pos[r * 3 + 2] - pos[c * 3 + 2];
    float d = sqrtf(dx * dx + dy * dy + dz * dz);
    float C = 0.5f * (cosf(d * (3.14159265358979323846f / CUTOFF_C)) + 1.0f);
    float t = fminf(d, DMAX) * ((TBL - 1) / DMAX);
    int i0 = (int)t;
    if (i0 > TBL - 2) i0 = TBL - 2;
    float fr = t - (float)i0;
    __half2 abh = __floats2half2_rn(C * (1.0f - fr), C * fr);
    int pos_ = atomicAdd(&cursor[c], 1);
    ebuf[pos_] = make_uint2((unsigned)r | ((unsigned)i0 << 17),
                            *(unsigned*)&abh);
}

// ---------------------------------------------------------------- edge gather
// aggb[i] = bf16( sum_j xfb[row_j]*(a*tab[i0]+b*tab[i0+1]) ); 32 lanes/atom,
// 2 edges in flight (uint4 record-pair loads, dual accumulators).
__global__ __launch_bounds__(256) void edge_agg(
        const uint2* __restrict__ ebuf, const int* __restrict__ row_start,
        const unsigned short* __restrict__ xfb, const float* __restrict__ tab_l,
        unsigned short* __restrict__ aggb, int N) {
    int tid = threadIdx.x;
    int atom = blockIdx.x * 8 + (tid >> 5);
    if (atom >= N) return;
    int f4 = (tid & 31) * 4;
    float4 a0 = make_float4(0.f, 0.f, 0.f, 0.f);
    float4 a1 = make_float4(0.f, 0.f, 0.f, 0.f);
    int j0 = row_start[atom], j1 = row_start[atom + 1];
    int j = j0;
    if (j < j1 && (j & 1)) {   // align to even for uint4 pair loads
        uint2 ed = ebuf[j];
        int r = ed.x & 0x1ffff, i0 = ed.x >> 17;
        float2 ab = __half22float2(*(__half2*)&ed.y);
        const float4 w0 = *(const float4*)(tab_l + (size_t)i0 * 128 + f4);
        const float4 w1 = *(const float4*)(tab_l + ((size_t)i0 + 1) * 128 + f4);
        const ushort4 xu = *(const ushort4*)(xfb + (size_t)r * 128 + f4);
        a0.x += bf2f(xu.x) * (ab.x * w0.x + ab.y * w1.x);
        a0.y += bf2f(xu.y) * (ab.x * w0.y + ab.y * w1.y);
        a0.z += bf2f(xu.z) * (ab.x * w0.z + ab.y * w1.z);
        a0.w += bf2f(xu.w) * (ab.x * w0.w + ab.y * w1.w);
        ++j;
    }
    for (; j + 1 < j1; j += 2) {
        uint4 e2 = *(const uint4*)(ebuf + j);   // two records
        int r0 = e2.x & 0x1ffff, i00 = e2.x >> 17;
        int r1 = e2.z & 0x1ffff, i01 = e2.z >> 17;
        float2 ab0 = __half22float2(*(__half2*)&e2.y);
        float2 ab1 = __half22float2(*(__half2*)&e2.w);
        const float4 p0 = *(const float4*)(tab_l + (size_t)i00 * 128 + f4);
        const float4 p1 = *(const float4*)(tab_l + ((size_t)i00 + 1) * 128 + f4);
        const float4 q0 = *(const float4*)(tab_l + (size_t)i01 * 128 + f4);
        const float4 q1 = *(const float4*)(tab_l + ((size_t)i01 + 1) * 128 + f4);
        const ushort4 x0 = *(const ushort4*)(xfb + (size_t)r0 * 128 + f4);
        const ushort4 x1 = *(const ushort4*)(xfb + (size_t)r1 * 128 + f4);
        a0.x += bf2f(x0.x) * (ab0.x * p0.x + ab0.y * p1.x);
        a0.y += bf2f(x0.y) * (ab0.x * p0.y + ab0.y * p1.y);
        a0.z += bf2f(x0.z) * (ab0.x * p0.z + ab0.y * p1.z);
        a0.w += bf2f(x0.w) * (ab0.x * p0.w + ab0.y * p1.w);
        a1.x += bf2f(x1.x) * (ab1.x * q0.x + ab1.y * q1.x);
        a1.y += bf2f(x1.y) * (ab1.x * q0.y + ab1.y * q1.y);
        a1.z += bf2f(x1.z) * (ab1.x * q0.z + ab1.y * q1.z);
        a1.w += bf2f(x1.w) * (ab1.x * q0.w + ab1.y * q1.w);
    }
    if (j < j1) {
        uint2 ed = ebuf[j];
        int r = ed.x & 0x1ffff, i0 = ed.x >> 17;
        float2 ab = __half22float2(*(__half2*)&ed.y);
        const float4 w0 = *(const float4*)(tab_l + (size_t)i0 * 128 + f4);
        const float4 w1 = *(const float4*)(tab_l + ((size_t)i0 + 1) * 128 + f4);
        const ushort4 xu = *(const ushort4*)(xfb + (size_t)r * 128 + f4);
        a0.x += bf2f(xu.x) * (ab.x * w0.x + ab.y * w1.x);
        a0.y += bf2f(xu.y) * (ab.x * w0.y + ab.y * w1.y);
        a0.z += bf2f(xu.z) * (ab.x * w0.z + ab.y * w1.z);
        a0.w += bf2f(xu.w) * (ab.x * w0.w + ab.y * w1.w);
    }
    a0.x += a1.x; a0.y += a1.y; a0.z += a1.z; a0.w += a1.w;
    unsigned short o[4] = {f2bf(a0.x), f2bf(a0.y), f2bf(a0.z), f2bf(a0.w)};
    *(uint2*)(aggb + (size_t)atom * 128 + f4) = *(const uint2*)o;
}

// ---------------------------------------------------------------- GEMM v2 (layer-0 xf)
#define MODE_BIAS     1
#define MODE_SSP_OUT  2
#define MODE_OUT_BF16 4

__global__ __launch_bounds__(256, 4) void gemm_v2(
        const float* __restrict__ A, const unsigned short* __restrict__ Bsw,
        const float* __restrict__ bias, float* __restrict__ OutF,
        unsigned short* __restrict__ OutB, int M, int mode) {
    __shared__ __align__(16) float smem[64 * 132];
    unsigned short* asw = (unsigned short*)smem;
    int tid = threadIdx.x;
    int m0 = blockIdx.x * 64;

    for (int i = tid; i < 1024; i += 256) {
        int ks = i >> 8, w = (i >> 6) & 3, ln = i & 63;
        int row = m0 + w * 16 + (ln & 15);
        int kb = ks * 32 + (ln >> 4) * 8;
        unsigned short tmp[8];
        if (row < M) {
            const float* ap = A + (size_t)row * 128 + kb;
            float4 v0 = *(const float4*)ap;
            float4 v1 = *(const float4*)(ap + 4);
            tmp[0] = f2bf(v0.x); tmp[1] = f2bf(v0.y);
            tmp[2] = f2bf(v0.z); tmp[3] = f2bf(v0.w);
            tmp[4] = f2bf(v1.x); tmp[5] = f2bf(v1.y);
            tmp[6] = f2bf(v1.z); tmp[7] = f2bf(v1.w);
        } else {
#pragma unroll
            for (int j = 0; j < 8; ++j) tmp[j] = 0;
        }
        *(uint4*)(asw + (size_t)i * 8) = *(const uint4*)tmp;
    }
    __syncthreads();

    int w = tid >> 6, ln = tid & 63;
    int quad = ln >> 4, l15 = ln & 15;
    f32x4 acc[8] = {};
#pragma unroll
    for (int ks = 0; ks < 4; ++ks) {
        bf16x8 af = *(const bf16x8*)(asw + ((ks * 4 + w) * 64 + ln) * 8);
#pragma unroll
        for (int j = 0; j < 8; ++j) {
            bf16x8 bf = *(const bf16x8*)(Bsw + (((ks * 8 + j) * 64) + ln) * 8);
            acc[j] = __builtin_amdgcn_mfma_f32_16x16x32_bf16(af, bf, acc[j], 0, 0, 0);
        }
    }
    __syncthreads();

#pragma unroll
    for (int j = 0; j < 8; ++j) {
        int col = j * 16 + l15;
        float bv = (mode & MODE_BIAS) ? bias[col] : 0.f;
#pragma unroll
        for (int r = 0; r < 4; ++r)
            smem[(w * 16 + quad * 4 + r) * 132 + col] = acc[j][r] + bv;
    }
    __syncthreads();

    for (int i = tid; i < 2048; i += 256) {
        int row = i >> 5, c4 = (i & 31) * 4;
        int grow = m0 + row;
        if (grow >= M) continue;
        float4 v = *(const float4*)(smem + row * 132 + c4);
        if (mode & MODE_SSP_OUT) {
            v.x = sspf(v.x); v.y = sspf(v.y); v.z = sspf(v.z); v.w = sspf(v.w);
        }
        if (mode & MODE_OUT_BF16) {
            unsigned short o[4] = {f2bf(v.x), f2bf(v.y), f2bf(v.z), f2bf(v.w)};
            *(uint2*)(OutB + (size_t)grow * 128 + c4) = *(const uint2*)o;
        } else {
            *(float4*)(OutF + (size_t)grow * 128 + c4) = v;
        }
    }
}

// ---------------------------------------------------------------- fused layer
// t1 = aggb @ c2w + c2b;  x = ssp(t1) @ iw + ib;  h += x;
// then xfb_next = bf16(h @ B3) (mid) or s_out = ssp(h @ B3 + b3) (last).
// A-frag LDS chunks XOR-swizzled (bank-conflict-free); bf16 staging rows
// at stride 140 (conflict-free writes, 2-way reads). LDS 33.5 KB -> 4 blk/CU.
__global__ __launch_bounds__(256, 4) void fused_layer(
        const unsigned short* __restrict__ aggb,
        const unsigned short* __restrict__ B1sw, const float* __restrict__ b1v,
        const unsigned short* __restrict__ B2sw, const float* __restrict__ b2v,
        const unsigned short* __restrict__ B3sw, const float* __restrict__ b3v,
        float* __restrict__ h, unsigned short* __restrict__ xfb_next,
        float* __restrict__ s_out, int M, int last) {
    __shared__ __align__(16) unsigned short frag[8192];         // 16 KB
    __shared__ __align__(16) unsigned short stg[64 * STG_STR];  // 17.5 KB
    int tid = threadIdx.x;
    int m0 = blockIdx.x * 64;

    // 1. stage aggb rows -> swizzled A-frags
    for (int i = tid; i < 1024; i += 256) {
        int ks = i >> 8, w_ = (i >> 6) & 3, ln_ = i & 63;
        int row = m0 + w_ * 16 + (ln_ & 15);
        int kb = ks * 32 + (ln_ >> 4) * 8;
        uint4 v = make_uint4(0, 0, 0, 0);
        if (row < M) v = *(const uint4*)(aggb + (size_t)row * 128 + kb);
        *(uint4*)(frag + swz(i) * 8) = v;
    }
    __syncthreads();

    int w = tid >> 6, ln = tid & 63;
    int quad = ln >> 4, l15 = ln & 15;

    // 2. conv2 MFMA
    f32x4 acc[8] = {};
#pragma unroll
    for (int ks = 0; ks < 4; ++ks) {
        bf16x8 af = *(const bf16x8*)(frag + swz((ks * 4 + w) * 64 + ln) * 8);
#pragma unroll
        for (int j = 0; j < 8; ++j) {
            bf16x8 bf = *(const bf16x8*)(B1sw + (((ks * 8 + j) * 64) + ln) * 8);
            acc[j] = __builtin_amdgcn_mfma_f32_16x16x32_bf16(af, bf, acc[j], 0, 0, 0);
        }
    }

    // 3. repack ssp(t1+b1) -> A-frags. Wave w only touches (.,w) chunks in
    //    both step 2 and here -> no barrier needed (within-wave ds ordering).
#pragma unroll
    for (int j = 0; j < 8; ++j) {
        int col = j * 16 + l15;
        float bv = b1v[col];
        int ks2 = j >> 1;
        int quad2 = (col >> 3) & 3;
        int jj = l15 & 7;
        int cbase = (ks2 * 4 + w) * 64 + quad2 * 16 + quad * 4;
#pragma unroll
        for (int r = 0; r < 4; ++r) {
            float s = sspf(acc[j][r] + bv);
            frag[swz(cbase + r) * 8 + jj] = f2bf(s);
        }
    }

    // 4. int_lin MFMA (same-wave chunks; compiler's lgkmcnt covers RAW)
    f32x4 acc2[8] = {};
#pragma unroll
    for (int ks = 0; ks < 4; ++ks) {
        bf16x8 af = *(const bf16x8*)(frag + swz((ks * 4 + w) * 64 + ln) * 8);
#pragma unroll
        for (int j = 0; j < 8; ++j) {
            bf16x8 bf = *(const bf16x8*)(B2sw + (((ks * 8 + j) * 64) + ln) * 8);
            acc2[j] = __builtin_amdgcn_mfma_f32_16x16x32_bf16(af, bf, acc2[j], 0, 0, 0);
        }
    }

    // 5. stage x = bf16(acc2 + b2), row-major stride-140 (own-wave rows)
#pragma unroll
    for (int j = 0; j < 8; ++j) {
        int col = j * 16 + l15;
        float bv = b2v[col];
#pragma unroll
        for (int r = 0; r < 4; ++r)
            stg[(w * 16 + quad * 4 + r) * STG_STR + col] = f2bf(acc2[j][r] + bv);
    }
    __syncthreads();   // A: frag reads (4) and stg writes (5) complete

    // 6. h += x (coalesced); write bf16(h_new) A-frags into frag (swizzled)
    for (int i = tid; i < 2048; i += 256) {
        int row = i >> 5, c4 = (i & 31) * 4;
        int grow = m0 + row;
        ushort4 xv = *(const ushort4*)(stg + row * STG_STR + c4);
        float4 v;
        v.x = bf2f(xv.x); v.y = bf2f(xv.y); v.z = bf2f(xv.z); v.w = bf2f(xv.w);
        if (grow < M) {
            float* hp = h + (size_t)grow * 128 + c4;
            float4 o = *(const float4*)hp;
            v.x += o.x; v.y += o.y; v.z += o.z; v.w += o.w;
            *(float4*)hp = v;
        } else {
            v = make_float4(0.f, 0.f, 0.f, 0.f);
        }
        unsigned short t4[4] = {f2bf(v.x), f2bf(v.y), f2bf(v.z), f2bf(v.w)};
        int w_ = row >> 4, l15_ = row & 15;
        int ks = c4 >> 5, q_ = (c4 >> 3) & 3, jj = c4 & 7;
        int c = (ks * 4 + w_) * 64 + q_ * 16 + l15_;
        *(uint2*)(frag + swz(c) * 8 + jj) = *(const uint2*)t4;
    }
    __syncthreads();   // B: frag/h-frag writes visible; stg reads complete

    // 7. next conv1 (or lin1) MFMA
    f32x4 acc3[8] = {};
#pragma unroll
    for (int ks = 0; ks < 4; ++ks) {
        bf16x8 af = *(const bf16x8*)(frag + swz((ks * 4 + w) * 64 + ln) * 8);
#pragma unroll
        for (int j = 0; j < 8; ++j) {
            bf16x8 bf = *(const bf16x8*)(B3sw + (((ks * 8 + j) * 64) + ln) * 8);
            acc3[j] = __builtin_amdgcn_mfma_f32_16x16x32_bf16(af, bf, acc3[j], 0, 0, 0);
        }
    }

    // 8. stage output bf16 (ssp in fp32 before rounding for last layer)
#pragma unroll
    for (int j = 0; j < 8; ++j) {
        int col = j * 16 + l15;
        float bv = last ? b3v[col] : 0.f;
#pragma unroll
        for (int r = 0; r < 4; ++r) {
            float v = acc3[j][r] + bv;
            if (last) v = sspf(v);
            stg[(w * 16 + quad * 4 + r) * STG_STR + col] = f2bf(v);
        }
    }
    __syncthreads();   // C

    // 9. write xfb_next (bf16) or s_out (fp32)
    for (int i = tid; i < 2048; i += 256) {
        int row = i >> 5, c4 = (i & 31) * 4;
        int grow = m0 + row;
        if (grow >= M) continue;
        ushort4 s4 = *(const ushort4*)(stg + row * STG_STR + c4);
        if (last) {
            float4 v;
            v.x = bf2f(s4.x); v.y = bf2f(s4.y); v.z = bf2f(s4.z); v.w = bf2f(s4.w);
            *(float4*)(s_out + (size_t)grow * 128 + c4) = v;
        } else {
            *(uint2*)(xfb_next + (size_t)grow * 128 + c4) = *(const uint2*)&s4;
        }
    }
}

// ---------------------------------------------------------------- atom -> mol sum
#define MR_ATOMS 32
__global__ __launch_bounds__(128) void mol_reduce(
        const float* __restrict__ s, const int* __restrict__ a2c,
        const int* __restrict__ c2m, float* __restrict__ mols,
        int* __restrict__ cnt, int N) {
    int f = threadIdx.x;
    int a0 = blockIdx.x * MR_ATOMS;
    int a1 = min(a0 + MR_ATOMS, N);
    float sum = 0.f;
    int cur = -1, run = 0;
    for (int a = a0; a < a1; ++a) {
        int m = c2m[a2c[a]];
        if (m != cur) {
            if (cur >= 0) {
                unsafeAtomicAdd(&mols[(size_t)cur * H_DIM + f], sum);
                if (f == 0) atomicAdd(&cnt[cur], run);
            }
            cur = m; sum = 0.f; run = 0;
        }
        sum += s[(size_t)a * H_DIM + f];
        ++run;
    }
    if (cur >= 0) {
        unsafeAtomicAdd(&mols[(size_t)cur * H_DIM + f], sum);
        if (f == 0) atomicAdd(&cnt[cur], run);
    }
}

// ---------------------------------------------------------------- head
__global__ __launch_bounds__(128) void head_kernel(
        const float* __restrict__ mols, const int* __restrict__ cnt,
        const float* __restrict__ l2w, const float* __restrict__ l2b,
        const float* __restrict__ hw1, const float* __restrict__ hb1,
        const float* __restrict__ hw2, const float* __restrict__ hb2,
        float* __restrict__ out) {
    int m = blockIdx.x, f = threadIdx.x;
    __shared__ float me[H_DIM];
    __shared__ float u[H_DIM / 2];
    const float* ms = mols + (size_t)m * H_DIM;
    float acc = l2b[f] * (float)cnt[m];
#pragma unroll 16
    for (int k = 0; k < H_DIM; ++k) acc += ms[k] * l2w[k * H_DIM + f];
    me[f] = acc;
    __syncthreads();
    if (f < 64) {
        float a2 = hb1[f];
#pragma unroll 16
        for (int k = 0; k < H_DIM; ++k) a2 += me[k] * hw1[k * 64 + f];
        u[f] = sspf(a2);
    }
    __syncthreads();
    if (f == 0) {
        float o = hb2[0];
#pragma unroll 16
        for (int j = 0; j < 64; ++j) o += u[j] * hw2[j];
        out[m] = o;
    }
}

// ---------------------------------------------------------------- launch
extern "C" void kernel_launch(void* const* d_in, const int* in_sizes, int n_in,
                              void* d_out, int out_size, void* d_ws, size_t ws_size,
                              hipStream_t stream) {
    const int*   z   = (const int*)d_in[0];
    const float* pos = (const float*)d_in[1];
    const int*   er  = (const int*)d_in[2];
    const int*   ec  = (const int*)d_in[3];
    const int*   a2c = (const int*)d_in[4];
    const int*   c2m = (const int*)d_in[5];
    const float* emb = (const float*)d_in[6];
    const float* w1  = (const float*)d_in[7];
    const float* b1  = (const float*)d_in[8];
    const float* w2  = (const float*)d_in[9];
    const float* b2  = (const float*)d_in[10];
    const float* c1w = (const float*)d_in[11];
    const float* c2w = (const float*)d_in[12];
    const float* c2b = (const float*)d_in[13];
    const float* iw  = (const float*)d_in[14];
    const float* ib  = (const float*)d_in[15];
    const float* l1w = (const float*)d_in[16];
    const float* l1b = (const float*)d_in[17];
    const float* l2w = (const float*)d_in[18];
    const float* l2b = (const float*)d_in[19];
    const float* hw1 = (const float*)d_in[20];
    const float* hb1 = (const float*)d_in[21];
    const float* hw2 = (const float*)d_in[22];
    const float* hb2 = (const float*)d_in[23];

    const int N  = in_sizes[0];
    const int E  = in_sizes[2];
    const int NM = out_size;
    float* out = (float*)d_out;

    // workspace layout (~89 MB)
    char* wsp = (char*)d_ws;
    uint2* ebuf = (uint2*)wsp;            wsp += (size_t)E * 8;
    float* tab  = (float*)wsp;            wsp += (size_t)L_LAYERS * TBL * NF_DIM * 4;
    unsigned short* wbt = (unsigned short*)wsp;  wsp += (size_t)19 * 16384 * 2;
    float* h    = (float*)wsp;            wsp += (size_t)N * H_DIM * 4;
    unsigned short* xfb = (unsigned short*)wsp;  wsp += (size_t)N * H_DIM * 2;
    unsigned short* aggb = (unsigned short*)wsp; wsp += (size_t)N * H_DIM * 2;
    float* sbuf = (float*)wsp;            wsp += (size_t)N * H_DIM * 4;
    float* mols = (float*)wsp;            wsp += (size_t)NM * H_DIM * 4;
    int*   cnt_m = (int*)wsp;             wsp += (size_t)NM * 4;
    int*   ccnt  = (int*)wsp;             wsp += (size_t)N * 4;
    int*   row_start = (int*)wsp;         wsp += (size_t)(N + 1) * 4;
    int*   cursor = (int*)wsp;            wsp += (size_t)N * 4;
    int*   bsums  = (int*)wsp;            wsp += 256 * 4;
    int*   excl   = (int*)wsp;

    // --- CSR build (edges fixed across layers) ---
    hipMemsetAsync(ccnt, 0, (size_t)N * sizeof(int), stream);
    count_kernel<<<(E + 255) / 256, 256, 0, stream>>>(ec, ccnt, E);
    int nb = (N + SCAN_B - 1) / SCAN_B;
    scan1<<<nb, SCAN_B, 0, stream>>>(ccnt, excl, bsums, N);
    scan2<<<1, SCAN_B, 0, stream>>>(bsums, nb);
    scan3<<<nb, SCAN_B, 0, stream>>>(excl, bsums, row_start, cursor, N, E);
    build_edges<<<(E + 255) / 256, 256, 0, stream>>>(er, ec, pos, cursor, ebuf, E);

    build_tables<<<L_LAYERS * (TBL / T_PER), 128, 0, stream>>>(w1, b1, w2, b2, tab);
    embed_kernel<<<(N * H_DIM + 255) / 256, 256, 0, stream>>>(z, emb, h, N);

    // --- weight prep: bf16 in MFMA B-fragment order ---
    prep_wt_sw<<<L_LAYERS, 256, 0, stream>>>(c1w, wbt);
    prep_wt_sw<<<L_LAYERS, 256, 0, stream>>>(c2w, wbt + (size_t)6 * 16384);
    prep_wt_sw<<<L_LAYERS, 256, 0, stream>>>(iw,  wbt + (size_t)12 * 16384);
    prep_wt_sw<<<1,        256, 0, stream>>>(l1w, wbt + (size_t)18 * 16384);

    int gblocks = (N + 63) / 64;
    // xf0 = bf16(h @ conv_lin1_w[0])
    gemm_v2<<<gblocks, 256, 0, stream>>>(
        h, wbt, nullptr, nullptr, xfb, N, MODE_OUT_BF16);

    for (int l = 0; l < L_LAYERS; ++l) {
        edge_agg<<<(N + 7) / 8, 256, 0, stream>>>(
            ebuf, row_start, xfb, tab + (size_t)l * TBL * NF_DIM, aggb, N);
        int last = (l == L_LAYERS - 1);
        const unsigned short* B3 = last ? wbt + (size_t)18 * 16384
                                        : wbt + (size_t)(l + 1) * 16384;
        fused_layer<<<gblocks, 256, 0, stream>>>(
            aggb,
            wbt + (size_t)(6 + l) * 16384,  c2b + (size_t)l * H_DIM,
            wbt + (size_t)(12 + l) * 16384, ib + (size_t)l * H_DIM,
            B3, l1b, h, xfb, sbuf, N, last);
    }

    hipMemsetAsync(mols, 0, (size_t)NM * H_DIM * sizeof(float) + NM * sizeof(int), stream);
    mol_reduce<<<(N + MR_ATOMS - 1) / MR_ATOMS, 128, 0, stream>>>(
        sbuf, a2c, c2m, mols, cnt_m, N);
    head_kernel<<<NM, 128, 0, stream>>>(mols, cnt_m, l2w, l2b, hw1, hb1, hw2, hb2, out);
}

// Round 7
// 693.819 us; speedup vs baseline: 10.4125x; 1.0667x over previous
//
#include <hip/hip_runtime.h>
#include <hip/hip_bf16.h>
#include <hip/hip_fp16.h>
#include <math.h>

#define H_DIM   128
#define NF_DIM  128
#define G_DIM   50
#define L_LAYERS 6
#define TBL     2048
#define DMAX    12.8f
#define CUTOFF_C 10.0f
#define COEFF_C (-0.5f * 49.0f * 49.0f / 100.0f)
#define SCAN_B  256
#define T_PER   16
#define T_PER2  (T_PER + 1)
#define STG_STR 140

typedef __bf16 bf16x8 __attribute__((ext_vector_type(8)));
typedef float  f32x4  __attribute__((ext_vector_type(4)));

__device__ __forceinline__ float sspf(float x) {
    float e = __expf(-fabsf(x));
    return fmaxf(x, 0.0f) + __logf(1.0f + e) - 0.69314718055994530942f;
}

__device__ __forceinline__ unsigned short f2bf(float f) {
    unsigned int u = __float_as_uint(f);
    u = (u + 0x7fffu + ((u >> 16) & 1u)) >> 16;   // RNE
    return (unsigned short)u;
}

__device__ __forceinline__ float bf2f(unsigned short u) {
    return __uint_as_float(((unsigned int)u) << 16);
}

// XOR bank-swizzle for 16B A-frag chunks (c < 1024)
__device__ __forceinline__ int swz(int c) {
    return c ^ ((c >> 3) & 7) ^ ((c >> 8) & 3);
}

// ---------------------------------------------------------------- filter tables
// Emits interleaved bf16 pair table: tab2[t][f] = (bf16(W[t+1][f])<<16)|bf16(W[t][f])
// Each block computes T_PER+1 rows (one redundant) so pairs stay block-local.
__global__ __launch_bounds__(128) void build_tables(
        const float* __restrict__ w1, const float* __restrict__ b1,
        const float* __restrict__ w2, const float* __restrict__ b2,
        unsigned int* __restrict__ tab2) {
    int l  = blockIdx.x / (TBL / T_PER);
    int t0 = (blockIdx.x % (TBL / T_PER)) * T_PER;
    int f  = threadIdx.x;  // 128
    __shared__ float sW1[G_DIM * 128];        // 25.6 KB
    __shared__ float gs[T_PER2][G_DIM + 2];
    __shared__ float sy[T_PER2][130];
    for (int i = f; i < G_DIM * 128; i += 128)
        sW1[i] = w1[(size_t)l * G_DIM * 128 + i];
    if (f < G_DIM) {
        float o = f * (CUTOFF_C / (G_DIM - 1));
#pragma unroll
        for (int u = 0; u < T_PER2; ++u) {
            int t = t0 + u;
            if (t > TBL - 1) t = TBL - 1;   // last pair never read; clamp
            float dt = t * (DMAX / (TBL - 1));
            float dd = dt - o;
            gs[u][f] = __expf(COEFF_C * dd * dd);
        }
    }
    __syncthreads();
    float y[T_PER2];
    float bb = b1[l * 128 + f];
#pragma unroll
    for (int u = 0; u < T_PER2; ++u) y[u] = bb;
    for (int g = 0; g < G_DIM; ++g) {
        float wv = sW1[g * 128 + f];
#pragma unroll
        for (int u = 0; u < T_PER2; ++u) y[u] += gs[u][g] * wv;
    }
#pragma unroll
    for (int u = 0; u < T_PER2; ++u) sy[u][f] = sspf(y[u]);
    __syncthreads();
    float acc[T_PER2];
    float b2v = b2[l * 128 + f];
#pragma unroll
    for (int u = 0; u < T_PER2; ++u) acc[u] = b2v;
    const float* W2 = w2 + (size_t)l * 16384;
    for (int k = 0; k < 128; ++k) {
        float wv = W2[k * 128 + f];
#pragma unroll
        for (int u = 0; u < T_PER2; ++u) acc[u] += sy[u][k] * wv;
    }
#pragma unroll
    for (int u = 0; u < T_PER; ++u) {
        unsigned int lo = f2bf(acc[u]);
        unsigned int hi = f2bf(acc[u + 1]);
        tab2[((size_t)l * TBL + t0 + u) * 128 + f] = (hi << 16) | lo;
    }
}

// ---------------------------------------------------------------- embedding
__global__ __launch_bounds__(256) void embed_kernel(
        const int* __restrict__ z, const float* __restrict__ emb,
        float* __restrict__ h, int N) {
    int idx = blockIdx.x * blockDim.x + threadIdx.x;
    if (idx >= N * H_DIM) return;
    int n = idx >> 7, f = idx & 127;
    h[idx] = emb[z[n] * H_DIM + f];
}

// ---------------------------------------------------------------- weight prep
__global__ __launch_bounds__(256) void prep_wt_sw(
        const float* __restrict__ W, unsigned short* __restrict__ Bsw) {
    int m = blockIdx.x;
    const float* src = W + (size_t)m * 16384;
    unsigned short* dst = Bsw + (size_t)m * 16384;
    for (int i = threadIdx.x; i < 16384; i += 256) {
        int jj = i & 7, lane = (i >> 3) & 63, j = (i >> 9) & 7, ks = i >> 12;
        int n = j * 16 + (lane & 15);
        int k = ks * 32 + ((lane >> 4) & 3) * 8 + jj;
        dst[i] = f2bf(src[k * 128 + n]);
    }
}

// ---------------------------------------------------------------- CSR build
__global__ __launch_bounds__(256) void count_kernel(
        const int* __restrict__ ec, int* __restrict__ cnt, int E) {
    int e = blockIdx.x * blockDim.x + threadIdx.x;
    if (e < E) atomicAdd(&cnt[ec[e]], 1);
}

__global__ __launch_bounds__(SCAN_B) void scan1(
        const int* __restrict__ cnt, int* __restrict__ excl,
        int* __restrict__ bsums, int N) {
    __shared__ int s[SCAN_B];
    int i = blockIdx.x * SCAN_B + threadIdx.x;
    int v = (i < N) ? cnt[i] : 0;
    s[threadIdx.x] = v;
    __syncthreads();
    for (int off = 1; off < SCAN_B; off <<= 1) {
        int t = (threadIdx.x >= off) ? s[threadIdx.x - off] : 0;
        __syncthreads();
        s[threadIdx.x] += t;
        __syncthreads();
    }
    if (i < N) excl[i] = s[threadIdx.x] - v;
    if (threadIdx.x == SCAN_B - 1) bsums[blockIdx.x] = s[SCAN_B - 1];
}

__global__ __launch_bounds__(SCAN_B) void scan2(int* __restrict__ bsums, int nb) {
    __shared__ int s[SCAN_B];
    int v = (threadIdx.x < nb) ? bsums[threadIdx.x] : 0;
    s[threadIdx.x] = v;
    __syncthreads();
    for (int off = 1; off < SCAN_B; off <<= 1) {
        int t = (threadIdx.x >= off) ? s[threadIdx.x - off] : 0;
        __syncthreads();
        s[threadIdx.x] += t;
        __syncthreads();
    }
    if (threadIdx.x < nb) bsums[threadIdx.x] = s[threadIdx.x] - v;
}

__global__ __launch_bounds__(SCAN_B) void scan3(
        const int* __restrict__ excl, const int* __restrict__ bsums,
        int* __restrict__ row_start, int* __restrict__ cursor, int N, int E) {
    int i = blockIdx.x * SCAN_B + threadIdx.x;
    if (i < N) {
        int v = excl[i] + bsums[blockIdx.x];
        row_start[i] = v;
        cursor[i] = v;
    }
    if (i == 0) row_start[N] = E;
}

// 8-byte edge record: {row | (i0<<17), half2(C*(1-fr), C*fr)}
__global__ __launch_bounds__(256) void build_edges(
        const int* __restrict__ er, const int* __restrict__ ec,
        const float* __restrict__ pos, int* __restrict__ cursor,
        uint2* __restrict__ ebuf, int E) {
    int e = blockIdx.x * blockDim.x + threadIdx.x;
    if (e >= E) return;
    int r = er[e], c = ec[e];
    float dx = pos[r * 3 + 0] - pos[c * 3 + 0];
    float dy = pos[r * 3 + 1] - pos[c * 3 + 1];
    float dz = pos[r * 3 + 2] - pos[c * 3 + 2];
    float d = sqrtf(dx * dx + dy * dy + dz * dz);
    float C = 0.5f * (cosf(d * (3.14159265358979323846f / CUTOFF_C)) + 1.0f);
    float t = fminf(d, DMAX) * ((TBL - 1) / DMAX);
    int i0 = (int)t;
    if (i0 > TBL - 2) i0 = TBL - 2;
    float fr = t - (float)i0;
    __half2 abh = __floats2half2_rn(C * (1.0f - fr), C * fr);
    int pos_ = atomicAdd(&cursor[c], 1);
    ebuf[pos_] = make_uint2((unsigned)r | ((unsigned)i0 << 17),
                            *(unsigned*)&abh);
}

// ---------------------------------------------------------------- edge gather
// aggb[i] = bf16( sum_j xfb[row_j]*(a*W0+b*W1) ); W pairs packed bf16x2 in tab2.
// 32 lanes/atom, 2 edges in flight.
__device__ __forceinline__ void edge_acc(
        unsigned ex, unsigned ey, const unsigned int* __restrict__ tab2,
        const unsigned short* __restrict__ xfb, int f4, float4& acc) {
    int r = ex & 0x1ffff, i0 = ex >> 17;
    float2 ab = __half22float2(*(__half2*)&ey);
    uint4 tp = *(const uint4*)(tab2 + (size_t)i0 * 128 + f4);
    const ushort4 xu = *(const ushort4*)(xfb + (size_t)r * 128 + f4);
    acc.x += bf2f(xu.x) * (ab.x * __uint_as_float(tp.x << 16) +
                           ab.y * __uint_as_float(tp.x & 0xffff0000u));
    acc.y += bf2f(xu.y) * (ab.x * __uint_as_float(tp.y << 16) +
                           ab.y * __uint_as_float(tp.y & 0xffff0000u));
    acc.z += bf2f(xu.z) * (ab.x * __uint_as_float(tp.z << 16) +
                           ab.y * __uint_as_float(tp.z & 0xffff0000u));
    acc.w += bf2f(xu.w) * (ab.x * __uint_as_float(tp.w << 16) +
                           ab.y * __uint_as_float(tp.w & 0xffff0000u));
}

__global__ __launch_bounds__(256) void edge_agg(
        const uint2* __restrict__ ebuf, const int* __restrict__ row_start,
        const unsigned short* __restrict__ xfb, const unsigned int* __restrict__ tab2,
        unsigned short* __restrict__ aggb, int N) {
    int tid = threadIdx.x;
    int atom = blockIdx.x * 8 + (tid >> 5);
    if (atom >= N) return;
    int f4 = (tid & 31) * 4;
    float4 a0 = make_float4(0.f, 0.f, 0.f, 0.f);
    float4 a1 = make_float4(0.f, 0.f, 0.f, 0.f);
    int j0 = row_start[atom], j1 = row_start[atom + 1];
    int j = j0;
    if (j < j1 && (j & 1)) {   // align to even for uint4 pair loads
        uint2 ed = ebuf[j];
        edge_acc(ed.x, ed.y, tab2, xfb, f4, a0);
        ++j;
    }
    for (; j + 1 < j1; j += 2) {
        uint4 e2 = *(const uint4*)(ebuf + j);
        edge_acc(e2.x, e2.y, tab2, xfb, f4, a0);
        edge_acc(e2.z, e2.w, tab2, xfb, f4, a1);
    }
    if (j < j1) {
        uint2 ed = ebuf[j];
        edge_acc(ed.x, ed.y, tab2, xfb, f4, a0);
    }
    a0.x += a1.x; a0.y += a1.y; a0.z += a1.z; a0.w += a1.w;
    unsigned short o[4] = {f2bf(a0.x), f2bf(a0.y), f2bf(a0.z), f2bf(a0.w)};
    *(uint2*)(aggb + (size_t)atom * 128 + f4) = *(const uint2*)o;
}

// ---------------------------------------------------------------- GEMM v2 (layer-0 xf)
#define MODE_BIAS     1
#define MODE_SSP_OUT  2
#define MODE_OUT_BF16 4

__global__ __launch_bounds__(256, 4) void gemm_v2(
        const float* __restrict__ A, const unsigned short* __restrict__ Bsw,
        const float* __restrict__ bias, float* __restrict__ OutF,
        unsigned short* __restrict__ OutB, int M, int mode) {
    __shared__ __align__(16) float smem[64 * 132];
    unsigned short* asw = (unsigned short*)smem;
    int tid = threadIdx.x;
    int m0 = blockIdx.x * 64;

    for (int i = tid; i < 1024; i += 256) {
        int ks = i >> 8, w = (i >> 6) & 3, ln = i & 63;
        int row = m0 + w * 16 + (ln & 15);
        int kb = ks * 32 + (ln >> 4) * 8;
        unsigned short tmp[8];
        if (row < M) {
            const float* ap = A + (size_t)row * 128 + kb;
            float4 v0 = *(const float4*)ap;
            float4 v1 = *(const float4*)(ap + 4);
            tmp[0] = f2bf(v0.x); tmp[1] = f2bf(v0.y);
            tmp[2] = f2bf(v0.z); tmp[3] = f2bf(v0.w);
            tmp[4] = f2bf(v1.x); tmp[5] = f2bf(v1.y);
            tmp[6] = f2bf(v1.z); tmp[7] = f2bf(v1.w);
        } else {
#pragma unroll
            for (int j = 0; j < 8; ++j) tmp[j] = 0;
        }
        *(uint4*)(asw + (size_t)i * 8) = *(const uint4*)tmp;
    }
    __syncthreads();

    int w = tid >> 6, ln = tid & 63;
    int quad = ln >> 4, l15 = ln & 15;
    f32x4 acc[8] = {};
#pragma unroll
    for (int ks = 0; ks < 4; ++ks) {
        bf16x8 af = *(const bf16x8*)(asw + ((ks * 4 + w) * 64 + ln) * 8);
#pragma unroll
        for (int j = 0; j < 8; ++j) {
            bf16x8 bf = *(const bf16x8*)(Bsw + (((ks * 8 + j) * 64) + ln) * 8);
            acc[j] = __builtin_amdgcn_mfma_f32_16x16x32_bf16(af, bf, acc[j], 0, 0, 0);
        }
    }
    __syncthreads();

#pragma unroll
    for (int j = 0; j < 8; ++j) {
        int col = j * 16 + l15;
        float bv = (mode & MODE_BIAS) ? bias[col] : 0.f;
#pragma unroll
        for (int r = 0; r < 4; ++r)
            smem[(w * 16 + quad * 4 + r) * 132 + col] = acc[j][r] + bv;
    }
    __syncthreads();

    for (int i = tid; i < 2048; i += 256) {
        int row = i >> 5, c4 = (i & 31) * 4;
        int grow = m0 + row;
        if (grow >= M) continue;
        float4 v = *(const float4*)(smem + row * 132 + c4);
        if (mode & MODE_SSP_OUT) {
            v.x = sspf(v.x); v.y = sspf(v.y); v.z = sspf(v.z); v.w = sspf(v.w);
        }
        if (mode & MODE_OUT_BF16) {
            unsigned short o[4] = {f2bf(v.x), f2bf(v.y), f2bf(v.z), f2bf(v.w)};
            *(uint2*)(OutB + (size_t)grow * 128 + c4) = *(const uint2*)o;
        } else {
            *(float4*)(OutF + (size_t)grow * 128 + c4) = v;
        }
    }
}

// ---------------------------------------------------------------- fused layer
__global__ __launch_bounds__(256, 4) void fused_layer(
        const unsigned short* __restrict__ aggb,
        const unsigned short* __restrict__ B1sw, const float* __restrict__ b1v,
        const unsigned short* __restrict__ B2sw, const float* __restrict__ b2v,
        const unsigned short* __restrict__ B3sw, const float* __restrict__ b3v,
        float* __restrict__ h, unsigned short* __restrict__ xfb_next,
        float* __restrict__ s_out, int M, int last) {
    __shared__ __align__(16) unsigned short frag[8192];         // 16 KB
    __shared__ __align__(16) unsigned short stg[64 * STG_STR];  // 17.5 KB
    int tid = threadIdx.x;
    int m0 = blockIdx.x * 64;

    // 1. stage aggb rows -> swizzled A-frags
    for (int i = tid; i < 1024; i += 256) {
        int ks = i >> 8, w_ = (i >> 6) & 3, ln_ = i & 63;
        int row = m0 + w_ * 16 + (ln_ & 15);
        int kb = ks * 32 + (ln_ >> 4) * 8;
        uint4 v = make_uint4(0, 0, 0, 0);
        if (row < M) v = *(const uint4*)(aggb + (size_t)row * 128 + kb);
        *(uint4*)(frag + swz(i) * 8) = v;
    }
    __syncthreads();

    int w = tid >> 6, ln = tid & 63;
    int quad = ln >> 4, l15 = ln & 15;

    // 2. conv2 MFMA
    f32x4 acc[8] = {};
#pragma unroll
    for (int ks = 0; ks < 4; ++ks) {
        bf16x8 af = *(const bf16x8*)(frag + swz((ks * 4 + w) * 64 + ln) * 8);
#pragma unroll
        for (int j = 0; j < 8; ++j) {
            bf16x8 bf = *(const bf16x8*)(B1sw + (((ks * 8 + j) * 64) + ln) * 8);
            acc[j] = __builtin_amdgcn_mfma_f32_16x16x32_bf16(af, bf, acc[j], 0, 0, 0);
        }
    }

    // 3. repack ssp(t1+b1) -> A-frags (own-wave chunks; intra-wave ordering)
#pragma unroll
    for (int j = 0; j < 8; ++j) {
        int col = j * 16 + l15;
        float bv = b1v[col];
        int ks2 = j >> 1;
        int quad2 = (col >> 3) & 3;
        int jj = l15 & 7;
        int cbase = (ks2 * 4 + w) * 64 + quad2 * 16 + quad * 4;
#pragma unroll
        for (int r = 0; r < 4; ++r) {
            float s = sspf(acc[j][r] + bv);
            frag[swz(cbase + r) * 8 + jj] = f2bf(s);
        }
    }

    // 4. int_lin MFMA
    f32x4 acc2[8] = {};
#pragma unroll
    for (int ks = 0; ks < 4; ++ks) {
        bf16x8 af = *(const bf16x8*)(frag + swz((ks * 4 + w) * 64 + ln) * 8);
#pragma unroll
        for (int j = 0; j < 8; ++j) {
            bf16x8 bf = *(const bf16x8*)(B2sw + (((ks * 8 + j) * 64) + ln) * 8);
            acc2[j] = __builtin_amdgcn_mfma_f32_16x16x32_bf16(af, bf, acc2[j], 0, 0, 0);
        }
    }

    // 5. stage x = bf16(acc2 + b2)
#pragma unroll
    for (int j = 0; j < 8; ++j) {
        int col = j * 16 + l15;
        float bv = b2v[col];
#pragma unroll
        for (int r = 0; r < 4; ++r)
            stg[(w * 16 + quad * 4 + r) * STG_STR + col] = f2bf(acc2[j][r] + bv);
    }
    __syncthreads();

    // 6. h += x; write bf16(h_new) A-frags (swizzled)
    for (int i = tid; i < 2048; i += 256) {
        int row = i >> 5, c4 = (i & 31) * 4;
        int grow = m0 + row;
        ushort4 xv = *(const ushort4*)(stg + row * STG_STR + c4);
        float4 v;
        v.x = bf2f(xv.x); v.y = bf2f(xv.y); v.z = bf2f(xv.z); v.w = bf2f(xv.w);
        if (grow < M) {
            float* hp = h + (size_t)grow * 128 + c4;
            float4 o = *(const float4*)hp;
            v.x += o.x; v.y += o.y; v.z += o.z; v.w += o.w;
            *(float4*)hp = v;
        } else {
            v = make_float4(0.f, 0.f, 0.f, 0.f);
        }
        unsigned short t4[4] = {f2bf(v.x), f2bf(v.y), f2bf(v.z), f2bf(v.w)};
        int w_ = row >> 4, l15_ = row & 15;
        int ks = c4 >> 5, q_ = (c4 >> 3) & 3, jj = c4 & 7;
        int c = (ks * 4 + w_) * 64 + q_ * 16 + l15_;
        *(uint2*)(frag + swz(c) * 8 + jj) = *(const uint2*)t4;
    }
    __syncthreads();

    // 7. next conv1 (or lin1) MFMA
    f32x4 acc3[8] = {};
#pragma unroll
    for (int ks = 0; ks < 4; ++ks) {
        bf16x8 af = *(const bf16x8*)(frag + swz((ks * 4 + w) * 64 + ln) * 8);
#pragma unroll
        for (int j = 0; j < 8; ++j) {
            bf16x8 bf = *(const bf16x8*)(B3sw + (((ks * 8 + j) * 64) + ln) * 8);
            acc3[j] = __builtin_amdgcn_mfma_f32_16x16x32_bf16(af, bf, acc3[j], 0, 0, 0);
        }
    }

    // 8. stage output bf16 (ssp before rounding on last layer)
#pragma unroll
    for (int j = 0; j < 8; ++j) {
        int col = j * 16 + l15;
        float bv = last ? b3v[col] : 0.f;
#pragma unroll
        for (int r = 0; r < 4; ++r) {
            float v = acc3[j][r] + bv;
            if (last) v = sspf(v);
            stg[(w * 16 + quad * 4 + r) * STG_STR + col] = f2bf(v);
        }
    }
    __syncthreads();

    // 9. write xfb_next (bf16) or s_out (fp32)
    for (int i = tid; i < 2048; i += 256) {
        int row = i >> 5, c4 = (i & 31) * 4;
        int grow = m0 + row;
        if (grow >= M) continue;
        ushort4 s4 = *(const ushort4*)(stg + row * STG_STR + c4);
        if (last) {
            float4 v;
            v.x = bf2f(s4.x); v.y = bf2f(s4.y); v.z = bf2f(s4.z); v.w = bf2f(s4.w);
            *(float4*)(s_out + (size_t)grow * 128 + c4) = v;
        } else {
            *(uint2*)(xfb_next + (size_t)grow * 128 + c4) = *(const uint2*)&s4;
        }
    }
}

// ---------------------------------------------------------------- atom -> mol sum
#define MR_ATOMS 32
__global__ __launch_bounds__(128) void mol_reduce(
        const float* __restrict__ s, const int* __restrict__ a2c,
        const int* __restrict__ c2m, float* __restrict__ mols,
        int* __restrict__ cnt, int N) {
    int f = threadIdx.x;
    int a0 = blockIdx.x * MR_ATOMS;
    int a1 = min(a0 + MR_ATOMS, N);
    float sum = 0.f;
    int cur = -1, run = 0;
    for (int a = a0; a < a1; ++a) {
        int m = c2m[a2c[a]];
        if (m != cur) {
            if (cur >= 0) {
                unsafeAtomicAdd(&mols[(size_t)cur * H_DIM + f], sum);
                if (f == 0) atomicAdd(&cnt[cur], run);
            }
            cur = m; sum = 0.f; run = 0;
        }
        sum += s[(size_t)a * H_DIM + f];
        ++run;
    }
    if (cur >= 0) {
        unsafeAtomicAdd(&mols[(size_t)cur * H_DIM + f], sum);
        if (f == 0) atomicAdd(&cnt[cur], run);
    }
}

// ---------------------------------------------------------------- head
__global__ __launch_bounds__(128) void head_kernel(
        const float* __restrict__ mols, const int* __restrict__ cnt,
        const float* __restrict__ l2w, const float* __restrict__ l2b,
        const float* __restrict__ hw1, const float* __restrict__ hb1,
        const float* __restrict__ hw2, const float* __restrict__ hb2,
        float* __restrict__ out) {
    int m = blockIdx.x, f = threadIdx.x;
    __shared__ float me[H_DIM];
    __shared__ float u[H_DIM / 2];
    const float* ms = mols + (size_t)m * H_DIM;
    float acc = l2b[f] * (float)cnt[m];
#pragma unroll 16
    for (int k = 0; k < H_DIM; ++k) acc += ms[k] * l2w[k * H_DIM + f];
    me[f] = acc;
    __syncthreads();
    if (f < 64) {
        float a2 = hb1[f];
#pragma unroll 16
        for (int k = 0; k < H_DIM; ++k) a2 += me[k] * hw1[k * 64 + f];
        u[f] = sspf(a2);
    }
    __syncthreads();
    if (f == 0) {
        float o = hb2[0];
#pragma unroll 16
        for (int j = 0; j < 64; ++j) o += u[j] * hw2[j];
        out[m] = o;
    }
}

// ---------------------------------------------------------------- launch
extern "C" void kernel_launch(void* const* d_in, const int* in_sizes, int n_in,
                              void* d_out, int out_size, void* d_ws, size_t ws_size,
                              hipStream_t stream) {
    const int*   z   = (const int*)d_in[0];
    const float* pos = (const float*)d_in[1];
    const int*   er  = (const int*)d_in[2];
    const int*   ec  = (const int*)d_in[3];
    const int*   a2c = (const int*)d_in[4];
    const int*   c2m = (const int*)d_in[5];
    const float* emb = (const float*)d_in[6];
    const float* w1  = (const float*)d_in[7];
    const float* b1  = (const float*)d_in[8];
    const float* w2  = (const float*)d_in[9];
    const float* b2  = (const float*)d_in[10];
    const float* c1w = (const float*)d_in[11];
    const float* c2w = (const float*)d_in[12];
    const float* c2b = (const float*)d_in[13];
    const float* iw  = (const float*)d_in[14];
    const float* ib  = (const float*)d_in[15];
    const float* l1w = (const float*)d_in[16];
    const float* l1b = (const float*)d_in[17];
    const float* l2w = (const float*)d_in[18];
    const float* l2b = (const float*)d_in[19];
    const float* hw1 = (const float*)d_in[20];
    const float* hb1 = (const float*)d_in[21];
    const float* hw2 = (const float*)d_in[22];
    const float* hb2 = (const float*)d_in[23];

    const int N  = in_sizes[0];
    const int E  = in_sizes[2];
    const int NM = out_size;
    float* out = (float*)d_out;

    // workspace layout (~89 MB)
    char* wsp = (char*)d_ws;
    uint2* ebuf = (uint2*)wsp;            wsp += (size_t)E * 8;
    unsigned int* tab2 = (unsigned int*)wsp;  wsp += (size_t)L_LAYERS * TBL * NF_DIM * 4;
    unsigned short* wbt = (unsigned short*)wsp;  wsp += (size_t)19 * 16384 * 2;
    float* h    = (float*)wsp;            wsp += (size_t)N * H_DIM * 4;
    unsigned short* xfb = (unsigned short*)wsp;  wsp += (size_t)N * H_DIM * 2;
    unsigned short* aggb = (unsigned short*)wsp; wsp += (size_t)N * H_DIM * 2;
    float* sbuf = (float*)wsp;            wsp += (size_t)N * H_DIM * 4;
    float* mols = (float*)wsp;            wsp += (size_t)NM * H_DIM * 4;
    int*   cnt_m = (int*)wsp;             wsp += (size_t)NM * 4;
    int*   ccnt  = (int*)wsp;             wsp += (size_t)N * 4;
    int*   row_start = (int*)wsp;         wsp += (size_t)(N + 1) * 4;
    int*   cursor = (int*)wsp;            wsp += (size_t)N * 4;
    int*   bsums  = (int*)wsp;            wsp += 256 * 4;
    int*   excl   = (int*)wsp;

    // --- CSR build (edges fixed across layers) ---
    hipMemsetAsync(ccnt, 0, (size_t)N * sizeof(int), stream);
    count_kernel<<<(E + 255) / 256, 256, 0, stream>>>(ec, ccnt, E);
    int nb = (N + SCAN_B - 1) / SCAN_B;
    scan1<<<nb, SCAN_B, 0, stream>>>(ccnt, excl, bsums, N);
    scan2<<<1, SCAN_B, 0, stream>>>(bsums, nb);
    scan3<<<nb, SCAN_B, 0, stream>>>(excl, bsums, row_start, cursor, N, E);
    build_edges<<<(E + 255) / 256, 256, 0, stream>>>(er, ec, pos, cursor, ebuf, E);

    build_tables<<<L_LAYERS * (TBL / T_PER), 128, 0, stream>>>(w1, b1, w2, b2, tab2);
    embed_kernel<<<(N * H_DIM + 255) / 256, 256, 0, stream>>>(z, emb, h, N);

    // --- weight prep: bf16 in MFMA B-fragment order ---
    prep_wt_sw<<<L_LAYERS, 256, 0, stream>>>(c1w, wbt);
    prep_wt_sw<<<L_LAYERS, 256, 0, stream>>>(c2w, wbt + (size_t)6 * 16384);
    prep_wt_sw<<<L_LAYERS, 256, 0, stream>>>(iw,  wbt + (size_t)12 * 16384);
    prep_wt_sw<<<1,        256, 0, stream>>>(l1w, wbt + (size_t)18 * 16384);

    int gblocks = (N + 63) / 64;
    // xf0 = bf16(h @ conv_lin1_w[0])
    gemm_v2<<<gblocks, 256, 0, stream>>>(
        h, wbt, nullptr, nullptr, xfb, N, MODE_OUT_BF16);

    for (int l = 0; l < L_LAYERS; ++l) {
        edge_agg<<<(N + 7) / 8, 256, 0, stream>>>(
            ebuf, row_start, xfb, tab2 + (size_t)l * TBL * NF_DIM, aggb, N);
        int last = (l == L_LAYERS - 1);
        const unsigned short* B3 = last ? wbt + (size_t)18 * 16384
                                        : wbt + (size_t)(l + 1) * 16384;
        fused_layer<<<gblocks, 256, 0, stream>>>(
            aggb,
            wbt + (size_t)(6 + l) * 16384,  c2b + (size_t)l * H_DIM,
            wbt + (size_t)(12 + l) * 16384, ib + (size_t)l * H_DIM,
            B3, l1b, h, xfb, sbuf, N, last);
    }

    hipMemsetAsync(mols, 0, (size_t)NM * H_DIM * sizeof(float) + NM * sizeof(int), stream);
    mol_reduce<<<(N + MR_ATOMS - 1) / MR_ATOMS, 128, 0, stream>>>(
        sbuf, a2c, c2m, mols, cnt_m, N);
    head_kernel<<<NM, 128, 0, stream>>>(mols, cnt_m, l2w, l2b, hw1, hb1, hw2, hb2, out);
}

// Round 8
// 680.952 us; speedup vs baseline: 10.6092x; 1.0189x over previous
//
#include <hip/hip_runtime.h>
#include <hip/hip_bf16.h>
#include <hip/hip_fp16.h>
#include <math.h>

#define H_DIM   128
#define NF_DIM  128
#define G_DIM   50
#define L_LAYERS 6
#define TBL     2048
#define DMAX    12.8f
#define CUTOFF_C 10.0f
#define COEFF_C (-0.5f * 49.0f * 49.0f / 100.0f)
#define SCAN_B  256
#define T_PER   16
#define T_PER2  (T_PER + 1)
#define STG_STR 140

typedef __bf16 bf16x8 __attribute__((ext_vector_type(8)));
typedef float  f32x4  __attribute__((ext_vector_type(4)));

__device__ __forceinline__ float sspf(float x) {
    float e = __expf(-fabsf(x));
    return fmaxf(x, 0.0f) + __logf(1.0f + e) - 0.69314718055994530942f;
}

__device__ __forceinline__ unsigned short f2bf(float f) {
    unsigned int u = __float_as_uint(f);
    u = (u + 0x7fffu + ((u >> 16) & 1u)) >> 16;   // RNE
    return (unsigned short)u;
}

__device__ __forceinline__ float bf2f(unsigned short u) {
    return __uint_as_float(((unsigned int)u) << 16);
}

// XOR bank-swizzle for 16B A-frag chunks (c < 1024)
__device__ __forceinline__ int swz(int c) {
    return c ^ ((c >> 3) & 7) ^ ((c >> 8) & 3);
}

// ---------------------------------------------------------------- filter tables
// Interleaved bf16 pair table: tab2[t][f] = (bf16(W[t+1][f])<<16)|bf16(W[t][f])
__global__ __launch_bounds__(128) void build_tables(
        const float* __restrict__ w1, const float* __restrict__ b1,
        const float* __restrict__ w2, const float* __restrict__ b2,
        unsigned int* __restrict__ tab2) {
    int l  = blockIdx.x / (TBL / T_PER);
    int t0 = (blockIdx.x % (TBL / T_PER)) * T_PER;
    int f  = threadIdx.x;  // 128
    __shared__ float sW1[G_DIM * 128];
    __shared__ float gs[T_PER2][G_DIM + 2];
    __shared__ float sy[T_PER2][130];
    for (int i = f; i < G_DIM * 128; i += 128)
        sW1[i] = w1[(size_t)l * G_DIM * 128 + i];
    if (f < G_DIM) {
        float o = f * (CUTOFF_C / (G_DIM - 1));
#pragma unroll
        for (int u = 0; u < T_PER2; ++u) {
            int t = t0 + u;
            if (t > TBL - 1) t = TBL - 1;
            float dt = t * (DMAX / (TBL - 1));
            float dd = dt - o;
            gs[u][f] = __expf(COEFF_C * dd * dd);
        }
    }
    __syncthreads();
    float y[T_PER2];
    float bb = b1[l * 128 + f];
#pragma unroll
    for (int u = 0; u < T_PER2; ++u) y[u] = bb;
    for (int g = 0; g < G_DIM; ++g) {
        float wv = sW1[g * 128 + f];
#pragma unroll
        for (int u = 0; u < T_PER2; ++u) y[u] += gs[u][g] * wv;
    }
#pragma unroll
    for (int u = 0; u < T_PER2; ++u) sy[u][f] = sspf(y[u]);
    __syncthreads();
    float acc[T_PER2];
    float b2v = b2[l * 128 + f];
#pragma unroll
    for (int u = 0; u < T_PER2; ++u) acc[u] = b2v;
    const float* W2 = w2 + (size_t)l * 16384;
    for (int k = 0; k < 128; ++k) {
        float wv = W2[k * 128 + f];
#pragma unroll
        for (int u = 0; u < T_PER2; ++u) acc[u] += sy[u][k] * wv;
    }
#pragma unroll
    for (int u = 0; u < T_PER; ++u) {
        unsigned int lo = f2bf(acc[u]);
        unsigned int hi = f2bf(acc[u + 1]);
        tab2[((size_t)l * TBL + t0 + u) * 128 + f] = (hi << 16) | lo;
    }
}

// ---------------------------------------------------------------- embedding
__global__ __launch_bounds__(256) void embed_kernel(
        const int* __restrict__ z, const float* __restrict__ emb,
        float* __restrict__ h, int N) {
    int idx = blockIdx.x * blockDim.x + threadIdx.x;
    if (idx >= N * H_DIM) return;
    int n = idx >> 7, f = idx & 127;
    h[idx] = emb[z[n] * H_DIM + f];
}

// ---------------------------------------------------------------- weight prep
__global__ __launch_bounds__(256) void prep_wt_sw(
        const float* __restrict__ W, unsigned short* __restrict__ Bsw) {
    int m = blockIdx.x;
    const float* src = W + (size_t)m * 16384;
    unsigned short* dst = Bsw + (size_t)m * 16384;
    for (int i = threadIdx.x; i < 16384; i += 256) {
        int jj = i & 7, lane = (i >> 3) & 63, j = (i >> 9) & 7, ks = i >> 12;
        int n = j * 16 + (lane & 15);
        int k = ks * 32 + ((lane >> 4) & 3) * 8 + jj;
        dst[i] = f2bf(src[k * 128 + n]);
    }
}

// ---------------------------------------------------------------- CSR build
// count + per-edge rank (old value of the atomic) in one pass
__global__ __launch_bounds__(256) void count_kernel(
        const int* __restrict__ ec, int* __restrict__ cnt,
        int* __restrict__ rank, int E) {
    int e = blockIdx.x * blockDim.x + threadIdx.x;
    if (e < E) rank[e] = atomicAdd(&cnt[ec[e]], 1);
}

__global__ __launch_bounds__(SCAN_B) void scan1(
        const int* __restrict__ cnt, int* __restrict__ excl,
        int* __restrict__ bsums, int N) {
    __shared__ int s[SCAN_B];
    int i = blockIdx.x * SCAN_B + threadIdx.x;
    int v = (i < N) ? cnt[i] : 0;
    s[threadIdx.x] = v;
    __syncthreads();
    for (int off = 1; off < SCAN_B; off <<= 1) {
        int t = (threadIdx.x >= off) ? s[threadIdx.x - off] : 0;
        __syncthreads();
        s[threadIdx.x] += t;
        __syncthreads();
    }
    if (i < N) excl[i] = s[threadIdx.x] - v;
    if (threadIdx.x == SCAN_B - 1) bsums[blockIdx.x] = s[SCAN_B - 1];
}

__global__ __launch_bounds__(SCAN_B) void scan2(int* __restrict__ bsums, int nb) {
    __shared__ int s[SCAN_B];
    int v = (threadIdx.x < nb) ? bsums[threadIdx.x] : 0;
    s[threadIdx.x] = v;
    __syncthreads();
    for (int off = 1; off < SCAN_B; off <<= 1) {
        int t = (threadIdx.x >= off) ? s[threadIdx.x - off] : 0;
        __syncthreads();
        s[threadIdx.x] += t;
        __syncthreads();
    }
    if (threadIdx.x < nb) bsums[threadIdx.x] = s[threadIdx.x] - v;
}

__global__ __launch_bounds__(SCAN_B) void scan3(
        const int* __restrict__ excl, const int* __restrict__ bsums,
        int* __restrict__ row_start, int N, int E) {
    int i = blockIdx.x * SCAN_B + threadIdx.x;
    if (i < N) row_start[i] = excl[i] + bsums[blockIdx.x];
    if (i == 0) row_start[N] = E;
}

// 8-byte edge record {row|(i0<<17), half2(a,b)} written to its CSR slot
// deterministically: slot = row_start[col] + rank[e]. No atomics.
__global__ __launch_bounds__(256) void build_edges(
        const int* __restrict__ er, const int* __restrict__ ec,
        const float* __restrict__ pos, const int* __restrict__ row_start,
        const int* __restrict__ rank, uint2* __restrict__ ebuf, int E) {
    int e = blockIdx.x * blockDim.x + threadIdx.x;
    if (e >= E) return;
    int r = er[e], c = ec[e];
    float dx = pos[r * 3 + 0] - pos[c * 3 + 0];
    float dy = pos[r * 3 + 1] - pos[c * 3 + 1];
    float dz = pos[r * 3 + 2] - pos[c * 3 + 2];
    float d = sqrtf(dx * dx + dy * dy + dz * dz);
    float C = 0.5f * (cosf(d * (3.14159265358979323846f / CUTOFF_C)) + 1.0f);
    float t = fminf(d, DMAX) * ((TBL - 1) / DMAX);
    int i0 = (int)t;
    if (i0 > TBL - 2) i0 = TBL - 2;
    float fr = t - (float)i0;
    __half2 abh = __floats2half2_rn(C * (1.0f - fr), C * fr);
    ebuf[row_start[c] + rank[e]] =
        make_uint2((unsigned)r | ((unsigned)i0 << 17), *(unsigned*)&abh);
}

// ---------------------------------------------------------------- edge gather
__device__ __forceinline__ void edge_acc(
        unsigned ex, unsigned ey, const unsigned int* __restrict__ tab2,
        const unsigned short* __restrict__ xfb, int f4, float4& acc) {
    int r = ex & 0x1ffff, i0 = ex >> 17;
    float2 ab = __half22float2(*(__half2*)&ey);
    uint4 tp = *(const uint4*)(tab2 + (size_t)i0 * 128 + f4);
    const ushort4 xu = *(const ushort4*)(xfb + (size_t)r * 128 + f4);
    acc.x += bf2f(xu.x) * (ab.x * __uint_as_float(tp.x << 16) +
                           ab.y * __uint_as_float(tp.x & 0xffff0000u));
    acc.y += bf2f(xu.y) * (ab.x * __uint_as_float(tp.y << 16) +
                           ab.y * __uint_as_float(tp.y & 0xffff0000u));
    acc.z += bf2f(xu.z) * (ab.x * __uint_as_float(tp.z << 16) +
                           ab.y * __uint_as_float(tp.z & 0xffff0000u));
    acc.w += bf2f(xu.w) * (ab.x * __uint_as_float(tp.w << 16) +
                           ab.y * __uint_as_float(tp.w & 0xffff0000u));
}

// 32 lanes/atom, 4 edges in flight (two uint4 record-pair loads, 4 accums)
__global__ __launch_bounds__(256) void edge_agg(
        const uint2* __restrict__ ebuf, const int* __restrict__ row_start,
        const unsigned short* __restrict__ xfb, const unsigned int* __restrict__ tab2,
        unsigned short* __restrict__ aggb, int N) {
    int tid = threadIdx.x;
    int atom = blockIdx.x * 8 + (tid >> 5);
    if (atom >= N) return;
    int f4 = (tid & 31) * 4;
    float4 a0 = make_float4(0.f, 0.f, 0.f, 0.f);
    float4 a1 = make_float4(0.f, 0.f, 0.f, 0.f);
    float4 a2 = make_float4(0.f, 0.f, 0.f, 0.f);
    float4 a3 = make_float4(0.f, 0.f, 0.f, 0.f);
    int j0 = row_start[atom], j1 = row_start[atom + 1];
    int j = j0;
    if (j < j1 && (j & 1)) {   // align to even for uint4 pair loads
        uint2 ed = ebuf[j];
        edge_acc(ed.x, ed.y, tab2, xfb, f4, a0);
        ++j;
    }
    for (; j + 3 < j1; j += 4) {
        uint4 e2 = *(const uint4*)(ebuf + j);
        uint4 e3 = *(const uint4*)(ebuf + j + 2);
        edge_acc(e2.x, e2.y, tab2, xfb, f4, a0);
        edge_acc(e2.z, e2.w, tab2, xfb, f4, a1);
        edge_acc(e3.x, e3.y, tab2, xfb, f4, a2);
        edge_acc(e3.z, e3.w, tab2, xfb, f4, a3);
    }
    if (j + 1 < j1) {
        uint4 e2 = *(const uint4*)(ebuf + j);
        edge_acc(e2.x, e2.y, tab2, xfb, f4, a0);
        edge_acc(e2.z, e2.w, tab2, xfb, f4, a1);
        j += 2;
    }
    if (j < j1) {
        uint2 ed = ebuf[j];
        edge_acc(ed.x, ed.y, tab2, xfb, f4, a0);
    }
    a0.x += a1.x + a2.x + a3.x;
    a0.y += a1.y + a2.y + a3.y;
    a0.z += a1.z + a2.z + a3.z;
    a0.w += a1.w + a2.w + a3.w;
    unsigned short o[4] = {f2bf(a0.x), f2bf(a0.y), f2bf(a0.z), f2bf(a0.w)};
    *(uint2*)(aggb + (size_t)atom * 128 + f4) = *(const uint2*)o;
}

// ---------------------------------------------------------------- GEMM v2 (layer-0 xf)
#define MODE_BIAS     1
#define MODE_SSP_OUT  2
#define MODE_OUT_BF16 4

__global__ __launch_bounds__(256, 4) void gemm_v2(
        const float* __restrict__ A, const unsigned short* __restrict__ Bsw,
        const float* __restrict__ bias, float* __restrict__ OutF,
        unsigned short* __restrict__ OutB, int M, int mode) {
    __shared__ __align__(16) float smem[64 * 132];
    unsigned short* asw = (unsigned short*)smem;
    int tid = threadIdx.x;
    int m0 = blockIdx.x * 64;

    for (int i = tid; i < 1024; i += 256) {
        int ks = i >> 8, w = (i >> 6) & 3, ln = i & 63;
        int row = m0 + w * 16 + (ln & 15);
        int kb = ks * 32 + (ln >> 4) * 8;
        unsigned short tmp[8];
        if (row < M) {
            const float* ap = A + (size_t)row * 128 + kb;
            float4 v0 = *(const float4*)ap;
            float4 v1 = *(const float4*)(ap + 4);
            tmp[0] = f2bf(v0.x); tmp[1] = f2bf(v0.y);
            tmp[2] = f2bf(v0.z); tmp[3] = f2bf(v0.w);
            tmp[4] = f2bf(v1.x); tmp[5] = f2bf(v1.y);
            tmp[6] = f2bf(v1.z); tmp[7] = f2bf(v1.w);
        } else {
#pragma unroll
            for (int j = 0; j < 8; ++j) tmp[j] = 0;
        }
        *(uint4*)(asw + (size_t)i * 8) = *(const uint4*)tmp;
    }
    __syncthreads();

    int w = tid >> 6, ln = tid & 63;
    int quad = ln >> 4, l15 = ln & 15;
    f32x4 acc[8] = {};
#pragma unroll
    for (int ks = 0; ks < 4; ++ks) {
        bf16x8 af = *(const bf16x8*)(asw + ((ks * 4 + w) * 64 + ln) * 8);
#pragma unroll
        for (int j = 0; j < 8; ++j) {
            bf16x8 bf = *(const bf16x8*)(Bsw + (((ks * 8 + j) * 64) + ln) * 8);
            acc[j] = __builtin_amdgcn_mfma_f32_16x16x32_bf16(af, bf, acc[j], 0, 0, 0);
        }
    }
    __syncthreads();

#pragma unroll
    for (int j = 0; j < 8; ++j) {
        int col = j * 16 + l15;
        float bv = (mode & MODE_BIAS) ? bias[col] : 0.f;
#pragma unroll
        for (int r = 0; r < 4; ++r)
            smem[(w * 16 + quad * 4 + r) * 132 + col] = acc[j][r] + bv;
    }
    __syncthreads();

    for (int i = tid; i < 2048; i += 256) {
        int row = i >> 5, c4 = (i & 31) * 4;
        int grow = m0 + row;
        if (grow >= M) continue;
        float4 v = *(const float4*)(smem + row * 132 + c4);
        if (mode & MODE_SSP_OUT) {
            v.x = sspf(v.x); v.y = sspf(v.y); v.z = sspf(v.z); v.w = sspf(v.w);
        }
        if (mode & MODE_OUT_BF16) {
            unsigned short o[4] = {f2bf(v.x), f2bf(v.y), f2bf(v.z), f2bf(v.w)};
            *(uint2*)(OutB + (size_t)grow * 128 + c4) = *(const uint2*)o;
        } else {
            *(float4*)(OutF + (size_t)grow * 128 + c4) = v;
        }
    }
}

// ---------------------------------------------------------------- fused layer
__global__ __launch_bounds__(256, 4) void fused_layer(
        const unsigned short* __restrict__ aggb,
        const unsigned short* __restrict__ B1sw, const float* __restrict__ b1v,
        const unsigned short* __restrict__ B2sw, const float* __restrict__ b2v,
        const unsigned short* __restrict__ B3sw, const float* __restrict__ b3v,
        float* __restrict__ h, unsigned short* __restrict__ xfb_next,
        float* __restrict__ s_out, int M, int last) {
    __shared__ __align__(16) unsigned short frag[8192];         // 16 KB
    __shared__ __align__(16) unsigned short stg[64 * STG_STR];  // 17.5 KB
    int tid = threadIdx.x;
    int m0 = blockIdx.x * 64;

    // 1. stage aggb rows -> swizzled A-frags
    for (int i = tid; i < 1024; i += 256) {
        int ks = i >> 8, w_ = (i >> 6) & 3, ln_ = i & 63;
        int row = m0 + w_ * 16 + (ln_ & 15);
        int kb = ks * 32 + (ln_ >> 4) * 8;
        uint4 v = make_uint4(0, 0, 0, 0);
        if (row < M) v = *(const uint4*)(aggb + (size_t)row * 128 + kb);
        *(uint4*)(frag + swz(i) * 8) = v;
    }
    __syncthreads();

    int w = tid >> 6, ln = tid & 63;
    int quad = ln >> 4, l15 = ln & 15;

    // 2. conv2 MFMA
    f32x4 acc[8] = {};
#pragma unroll
    for (int ks = 0; ks < 4; ++ks) {
        bf16x8 af = *(const bf16x8*)(frag + swz((ks * 4 + w) * 64 + ln) * 8);
#pragma unroll
        for (int j = 0; j < 8; ++j) {
            bf16x8 bf = *(const bf16x8*)(B1sw + (((ks * 8 + j) * 64) + ln) * 8);
            acc[j] = __builtin_amdgcn_mfma_f32_16x16x32_bf16(af, bf, acc[j], 0, 0, 0);
        }
    }

    // 3. repack ssp(t1+b1) -> A-frags (own-wave chunks; intra-wave ordering)
#pragma unroll
    for (int j = 0; j < 8; ++j) {
        int col = j * 16 + l15;
        float bv = b1v[col];
        int ks2 = j >> 1;
        int quad2 = (col >> 3) & 3;
        int jj = l15 & 7;
        int cbase = (ks2 * 4 + w) * 64 + quad2 * 16 + quad * 4;
#pragma unroll
        for (int r = 0; r < 4; ++r) {
            float s = sspf(acc[j][r] + bv);
            frag[swz(cbase + r) * 8 + jj] = f2bf(s);
        }
    }

    // 4. int_lin MFMA
    f32x4 acc2[8] = {};
#pragma unroll
    for (int ks = 0; ks < 4; ++ks) {
        bf16x8 af = *(const bf16x8*)(frag + swz((ks * 4 + w) * 64 + ln) * 8);
#pragma unroll
        for (int j = 0; j < 8; ++j) {
            bf16x8 bf = *(const bf16x8*)(B2sw + (((ks * 8 + j) * 64) + ln) * 8);
            acc2[j] = __builtin_amdgcn_mfma_f32_16x16x32_bf16(af, bf, acc2[j], 0, 0, 0);
        }
    }

    // 5. stage x = bf16(acc2 + b2)
#pragma unroll
    for (int j = 0; j < 8; ++j) {
        int col = j * 16 + l15;
        float bv = b2v[col];
#pragma unroll
        for (int r = 0; r < 4; ++r)
            stg[(w * 16 + quad * 4 + r) * STG_STR + col] = f2bf(acc2[j][r] + bv);
    }
    __syncthreads();

    // 6. h += x; write bf16(h_new) A-frags (swizzled)
    for (int i = tid; i < 2048; i += 256) {
        int row = i >> 5, c4 = (i & 31) * 4;
        int grow = m0 + row;
        ushort4 xv = *(const ushort4*)(stg + row * STG_STR + c4);
        float4 v;
        v.x = bf2f(xv.x); v.y = bf2f(xv.y); v.z = bf2f(xv.z); v.w = bf2f(xv.w);
        if (grow < M) {
            float* hp = h + (size_t)grow * 128 + c4;
            float4 o = *(const float4*)hp;
            v.x += o.x; v.y += o.y; v.z += o.z; v.w += o.w;
            *(float4*)hp = v;
        } else {
            v = make_float4(0.f, 0.f, 0.f, 0.f);
        }
        unsigned short t4[4] = {f2bf(v.x), f2bf(v.y), f2bf(v.z), f2bf(v.w)};
        int w_ = row >> 4, l15_ = row & 15;
        int ks = c4 >> 5, q_ = (c4 >> 3) & 3, jj = c4 & 7;
        int c = (ks * 4 + w_) * 64 + q_ * 16 + l15_;
        *(uint2*)(frag + swz(c) * 8 + jj) = *(const uint2*)t4;
    }
    __syncthreads();

    // 7. next conv1 (or lin1) MFMA
    f32x4 acc3[8] = {};
#pragma unroll
    for (int ks = 0; ks < 4; ++ks) {
        bf16x8 af = *(const bf16x8*)(frag + swz((ks * 4 + w) * 64 + ln) * 8);
#pragma unroll
        for (int j = 0; j < 8; ++j) {
            bf16x8 bf = *(const bf16x8*)(B3sw + (((ks * 8 + j) * 64) + ln) * 8);
            acc3[j] = __builtin_amdgcn_mfma_f32_16x16x32_bf16(af, bf, acc3[j], 0, 0, 0);
        }
    }

    // 8. stage output bf16 (ssp before rounding on last layer)
#pragma unroll
    for (int j = 0; j < 8; ++j) {
        int col = j * 16 + l15;
        float bv = last ? b3v[col] : 0.f;
#pragma unroll
        for (int r = 0; r < 4; ++r) {
            float v = acc3[j][r] + bv;
            if (last) v = sspf(v);
            stg[(w * 16 + quad * 4 + r) * STG_STR + col] = f2bf(v);
        }
    }
    __syncthreads();

    // 9. write xfb_next (bf16) or s_out (fp32)
    for (int i = tid; i < 2048; i += 256) {
        int row = i >> 5, c4 = (i & 31) * 4;
        int grow = m0 + row;
        if (grow >= M) continue;
        ushort4 s4 = *(const ushort4*)(stg + row * STG_STR + c4);
        if (last) {
            float4 v;
            v.x = bf2f(s4.x); v.y = bf2f(s4.y); v.z = bf2f(s4.z); v.w = bf2f(s4.w);
            *(float4*)(s_out + (size_t)grow * 128 + c4) = v;
        } else {
            *(uint2*)(xfb_next + (size_t)grow * 128 + c4) = *(const uint2*)&s4;
        }
    }
}

// ---------------------------------------------------------------- atom -> mol sum
#define MR_ATOMS 32
__global__ __launch_bounds__(128) void mol_reduce(
        const float* __restrict__ s, const int* __restrict__ a2c,
        const int* __restrict__ c2m, float* __restrict__ mols,
        int* __restrict__ cnt, int N) {
    int f = threadIdx.x;
    int a0 = blockIdx.x * MR_ATOMS;
    int a1 = min(a0 + MR_ATOMS, N);
    float sum = 0.f;
    int cur = -1, run = 0;
    for (int a = a0; a < a1; ++a) {
        int m = c2m[a2c[a]];
        if (m != cur) {
            if (cur >= 0) {
                unsafeAtomicAdd(&mols[(size_t)cur * H_DIM + f], sum);
                if (f == 0) atomicAdd(&cnt[cur], run);
            }
            cur = m; sum = 0.f; run = 0;
        }
        sum += s[(size_t)a * H_DIM + f];
        ++run;
    }
    if (cur >= 0) {
        unsafeAtomicAdd(&mols[(size_t)cur * H_DIM + f], sum);
        if (f == 0) atomicAdd(&cnt[cur], run);
    }
}

// ---------------------------------------------------------------- head
__global__ __launch_bounds__(128) void head_kernel(
        const float* __restrict__ mols, const int* __restrict__ cnt,
        const float* __restrict__ l2w, const float* __restrict__ l2b,
        const float* __restrict__ hw1, const float* __restrict__ hb1,
        const float* __restrict__ hw2, const float* __restrict__ hb2,
        float* __restrict__ out) {
    int m = blockIdx.x, f = threadIdx.x;
    __shared__ float me[H_DIM];
    __shared__ float u[H_DIM / 2];
    const float* ms = mols + (size_t)m * H_DIM;
    float acc = l2b[f] * (float)cnt[m];
#pragma unroll 16
    for (int k = 0; k < H_DIM; ++k) acc += ms[k] * l2w[k * H_DIM + f];
    me[f] = acc;
    __syncthreads();
    if (f < 64) {
        float a2 = hb1[f];
#pragma unroll 16
        for (int k = 0; k < H_DIM; ++k) a2 += me[k] * hw1[k * 64 + f];
        u[f] = sspf(a2);
    }
    __syncthreads();
    if (f == 0) {
        float o = hb2[0];
#pragma unroll 16
        for (int j = 0; j < 64; ++j) o += u[j] * hw2[j];
        out[m] = o;
    }
}

// ---------------------------------------------------------------- launch
extern "C" void kernel_launch(void* const* d_in, const int* in_sizes, int n_in,
                              void* d_out, int out_size, void* d_ws, size_t ws_size,
                              hipStream_t stream) {
    const int*   z   = (const int*)d_in[0];
    const float* pos = (const float*)d_in[1];
    const int*   er  = (const int*)d_in[2];
    const int*   ec  = (const int*)d_in[3];
    const int*   a2c = (const int*)d_in[4];
    const int*   c2m = (const int*)d_in[5];
    const float* emb = (const float*)d_in[6];
    const float* w1  = (const float*)d_in[7];
    const float* b1  = (const float*)d_in[8];
    const float* w2  = (const float*)d_in[9];
    const float* b2  = (const float*)d_in[10];
    const float* c1w = (const float*)d_in[11];
    const float* c2w = (const float*)d_in[12];
    const float* c2b = (const float*)d_in[13];
    const float* iw  = (const float*)d_in[14];
    const float* ib  = (const float*)d_in[15];
    const float* l1w = (const float*)d_in[16];
    const float* l1b = (const float*)d_in[17];
    const float* l2w = (const float*)d_in[18];
    const float* l2b = (const float*)d_in[19];
    const float* hw1 = (const float*)d_in[20];
    const float* hb1 = (const float*)d_in[21];
    const float* hw2 = (const float*)d_in[22];
    const float* hb2 = (const float*)d_in[23];

    const int N  = in_sizes[0];
    const int E  = in_sizes[2];
    const int NM = out_size;
    float* out = (float*)d_out;

    // workspace layout (~91 MB)
    char* wsp = (char*)d_ws;
    uint2* ebuf = (uint2*)wsp;            wsp += (size_t)E * 8;
    unsigned int* tab2 = (unsigned int*)wsp;  wsp += (size_t)L_LAYERS * TBL * NF_DIM * 4;
    unsigned short* wbt = (unsigned short*)wsp;  wsp += (size_t)19 * 16384 * 2;
    float* h    = (float*)wsp;            wsp += (size_t)N * H_DIM * 4;
    unsigned short* xfb = (unsigned short*)wsp;  wsp += (size_t)N * H_DIM * 2;
    unsigned short* aggb = (unsigned short*)wsp; wsp += (size_t)N * H_DIM * 2;
    float* sbuf = (float*)wsp;            wsp += (size_t)N * H_DIM * 4;
    float* mols = (float*)wsp;            wsp += (size_t)NM * H_DIM * 4;
    int*   cnt_m = (int*)wsp;             wsp += (size_t)NM * 4;
    int*   ccnt  = (int*)wsp;             wsp += (size_t)N * 4;
    int*   row_start = (int*)wsp;         wsp += (size_t)(N + 1) * 4;
    int*   rank  = (int*)wsp;             wsp += (size_t)E * 4;
    int*   bsums = (int*)wsp;             wsp += 256 * 4;
    int*   excl  = (int*)wsp;

    // --- CSR build (edges fixed across layers); rank-based, atomic-free scatter
    hipMemsetAsync(ccnt, 0, (size_t)N * sizeof(int), stream);
    count_kernel<<<(E + 255) / 256, 256, 0, stream>>>(ec, ccnt, rank, E);
    int nb = (N + SCAN_B - 1) / SCAN_B;
    scan1<<<nb, SCAN_B, 0, stream>>>(ccnt, excl, bsums, N);
    scan2<<<1, SCAN_B, 0, stream>>>(bsums, nb);
    scan3<<<nb, SCAN_B, 0, stream>>>(excl, bsums, row_start, N, E);
    build_edges<<<(E + 255) / 256, 256, 0, stream>>>(
        er, ec, pos, row_start, rank, ebuf, E);

    build_tables<<<L_LAYERS * (TBL / T_PER), 128, 0, stream>>>(w1, b1, w2, b2, tab2);
    embed_kernel<<<(N * H_DIM + 255) / 256, 256, 0, stream>>>(z, emb, h, N);

    // --- weight prep: bf16 in MFMA B-fragment order ---
    prep_wt_sw<<<L_LAYERS, 256, 0, stream>>>(c1w, wbt);
    prep_wt_sw<<<L_LAYERS, 256, 0, stream>>>(c2w, wbt + (size_t)6 * 16384);
    prep_wt_sw<<<L_LAYERS, 256, 0, stream>>>(iw,  wbt + (size_t)12 * 16384);
    prep_wt_sw<<<1,        256, 0, stream>>>(l1w, wbt + (size_t)18 * 16384);

    int gblocks = (N + 63) / 64;
    // xf0 = bf16(h @ conv_lin1_w[0])
    gemm_v2<<<gblocks, 256, 0, stream>>>(
        h, wbt, nullptr, nullptr, xfb, N, MODE_OUT_BF16);

    for (int l = 0; l < L_LAYERS; ++l) {
        edge_agg<<<(N + 7) / 8, 256, 0, stream>>>(
            ebuf, row_start, xfb, tab2 + (size_t)l * TBL * NF_DIM, aggb, N);
        int last = (l == L_LAYERS - 1);
        const unsigned short* B3 = last ? wbt + (size_t)18 * 16384
                                        : wbt + (size_t)(l + 1) * 16384;
        fused_layer<<<gblocks, 256, 0, stream>>>(
            aggb,
            wbt + (size_t)(6 + l) * 16384,  c2b + (size_t)l * H_DIM,
            wbt + (size_t)(12 + l) * 16384, ib + (size_t)l * H_DIM,
            B3, l1b, h, xfb, sbuf, N, last);
    }

    hipMemsetAsync(mols, 0, (size_t)NM * H_DIM * sizeof(float) + NM * sizeof(int), stream);
    mol_reduce<<<(N + MR_ATOMS - 1) / MR_ATOMS, 128, 0, stream>>>(
        sbuf, a2c, c2m, mols, cnt_m, N);
    head_kernel<<<NM, 128, 0, stream>>>(mols, cnt_m, l2w, l2b, hw1, hb1, hw2, hb2, out);
}

// Round 9
// 677.670 us; speedup vs baseline: 10.6606x; 1.0048x over previous
//
#include <hip/hip_runtime.h>
#include <hip/hip_bf16.h>
#include <hip/hip_fp16.h>
#include <math.h>

#define H_DIM   128
#define NF_DIM  128
#define G_DIM   50
#define L_LAYERS 6
#define TBL     2048
#define DMAX    12.8f
#define CUTOFF_C 10.0f
#define COEFF_C (-0.5f * 49.0f * 49.0f / 100.0f)
#define SCAN_B  256
#define T_PER   16
#define T_PER2  (T_PER + 1)
#define STG_STR 140

typedef __bf16 bf16x8 __attribute__((ext_vector_type(8)));
typedef float  f32x4  __attribute__((ext_vector_type(4)));

__device__ __forceinline__ float sspf(float x) {
    float e = __expf(-fabsf(x));
    return fmaxf(x, 0.0f) + __logf(1.0f + e) - 0.69314718055994530942f;
}

__device__ __forceinline__ unsigned short f2bf(float f) {
    unsigned int u = __float_as_uint(f);
    u = (u + 0x7fffu + ((u >> 16) & 1u)) >> 16;   // RNE
    return (unsigned short)u;
}

__device__ __forceinline__ float bf2f(unsigned short u) {
    return __uint_as_float(((unsigned int)u) << 16);
}

// XOR bank-swizzle for 16B A-frag chunks (c < 1024)
__device__ __forceinline__ int swz(int c) {
    return c ^ ((c >> 3) & 7) ^ ((c >> 8) & 3);
}

// ---------------------------------------------------------------- filter tables
// Interleaved bf16 pair table: tab2[t][f] = (bf16(W[t+1][f])<<16)|bf16(W[t][f])
__global__ __launch_bounds__(128) void build_tables(
        const float* __restrict__ w1, const float* __restrict__ b1,
        const float* __restrict__ w2, const float* __restrict__ b2,
        unsigned int* __restrict__ tab2) {
    int l  = blockIdx.x / (TBL / T_PER);
    int t0 = (blockIdx.x % (TBL / T_PER)) * T_PER;
    int f  = threadIdx.x;  // 128
    __shared__ float sW1[G_DIM * 128];
    __shared__ float gs[T_PER2][G_DIM + 2];
    __shared__ float sy[T_PER2][130];
    for (int i = f; i < G_DIM * 128; i += 128)
        sW1[i] = w1[(size_t)l * G_DIM * 128 + i];
    if (f < G_DIM) {
        float o = f * (CUTOFF_C / (G_DIM - 1));
#pragma unroll
        for (int u = 0; u < T_PER2; ++u) {
            int t = t0 + u;
            if (t > TBL - 1) t = TBL - 1;
            float dt = t * (DMAX / (TBL - 1));
            float dd = dt - o;
            gs[u][f] = __expf(COEFF_C * dd * dd);
        }
    }
    __syncthreads();
    float y[T_PER2];
    float bb = b1[l * 128 + f];
#pragma unroll
    for (int u = 0; u < T_PER2; ++u) y[u] = bb;
    for (int g = 0; g < G_DIM; ++g) {
        float wv = sW1[g * 128 + f];
#pragma unroll
        for (int u = 0; u < T_PER2; ++u) y[u] += gs[u][g] * wv;
    }
#pragma unroll
    for (int u = 0; u < T_PER2; ++u) sy[u][f] = sspf(y[u]);
    __syncthreads();
    float acc[T_PER2];
    float b2v = b2[l * 128 + f];
#pragma unroll
    for (int u = 0; u < T_PER2; ++u) acc[u] = b2v;
    const float* W2 = w2 + (size_t)l * 16384;
    for (int k = 0; k < 128; ++k) {
        float wv = W2[k * 128 + f];
#pragma unroll
        for (int u = 0; u < T_PER2; ++u) acc[u] += sy[u][k] * wv;
    }
#pragma unroll
    for (int u = 0; u < T_PER; ++u) {
        unsigned int lo = f2bf(acc[u]);
        unsigned int hi = f2bf(acc[u + 1]);
        tab2[((size_t)l * TBL + t0 + u) * 128 + f] = (hi << 16) | lo;
    }
}

// ---------------------------------------------------------------- embedding (bf16 h)
__global__ __launch_bounds__(256) void embed_kernel(
        const int* __restrict__ z, const float* __restrict__ emb,
        unsigned short* __restrict__ hb, int N) {
    int idx = blockIdx.x * blockDim.x + threadIdx.x;
    if (idx >= N * H_DIM) return;
    int n = idx >> 7, f = idx & 127;
    hb[idx] = f2bf(emb[z[n] * H_DIM + f]);
}

// ---------------------------------------------------------------- weight prep (all 19)
__global__ __launch_bounds__(256) void prep_wt_all(
        const float* __restrict__ c1w, const float* __restrict__ c2w,
        const float* __restrict__ iw, const float* __restrict__ l1w,
        unsigned short* __restrict__ Bsw) {
    int m = blockIdx.x;   // 0..18
    const float* src = (m < 6)  ? c1w + (size_t)m * 16384
                     : (m < 12) ? c2w + (size_t)(m - 6) * 16384
                     : (m < 18) ? iw  + (size_t)(m - 12) * 16384
                                : l1w;
    unsigned short* dst = Bsw + (size_t)m * 16384;
    for (int i = threadIdx.x; i < 16384; i += 256) {
        int jj = i & 7, lane = (i >> 3) & 63, j = (i >> 9) & 7, ks = i >> 12;
        int n = j * 16 + (lane & 15);
        int k = ks * 32 + ((lane >> 4) & 3) * 8 + jj;
        dst[i] = f2bf(src[k * 128 + n]);
    }
}

// ---------------------------------------------------------------- CSR build
__global__ __launch_bounds__(256) void count_kernel(
        const int* __restrict__ ec, int* __restrict__ cnt,
        int* __restrict__ rank, int E) {
    int e = blockIdx.x * blockDim.x + threadIdx.x;
    if (e < E) rank[e] = atomicAdd(&cnt[ec[e]], 1);
}

__global__ __launch_bounds__(SCAN_B) void scan1(
        const int* __restrict__ cnt, int* __restrict__ excl,
        int* __restrict__ bsums, int N) {
    __shared__ int s[SCAN_B];
    int i = blockIdx.x * SCAN_B + threadIdx.x;
    int v = (i < N) ? cnt[i] : 0;
    s[threadIdx.x] = v;
    __syncthreads();
    for (int off = 1; off < SCAN_B; off <<= 1) {
        int t = (threadIdx.x >= off) ? s[threadIdx.x - off] : 0;
        __syncthreads();
        s[threadIdx.x] += t;
        __syncthreads();
    }
    if (i < N) excl[i] = s[threadIdx.x] - v;
    if (threadIdx.x == SCAN_B - 1) bsums[blockIdx.x] = s[SCAN_B - 1];
}

__global__ __launch_bounds__(SCAN_B) void scan2(int* __restrict__ bsums, int nb) {
    __shared__ int s[SCAN_B];
    int v = (threadIdx.x < nb) ? bsums[threadIdx.x] : 0;
    s[threadIdx.x] = v;
    __syncthreads();
    for (int off = 1; off < SCAN_B; off <<= 1) {
        int t = (threadIdx.x >= off) ? s[threadIdx.x - off] : 0;
        __syncthreads();
        s[threadIdx.x] += t;
        __syncthreads();
    }
    if (threadIdx.x < nb) bsums[threadIdx.x] = s[threadIdx.x] - v;
}

__global__ __launch_bounds__(SCAN_B) void scan3(
        const int* __restrict__ excl, const int* __restrict__ bsums,
        int* __restrict__ row_start, int N, int E) {
    int i = blockIdx.x * SCAN_B + threadIdx.x;
    if (i < N) row_start[i] = excl[i] + bsums[blockIdx.x];
    if (i == 0) row_start[N] = E;
}

// 8-byte edge record {row|(i0<<17), half2(a,b)}; slot = row_start[col]+rank[e]
__global__ __launch_bounds__(256) void build_edges(
        const int* __restrict__ er, const int* __restrict__ ec,
        const float* __restrict__ pos, const int* __restrict__ row_start,
        const int* __restrict__ rank, uint2* __restrict__ ebuf, int E) {
    int e = blockIdx.x * blockDim.x + threadIdx.x;
    if (e >= E) return;
    int r = er[e], c = ec[e];
    float dx = pos[r * 3 + 0] - pos[c * 3 + 0];
    float dy = pos[r * 3 + 1] - pos[c * 3 + 1];
    float dz = pos[r * 3 + 2] - pos[c * 3 + 2];
    float d = sqrtf(dx * dx + dy * dy + dz * dz);
    float C = 0.5f * (cosf(d * (3.14159265358979323846f / CUTOFF_C)) + 1.0f);
    float t = fminf(d, DMAX) * ((TBL - 1) / DMAX);
    int i0 = (int)t;
    if (i0 > TBL - 2) i0 = TBL - 2;
    float fr = t - (float)i0;
    __half2 abh = __floats2half2_rn(C * (1.0f - fr), C * fr);
    ebuf[row_start[c] + rank[e]] =
        make_uint2((unsigned)r | ((unsigned)i0 << 17), *(unsigned*)&abh);
}

// ---------------------------------------------------------------- edge gather
__device__ __forceinline__ void edge_acc(
        unsigned ex, unsigned ey, const unsigned int* __restrict__ tab2,
        const unsigned short* __restrict__ xfb, int f4, float4& acc) {
    int r = ex & 0x1ffff, i0 = ex >> 17;
    float2 ab = __half22float2(*(__half2*)&ey);
    uint4 tp = *(const uint4*)(tab2 + (size_t)i0 * 128 + f4);
    const ushort4 xu = *(const ushort4*)(xfb + (size_t)r * 128 + f4);
    acc.x += bf2f(xu.x) * (ab.x * __uint_as_float(tp.x << 16) +
                           ab.y * __uint_as_float(tp.x & 0xffff0000u));
    acc.y += bf2f(xu.y) * (ab.x * __uint_as_float(tp.y << 16) +
                           ab.y * __uint_as_float(tp.y & 0xffff0000u));
    acc.z += bf2f(xu.z) * (ab.x * __uint_as_float(tp.z << 16) +
                           ab.y * __uint_as_float(tp.z & 0xffff0000u));
    acc.w += bf2f(xu.w) * (ab.x * __uint_as_float(tp.w << 16) +
                           ab.y * __uint_as_float(tp.w & 0xffff0000u));
}

// 32 lanes/atom, 8 edges in flight (four uint4 record-pair loads, 4 accums)
__global__ __launch_bounds__(256) void edge_agg(
        const uint2* __restrict__ ebuf, const int* __restrict__ row_start,
        const unsigned short* __restrict__ xfb, const unsigned int* __restrict__ tab2,
        unsigned short* __restrict__ aggb, int N) {
    int tid = threadIdx.x;
    int atom = blockIdx.x * 8 + (tid >> 5);
    if (atom >= N) return;
    int f4 = (tid & 31) * 4;
    float4 a0 = make_float4(0.f, 0.f, 0.f, 0.f);
    float4 a1 = make_float4(0.f, 0.f, 0.f, 0.f);
    float4 a2 = make_float4(0.f, 0.f, 0.f, 0.f);
    float4 a3 = make_float4(0.f, 0.f, 0.f, 0.f);
    int j0 = row_start[atom], j1 = row_start[atom + 1];
    int j = j0;
    if (j < j1 && (j & 1)) {   // align to even for uint4 pair loads
        uint2 ed = ebuf[j];
        edge_acc(ed.x, ed.y, tab2, xfb, f4, a0);
        ++j;
    }
    for (; j + 7 < j1; j += 8) {
        uint4 e0 = *(const uint4*)(ebuf + j);
        uint4 e1 = *(const uint4*)(ebuf + j + 2);
        uint4 e2 = *(const uint4*)(ebuf + j + 4);
        uint4 e3 = *(const uint4*)(ebuf + j + 6);
        edge_acc(e0.x, e0.y, tab2, xfb, f4, a0);
        edge_acc(e0.z, e0.w, tab2, xfb, f4, a1);
        edge_acc(e1.x, e1.y, tab2, xfb, f4, a2);
        edge_acc(e1.z, e1.w, tab2, xfb, f4, a3);
        edge_acc(e2.x, e2.y, tab2, xfb, f4, a0);
        edge_acc(e2.z, e2.w, tab2, xfb, f4, a1);
        edge_acc(e3.x, e3.y, tab2, xfb, f4, a2);
        edge_acc(e3.z, e3.w, tab2, xfb, f4, a3);
    }
    if (j + 3 < j1) {
        uint4 e0 = *(const uint4*)(ebuf + j);
        uint4 e1 = *(const uint4*)(ebuf + j + 2);
        edge_acc(e0.x, e0.y, tab2, xfb, f4, a0);
        edge_acc(e0.z, e0.w, tab2, xfb, f4, a1);
        edge_acc(e1.x, e1.y, tab2, xfb, f4, a2);
        edge_acc(e1.z, e1.w, tab2, xfb, f4, a3);
        j += 4;
    }
    if (j + 1 < j1) {
        uint4 e0 = *(const uint4*)(ebuf + j);
        edge_acc(e0.x, e0.y, tab2, xfb, f4, a0);
        edge_acc(e0.z, e0.w, tab2, xfb, f4, a1);
        j += 2;
    }
    if (j < j1) {
        uint2 ed = ebuf[j];
        edge_acc(ed.x, ed.y, tab2, xfb, f4, a0);
    }
    a0.x += a1.x + a2.x + a3.x;
    a0.y += a1.y + a2.y + a3.y;
    a0.z += a1.z + a2.z + a3.z;
    a0.w += a1.w + a2.w + a3.w;
    unsigned short o[4] = {f2bf(a0.x), f2bf(a0.y), f2bf(a0.z), f2bf(a0.w)};
    *(uint2*)(aggb + (size_t)atom * 128 + f4) = *(const uint2*)o;
}

// ---------------------------------------------------------------- layer-0 GEMM
// xfb = bf16( hb @ B )   (hb bf16, Bsw frag-ordered)
__global__ __launch_bounds__(256, 4) void gemm_l0(
        const unsigned short* __restrict__ hb, const unsigned short* __restrict__ Bsw,
        unsigned short* __restrict__ xfb, int M) {
    __shared__ __align__(16) unsigned short frag[8192];
    __shared__ __align__(16) unsigned short stg[64 * STG_STR];
    int tid = threadIdx.x;
    int m0 = blockIdx.x * 64;
    for (int i = tid; i < 1024; i += 256) {
        int ks = i >> 8, w_ = (i >> 6) & 3, ln_ = i & 63;
        int row = m0 + w_ * 16 + (ln_ & 15);
        int kb = ks * 32 + (ln_ >> 4) * 8;
        uint4 v = make_uint4(0, 0, 0, 0);
        if (row < M) v = *(const uint4*)(hb + (size_t)row * 128 + kb);
        *(uint4*)(frag + swz(i) * 8) = v;
    }
    __syncthreads();
    int w = tid >> 6, ln = tid & 63;
    int quad = ln >> 4, l15 = ln & 15;
    f32x4 acc[8] = {};
#pragma unroll
    for (int ks = 0; ks < 4; ++ks) {
        bf16x8 af = *(const bf16x8*)(frag + swz((ks * 4 + w) * 64 + ln) * 8);
#pragma unroll
        for (int j = 0; j < 8; ++j) {
            bf16x8 bf = *(const bf16x8*)(Bsw + (((ks * 8 + j) * 64) + ln) * 8);
            acc[j] = __builtin_amdgcn_mfma_f32_16x16x32_bf16(af, bf, acc[j], 0, 0, 0);
        }
    }
#pragma unroll
    for (int j = 0; j < 8; ++j) {
        int col = j * 16 + l15;
#pragma unroll
        for (int r = 0; r < 4; ++r)
            stg[(w * 16 + quad * 4 + r) * STG_STR + col] = f2bf(acc[j][r]);
    }
    __syncthreads();
    for (int i = tid; i < 2048; i += 256) {
        int row = i >> 5, c4 = (i & 31) * 4;
        int grow = m0 + row;
        if (grow >= M) continue;
        ushort4 s4 = *(const ushort4*)(stg + row * STG_STR + c4);
        *(uint2*)(xfb + (size_t)grow * 128 + c4) = *(const uint2*)&s4;
    }
}

// ---------------------------------------------------------------- fused layer
// t1 = aggb@c2w+c2b; x = ssp(t1)@iw+ib; h += x (h bf16);
// then xfb_next = bf16(h@B3) (mid) or s_out = ssp(h@B3+b3) fp32 (last).
__global__ __launch_bounds__(256, 4) void fused_layer(
        const unsigned short* __restrict__ aggb,
        const unsigned short* __restrict__ B1sw, const float* __restrict__ b1v,
        const unsigned short* __restrict__ B2sw, const float* __restrict__ b2v,
        const unsigned short* __restrict__ B3sw, const float* __restrict__ b3v,
        unsigned short* __restrict__ hb, unsigned short* __restrict__ xfb_next,
        float* __restrict__ s_out, int M, int last) {
    __shared__ __align__(16) unsigned short frag[8192];         // 16 KB
    __shared__ __align__(16) unsigned short stg[64 * STG_STR];  // 17.5 KB
    int tid = threadIdx.x;
    int m0 = blockIdx.x * 64;

    // 1. stage aggb rows -> swizzled A-frags
    for (int i = tid; i < 1024; i += 256) {
        int ks = i >> 8, w_ = (i >> 6) & 3, ln_ = i & 63;
        int row = m0 + w_ * 16 + (ln_ & 15);
        int kb = ks * 32 + (ln_ >> 4) * 8;
        uint4 v = make_uint4(0, 0, 0, 0);
        if (row < M) v = *(const uint4*)(aggb + (size_t)row * 128 + kb);
        *(uint4*)(frag + swz(i) * 8) = v;
    }
    __syncthreads();

    int w = tid >> 6, ln = tid & 63;
    int quad = ln >> 4, l15 = ln & 15;

    // 2. conv2 MFMA
    f32x4 acc[8] = {};
#pragma unroll
    for (int ks = 0; ks < 4; ++ks) {
        bf16x8 af = *(const bf16x8*)(frag + swz((ks * 4 + w) * 64 + ln) * 8);
#pragma unroll
        for (int j = 0; j < 8; ++j) {
            bf16x8 bf = *(const bf16x8*)(B1sw + (((ks * 8 + j) * 64) + ln) * 8);
            acc[j] = __builtin_amdgcn_mfma_f32_16x16x32_bf16(af, bf, acc[j], 0, 0, 0);
        }
    }

    // 3. repack ssp(t1+b1) -> A-frags (own-wave chunks)
#pragma unroll
    for (int j = 0; j < 8; ++j) {
        int col = j * 16 + l15;
        float bv = b1v[col];
        int ks2 = j >> 1;
        int quad2 = (col >> 3) & 3;
        int jj = l15 & 7;
        int cbase = (ks2 * 4 + w) * 64 + quad2 * 16 + quad * 4;
#pragma unroll
        for (int r = 0; r < 4; ++r) {
            float s = sspf(acc[j][r] + bv);
            frag[swz(cbase + r) * 8 + jj] = f2bf(s);
        }
    }

    // 4. int_lin MFMA
    f32x4 acc2[8] = {};
#pragma unroll
    for (int ks = 0; ks < 4; ++ks) {
        bf16x8 af = *(const bf16x8*)(frag + swz((ks * 4 + w) * 64 + ln) * 8);
#pragma unroll
        for (int j = 0; j < 8; ++j) {
            bf16x8 bf = *(const bf16x8*)(B2sw + (((ks * 8 + j) * 64) + ln) * 8);
            acc2[j] = __builtin_amdgcn_mfma_f32_16x16x32_bf16(af, bf, acc2[j], 0, 0, 0);
        }
    }

    // 5. stage x = bf16(acc2 + b2)
#pragma unroll
    for (int j = 0; j < 8; ++j) {
        int col = j * 16 + l15;
        float bv = b2v[col];
#pragma unroll
        for (int r = 0; r < 4; ++r)
            stg[(w * 16 + quad * 4 + r) * STG_STR + col] = f2bf(acc2[j][r] + bv);
    }
    __syncthreads();

    // 6. h += x (bf16 h, fp32 add); write bf16(h_new) A-frags (swizzled)
    for (int i = tid; i < 2048; i += 256) {
        int row = i >> 5, c4 = (i & 31) * 4;
        int grow = m0 + row;
        ushort4 xv = *(const ushort4*)(stg + row * STG_STR + c4);
        unsigned short t4[4];
        if (grow < M) {
            unsigned short* hp = hb + (size_t)grow * 128 + c4;
            ushort4 hv = *(const ushort4*)hp;
            t4[0] = f2bf(bf2f(hv.x) + bf2f(xv.x));
            t4[1] = f2bf(bf2f(hv.y) + bf2f(xv.y));
            t4[2] = f2bf(bf2f(hv.z) + bf2f(xv.z));
            t4[3] = f2bf(bf2f(hv.w) + bf2f(xv.w));
            *(uint2*)hp = *(const uint2*)t4;
        } else {
            t4[0] = t4[1] = t4[2] = t4[3] = 0;
        }
        int w_ = row >> 4, l15_ = row & 15;
        int ks = c4 >> 5, q_ = (c4 >> 3) & 3, jj = c4 & 7;
        int c = (ks * 4 + w_) * 64 + q_ * 16 + l15_;
        *(uint2*)(frag + swz(c) * 8 + jj) = *(const uint2*)t4;
    }
    __syncthreads();

    // 7. next conv1 (or lin1) MFMA
    f32x4 acc3[8] = {};
#pragma unroll
    for (int ks = 0; ks < 4; ++ks) {
        bf16x8 af = *(const bf16x8*)(frag + swz((ks * 4 + w) * 64 + ln) * 8);
#pragma unroll
        for (int j = 0; j < 8; ++j) {
            bf16x8 bf = *(const bf16x8*)(B3sw + (((ks * 8 + j) * 64) + ln) * 8);
            acc3[j] = __builtin_amdgcn_mfma_f32_16x16x32_bf16(af, bf, acc3[j], 0, 0, 0);
        }
    }

    // 8. stage output bf16 (ssp in fp32 before rounding on last layer)
#pragma unroll
    for (int j = 0; j < 8; ++j) {
        int col = j * 16 + l15;
        float bv = last ? b3v[col] : 0.f;
#pragma unroll
        for (int r = 0; r < 4; ++r) {
            float v = acc3[j][r] + bv;
            if (last) v = sspf(v);
            stg[(w * 16 + quad * 4 + r) * STG_STR + col] = f2bf(v);
        }
    }
    __syncthreads();

    // 9. write xfb_next (bf16) or s_out (fp32)
    for (int i = tid; i < 2048; i += 256) {
        int row = i >> 5, c4 = (i & 31) * 4;
        int grow = m0 + row;
        if (grow >= M) continue;
        ushort4 s4 = *(const ushort4*)(stg + row * STG_STR + c4);
        if (last) {
            float4 v;
            v.x = bf2f(s4.x); v.y = bf2f(s4.y); v.z = bf2f(s4.z); v.w = bf2f(s4.w);
            *(float4*)(s_out + (size_t)grow * 128 + c4) = v;
        } else {
            *(uint2*)(xfb_next + (size_t)grow * 128 + c4) = *(const uint2*)&s4;
        }
    }
}

// ---------------------------------------------------------------- atom -> mol sum
#define MR_ATOMS 32
__global__ __launch_bounds__(128) void mol_reduce(
        const float* __restrict__ s, const int* __restrict__ a2c,
        const int* __restrict__ c2m, float* __restrict__ mols,
        int* __restrict__ cnt, int N) {
    int f = threadIdx.x;
    int a0 = blockIdx.x * MR_ATOMS;
    int a1 = min(a0 + MR_ATOMS, N);
    float sum = 0.f;
    int cur = -1, run = 0;
    for (int a = a0; a < a1; ++a) {
        int m = c2m[a2c[a]];
        if (m != cur) {
            if (cur >= 0) {
                unsafeAtomicAdd(&mols[(size_t)cur * H_DIM + f], sum);
                if (f == 0) atomicAdd(&cnt[cur], run);
            }
            cur = m; sum = 0.f; run = 0;
        }
        sum += s[(size_t)a * H_DIM + f];
        ++run;
    }
    if (cur >= 0) {
        unsafeAtomicAdd(&mols[(size_t)cur * H_DIM + f], sum);
        if (f == 0) atomicAdd(&cnt[cur], run);
    }
}

// ---------------------------------------------------------------- head
__global__ __launch_bounds__(128) void head_kernel(
        const float* __restrict__ mols, const int* __restrict__ cnt,
        const float* __restrict__ l2w, const float* __restrict__ l2b,
        const float* __restrict__ hw1, const float* __restrict__ hb1,
        const float* __restrict__ hw2, const float* __restrict__ hb2,
        float* __restrict__ out) {
    int m = blockIdx.x, f = threadIdx.x;
    __shared__ float me[H_DIM];
    __shared__ float u[H_DIM / 2];
    const float* ms = mols + (size_t)m * H_DIM;
    float acc = l2b[f] * (float)cnt[m];
#pragma unroll 16
    for (int k = 0; k < H_DIM; ++k) acc += ms[k] * l2w[k * H_DIM + f];
    me[f] = acc;
    __syncthreads();
    if (f < 64) {
        float a2 = hb1[f];
#pragma unroll 16
        for (int k = 0; k < H_DIM; ++k) a2 += me[k] * hw1[k * 64 + f];
        u[f] = sspf(a2);
    }
    __syncthreads();
    if (f == 0) {
        float o = hb2[0];
#pragma unroll 16
        for (int j = 0; j < 64; ++j) o += u[j] * hw2[j];
        out[m] = o;
    }
}

// ---------------------------------------------------------------- launch
extern "C" void kernel_launch(void* const* d_in, const int* in_sizes, int n_in,
                              void* d_out, int out_size, void* d_ws, size_t ws_size,
                              hipStream_t stream) {
    const int*   z   = (const int*)d_in[0];
    const float* pos = (const float*)d_in[1];
    const int*   er  = (const int*)d_in[2];
    const int*   ec  = (const int*)d_in[3];
    const int*   a2c = (const int*)d_in[4];
    const int*   c2m = (const int*)d_in[5];
    const float* emb = (const float*)d_in[6];
    const float* w1  = (const float*)d_in[7];
    const float* b1  = (const float*)d_in[8];
    const float* w2  = (const float*)d_in[9];
    const float* b2  = (const float*)d_in[10];
    const float* c1w = (const float*)d_in[11];
    const float* c2w = (const float*)d_in[12];
    const float* c2b = (const float*)d_in[13];
    const float* iw  = (const float*)d_in[14];
    const float* ib  = (const float*)d_in[15];
    const float* l1w = (const float*)d_in[16];
    const float* l1b = (const float*)d_in[17];
    const float* l2w = (const float*)d_in[18];
    const float* l2b = (const float*)d_in[19];
    const float* hw1 = (const float*)d_in[20];
    const float* hb1 = (const float*)d_in[21];
    const float* hw2 = (const float*)d_in[22];
    const float* hb2 = (const float*)d_in[23];

    const int N  = in_sizes[0];
    const int E  = in_sizes[2];
    const int NM = out_size;
    float* out = (float*)d_out;

    // workspace layout (~78 MB)
    char* wsp = (char*)d_ws;
    uint2* ebuf = (uint2*)wsp;            wsp += (size_t)E * 8;
    unsigned int* tab2 = (unsigned int*)wsp;  wsp += (size_t)L_LAYERS * TBL * NF_DIM * 4;
    unsigned short* wbt = (unsigned short*)wsp;  wsp += (size_t)19 * 16384 * 2;
    unsigned short* hb  = (unsigned short*)wsp;  wsp += (size_t)N * H_DIM * 2;
    unsigned short* xfb = (unsigned short*)wsp;  wsp += (size_t)N * H_DIM * 2;
    unsigned short* aggb = (unsigned short*)wsp; wsp += (size_t)N * H_DIM * 2;
    float* sbuf = (float*)wsp;            wsp += (size_t)N * H_DIM * 4;
    float* mols = (float*)wsp;            wsp += (size_t)NM * H_DIM * 4;
    int*   cnt_m = (int*)wsp;             wsp += (size_t)NM * 4;
    int*   ccnt  = (int*)wsp;             wsp += (size_t)N * 4;
    int*   row_start = (int*)wsp;         wsp += (size_t)(N + 1) * 4;
    int*   rank  = (int*)wsp;             wsp += (size_t)E * 4;
    int*   bsums = (int*)wsp;             wsp += 256 * 4;
    int*   excl  = (int*)wsp;

    // --- CSR build (rank-based, atomic-free scatter) ---
    hipMemsetAsync(ccnt, 0, (size_t)N * sizeof(int), stream);
    count_kernel<<<(E + 255) / 256, 256, 0, stream>>>(ec, ccnt, rank, E);
    int nb = (N + SCAN_B - 1) / SCAN_B;
    scan1<<<nb, SCAN_B, 0, stream>>>(ccnt, excl, bsums, N);
    scan2<<<1, SCAN_B, 0, stream>>>(bsums, nb);
    scan3<<<nb, SCAN_B, 0, stream>>>(excl, bsums, row_start, N, E);
    build_edges<<<(E + 255) / 256, 256, 0, stream>>>(
        er, ec, pos, row_start, rank, ebuf, E);

    build_tables<<<L_LAYERS * (TBL / T_PER), 128, 0, stream>>>(w1, b1, w2, b2, tab2);
    embed_kernel<<<(N * H_DIM + 255) / 256, 256, 0, stream>>>(z, emb, hb, N);
    prep_wt_all<<<19, 256, 0, stream>>>(c1w, c2w, iw, l1w, wbt);

    int gblocks = (N + 63) / 64;
    // xf0 = bf16(h @ conv_lin1_w[0])
    gemm_l0<<<gblocks, 256, 0, stream>>>(hb, wbt, xfb, N);

    for (int l = 0; l < L_LAYERS; ++l) {
        edge_agg<<<(N + 7) / 8, 256, 0, stream>>>(
            ebuf, row_start, xfb, tab2 + (size_t)l * TBL * NF_DIM, aggb, N);
        int last = (l == L_LAYERS - 1);
        const unsigned short* B3 = last ? wbt + (size_t)18 * 16384
                                        : wbt + (size_t)(l + 1) * 16384;
        fused_layer<<<gblocks, 256, 0, stream>>>(
            aggb,
            wbt + (size_t)(6 + l) * 16384,  c2b + (size_t)l * H_DIM,
            wbt + (size_t)(12 + l) * 16384, ib + (size_t)l * H_DIM,
            B3, l1b, hb, xfb, sbuf, N, last);
    }

    hipMemsetAsync(mols, 0, (size_t)NM * H_DIM * sizeof(float) + NM * sizeof(int), stream);
    mol_reduce<<<(N + MR_ATOMS - 1) / MR_ATOMS, 128, 0, stream>>>(
        sbuf, a2c, c2m, mols, cnt_m, N);
    head_kernel<<<NM, 128, 0, stream>>>(mols, cnt_m, l2w, l2b, hw1, hb1, hw2, hb2, out);
}

// Round 10
// 675.994 us; speedup vs baseline: 10.6870x; 1.0025x over previous
//
#include <hip/hip_runtime.h>
#include <hip/hip_bf16.h>
#include <hip/hip_fp16.h>
#include <math.h>

#define H_DIM   128
#define NF_DIM  128
#define G_DIM   50
#define L_LAYERS 6
#define TBL     1024       // 512 KB/layer bf16-pair table -> L2-resident per XCD
#define DMAX    12.8f
#define CUTOFF_C 10.0f
#define COEFF_C (-0.5f * 49.0f * 49.0f / 100.0f)
#define SCAN_B  256
#define T_PER   16
#define T_PER2  (T_PER + 1)
#define STG_STR 140

typedef __bf16 bf16x8 __attribute__((ext_vector_type(8)));
typedef float  f32x4  __attribute__((ext_vector_type(4)));

__device__ __forceinline__ float sspf(float x) {
    float e = __expf(-fabsf(x));
    return fmaxf(x, 0.0f) + __logf(1.0f + e) - 0.69314718055994530942f;
}

__device__ __forceinline__ unsigned short f2bf(float f) {
    unsigned int u = __float_as_uint(f);
    u = (u + 0x7fffu + ((u >> 16) & 1u)) >> 16;   // RNE
    return (unsigned short)u;
}

__device__ __forceinline__ float bf2f(unsigned short u) {
    return __uint_as_float(((unsigned int)u) << 16);
}

// XOR bank-swizzle for 16B A-frag chunks (c < 1024)
__device__ __forceinline__ int swz(int c) {
    return c ^ ((c >> 3) & 7) ^ ((c >> 8) & 3);
}

// ---------------------------------------------------------------- filter tables
// Interleaved bf16 pair table: tab2[t][f] = (bf16(W[t+1][f])<<16)|bf16(W[t][f])
__global__ __launch_bounds__(128) void build_tables(
        const float* __restrict__ w1, const float* __restrict__ b1,
        const float* __restrict__ w2, const float* __restrict__ b2,
        unsigned int* __restrict__ tab2) {
    int l  = blockIdx.x / (TBL / T_PER);
    int t0 = (blockIdx.x % (TBL / T_PER)) * T_PER;
    int f  = threadIdx.x;  // 128
    __shared__ float sW1[G_DIM * 128];
    __shared__ float gs[T_PER2][G_DIM + 2];
    __shared__ float sy[T_PER2][130];
    for (int i = f; i < G_DIM * 128; i += 128)
        sW1[i] = w1[(size_t)l * G_DIM * 128 + i];
    if (f < G_DIM) {
        float o = f * (CUTOFF_C / (G_DIM - 1));
#pragma unroll
        for (int u = 0; u < T_PER2; ++u) {
            int t = t0 + u;
            if (t > TBL - 1) t = TBL - 1;
            float dt = t * (DMAX / (TBL - 1));
            float dd = dt - o;
            gs[u][f] = __expf(COEFF_C * dd * dd);
        }
    }
    __syncthreads();
    float y[T_PER2];
    float bb = b1[l * 128 + f];
#pragma unroll
    for (int u = 0; u < T_PER2; ++u) y[u] = bb;
    for (int g = 0; g < G_DIM; ++g) {
        float wv = sW1[g * 128 + f];
#pragma unroll
        for (int u = 0; u < T_PER2; ++u) y[u] += gs[u][g] * wv;
    }
#pragma unroll
    for (int u = 0; u < T_PER2; ++u) sy[u][f] = sspf(y[u]);
    __syncthreads();
    float acc[T_PER2];
    float b2v = b2[l * 128 + f];
#pragma unroll
    for (int u = 0; u < T_PER2; ++u) acc[u] = b2v;
    const float* W2 = w2 + (size_t)l * 16384;
    for (int k = 0; k < 128; ++k) {
        float wv = W2[k * 128 + f];
#pragma unroll
        for (int u = 0; u < T_PER2; ++u) acc[u] += sy[u][k] * wv;
    }
#pragma unroll
    for (int u = 0; u < T_PER; ++u) {
        unsigned int lo = f2bf(acc[u]);
        unsigned int hi = f2bf(acc[u + 1]);
        tab2[((size_t)l * TBL + t0 + u) * 128 + f] = (hi << 16) | lo;
    }
}

// ---------------------------------------------------------------- embedding (bf16 h)
__global__ __launch_bounds__(256) void embed_kernel(
        const int* __restrict__ z, const float* __restrict__ emb,
        unsigned short* __restrict__ hb, int N) {
    int idx = blockIdx.x * blockDim.x + threadIdx.x;
    if (idx >= N * H_DIM) return;
    int n = idx >> 7, f = idx & 127;
    hb[idx] = f2bf(emb[z[n] * H_DIM + f]);
}

// ---------------------------------------------------------------- weight prep (all 19)
__global__ __launch_bounds__(256) void prep_wt_all(
        const float* __restrict__ c1w, const float* __restrict__ c2w,
        const float* __restrict__ iw, const float* __restrict__ l1w,
        unsigned short* __restrict__ Bsw) {
    int m = blockIdx.x;   // 0..18
    const float* src = (m < 6)  ? c1w + (size_t)m * 16384
                     : (m < 12) ? c2w + (size_t)(m - 6) * 16384
                     : (m < 18) ? iw  + (size_t)(m - 12) * 16384
                                : l1w;
    unsigned short* dst = Bsw + (size_t)m * 16384;
    for (int i = threadIdx.x; i < 16384; i += 256) {
        int jj = i & 7, lane = (i >> 3) & 63, j = (i >> 9) & 7, ks = i >> 12;
        int n = j * 16 + (lane & 15);
        int k = ks * 32 + ((lane >> 4) & 3) * 8 + jj;
        dst[i] = f2bf(src[k * 128 + n]);
    }
}

// ---------------------------------------------------------------- CSR build
__global__ __launch_bounds__(256) void count_kernel(
        const int* __restrict__ ec, int* __restrict__ cnt,
        int* __restrict__ rank, int E) {
    int e = blockIdx.x * blockDim.x + threadIdx.x;
    if (e < E) rank[e] = atomicAdd(&cnt[ec[e]], 1);
}

__global__ __launch_bounds__(SCAN_B) void scan1(
        const int* __restrict__ cnt, int* __restrict__ excl,
        int* __restrict__ bsums, int N) {
    __shared__ int s[SCAN_B];
    int i = blockIdx.x * SCAN_B + threadIdx.x;
    int v = (i < N) ? cnt[i] : 0;
    s[threadIdx.x] = v;
    __syncthreads();
    for (int off = 1; off < SCAN_B; off <<= 1) {
        int t = (threadIdx.x >= off) ? s[threadIdx.x - off] : 0;
        __syncthreads();
        s[threadIdx.x] += t;
        __syncthreads();
    }
    if (i < N) excl[i] = s[threadIdx.x] - v;
    if (threadIdx.x == SCAN_B - 1) bsums[blockIdx.x] = s[SCAN_B - 1];
}

__global__ __launch_bounds__(SCAN_B) void scan2(int* __restrict__ bsums, int nb) {
    __shared__ int s[SCAN_B];
    int v = (threadIdx.x < nb) ? bsums[threadIdx.x] : 0;
    s[threadIdx.x] = v;
    __syncthreads();
    for (int off = 1; off < SCAN_B; off <<= 1) {
        int t = (threadIdx.x >= off) ? s[threadIdx.x - off] : 0;
        __syncthreads();
        s[threadIdx.x] += t;
        __syncthreads();
    }
    if (threadIdx.x < nb) bsums[threadIdx.x] = s[threadIdx.x] - v;
}

__global__ __launch_bounds__(SCAN_B) void scan3(
        const int* __restrict__ excl, const int* __restrict__ bsums,
        int* __restrict__ row_start, int N, int E) {
    int i = blockIdx.x * SCAN_B + threadIdx.x;
    if (i < N) row_start[i] = excl[i] + bsums[blockIdx.x];
    if (i == 0) row_start[N] = E;
}

// 8-byte edge record {row|(i0<<17), half2(a,b)}; slot = row_start[col]+rank[e]
__global__ __launch_bounds__(256) void build_edges(
        const int* __restrict__ er, const int* __restrict__ ec,
        const float* __restrict__ pos, const int* __restrict__ row_start,
        const int* __restrict__ rank, uint2* __restrict__ ebuf, int E) {
    int e = blockIdx.x * blockDim.x + threadIdx.x;
    if (e >= E) return;
    int r = er[e], c = ec[e];
    float dx = pos[r * 3 + 0] - pos[c * 3 + 0];
    float dy = pos[r * 3 + 1] - pos[c * 3 + 1];
    float dz = pos[r * 3 + 2] - pos[c * 3 + 2];
    float d = sqrtf(dx * dx + dy * dy + dz * dz);
    float C = 0.5f * (cosf(d * (3.14159265358979323846f / CUTOFF_C)) + 1.0f);
    float t = fminf(d, DMAX) * ((TBL - 1) / DMAX);
    int i0 = (int)t;
    if (i0 > TBL - 2) i0 = TBL - 2;
    float fr = t - (float)i0;
    __half2 abh = __floats2half2_rn(C * (1.0f - fr), C * fr);
    ebuf[row_start[c] + rank[e]] =
        make_uint2((unsigned)r | ((unsigned)i0 << 17), *(unsigned*)&abh);
}

// ---------------------------------------------------------------- edge gather
__device__ __forceinline__ void edge_acc(
        unsigned ex, unsigned ey, const unsigned int* __restrict__ tab2,
        const unsigned short* __restrict__ xfb, int f4, float4& acc) {
    int r = ex & 0x1ffff, i0 = ex >> 17;
    float2 ab = __half22float2(*(__half2*)&ey);
    uint4 tp = *(const uint4*)(tab2 + (size_t)i0 * 128 + f4);
    const ushort4 xu = *(const ushort4*)(xfb + (size_t)r * 128 + f4);
    acc.x += bf2f(xu.x) * (ab.x * __uint_as_float(tp.x << 16) +
                           ab.y * __uint_as_float(tp.x & 0xffff0000u));
    acc.y += bf2f(xu.y) * (ab.x * __uint_as_float(tp.y << 16) +
                           ab.y * __uint_as_float(tp.y & 0xffff0000u));
    acc.z += bf2f(xu.z) * (ab.x * __uint_as_float(tp.z << 16) +
                           ab.y * __uint_as_float(tp.z & 0xffff0000u));
    acc.w += bf2f(xu.w) * (ab.x * __uint_as_float(tp.w << 16) +
                           ab.y * __uint_as_float(tp.w & 0xffff0000u));
}

// 32 lanes/atom, 8 edges in flight (four uint4 record-pair loads, 4 accums)
__global__ __launch_bounds__(256) void edge_agg(
        const uint2* __restrict__ ebuf, const int* __restrict__ row_start,
        const unsigned short* __restrict__ xfb, const unsigned int* __restrict__ tab2,
        unsigned short* __restrict__ aggb, int N) {
    int tid = threadIdx.x;
    int atom = blockIdx.x * 8 + (tid >> 5);
    if (atom >= N) return;
    int f4 = (tid & 31) * 4;
    float4 a0 = make_float4(0.f, 0.f, 0.f, 0.f);
    float4 a1 = make_float4(0.f, 0.f, 0.f, 0.f);
    float4 a2 = make_float4(0.f, 0.f, 0.f, 0.f);
    float4 a3 = make_float4(0.f, 0.f, 0.f, 0.f);
    int j0 = row_start[atom], j1 = row_start[atom + 1];
    int j = j0;
    if (j < j1 && (j & 1)) {   // align to even for uint4 pair loads
        uint2 ed = ebuf[j];
        edge_acc(ed.x, ed.y, tab2, xfb, f4, a0);
        ++j;
    }
    for (; j + 7 < j1; j += 8) {
        uint4 e0 = *(const uint4*)(ebuf + j);
        uint4 e1 = *(const uint4*)(ebuf + j + 2);
        uint4 e2 = *(const uint4*)(ebuf + j + 4);
        uint4 e3 = *(const uint4*)(ebuf + j + 6);
        edge_acc(e0.x, e0.y, tab2, xfb, f4, a0);
        edge_acc(e0.z, e0.w, tab2, xfb, f4, a1);
        edge_acc(e1.x, e1.y, tab2, xfb, f4, a2);
        edge_acc(e1.z, e1.w, tab2, xfb, f4, a3);
        edge_acc(e2.x, e2.y, tab2, xfb, f4, a0);
        edge_acc(e2.z, e2.w, tab2, xfb, f4, a1);
        edge_acc(e3.x, e3.y, tab2, xfb, f4, a2);
        edge_acc(e3.z, e3.w, tab2, xfb, f4, a3);
    }
    if (j + 3 < j1) {
        uint4 e0 = *(const uint4*)(ebuf + j);
        uint4 e1 = *(const uint4*)(ebuf + j + 2);
        edge_acc(e0.x, e0.y, tab2, xfb, f4, a0);
        edge_acc(e0.z, e0.w, tab2, xfb, f4, a1);
        edge_acc(e1.x, e1.y, tab2, xfb, f4, a2);
        edge_acc(e1.z, e1.w, tab2, xfb, f4, a3);
        j += 4;
    }
    if (j + 1 < j1) {
        uint4 e0 = *(const uint4*)(ebuf + j);
        edge_acc(e0.x, e0.y, tab2, xfb, f4, a0);
        edge_acc(e0.z, e0.w, tab2, xfb, f4, a1);
        j += 2;
    }
    if (j < j1) {
        uint2 ed = ebuf[j];
        edge_acc(ed.x, ed.y, tab2, xfb, f4, a0);
    }
    a0.x += a1.x + a2.x + a3.x;
    a0.y += a1.y + a2.y + a3.y;
    a0.z += a1.z + a2.z + a3.z;
    a0.w += a1.w + a2.w + a3.w;
    unsigned short o[4] = {f2bf(a0.x), f2bf(a0.y), f2bf(a0.z), f2bf(a0.w)};
    *(uint2*)(aggb + (size_t)atom * 128 + f4) = *(const uint2*)o;
}

// ---------------------------------------------------------------- layer-0 GEMM
__global__ __launch_bounds__(256, 4) void gemm_l0(
        const unsigned short* __restrict__ hb, const unsigned short* __restrict__ Bsw,
        unsigned short* __restrict__ xfb, int M) {
    __shared__ __align__(16) unsigned short frag[8192];
    __shared__ __align__(16) unsigned short stg[64 * STG_STR];
    int tid = threadIdx.x;
    int m0 = blockIdx.x * 64;
    for (int i = tid; i < 1024; i += 256) {
        int ks = i >> 8, w_ = (i >> 6) & 3, ln_ = i & 63;
        int row = m0 + w_ * 16 + (ln_ & 15);
        int kb = ks * 32 + (ln_ >> 4) * 8;
        uint4 v = make_uint4(0, 0, 0, 0);
        if (row < M) v = *(const uint4*)(hb + (size_t)row * 128 + kb);
        *(uint4*)(frag + swz(i) * 8) = v;
    }
    __syncthreads();
    int w = tid >> 6, ln = tid & 63;
    int quad = ln >> 4, l15 = ln & 15;
    f32x4 acc[8] = {};
#pragma unroll
    for (int ks = 0; ks < 4; ++ks) {
        bf16x8 af = *(const bf16x8*)(frag + swz((ks * 4 + w) * 64 + ln) * 8);
#pragma unroll
        for (int j = 0; j < 8; ++j) {
            bf16x8 bf = *(const bf16x8*)(Bsw + (((ks * 8 + j) * 64) + ln) * 8);
            acc[j] = __builtin_amdgcn_mfma_f32_16x16x32_bf16(af, bf, acc[j], 0, 0, 0);
        }
    }
#pragma unroll
    for (int j = 0; j < 8; ++j) {
        int col = j * 16 + l15;
#pragma unroll
        for (int r = 0; r < 4; ++r)
            stg[(w * 16 + quad * 4 + r) * STG_STR + col] = f2bf(acc[j][r]);
    }
    __syncthreads();
    for (int i = tid; i < 2048; i += 256) {
        int row = i >> 5, c4 = (i & 31) * 4;
        int grow = m0 + row;
        if (grow >= M) continue;
        ushort4 s4 = *(const ushort4*)(stg + row * STG_STR + c4);
        *(uint2*)(xfb + (size_t)grow * 128 + c4) = *(const uint2*)&s4;
    }
}

// ---------------------------------------------------------------- fused layer
__global__ __launch_bounds__(256, 4) void fused_layer(
        const unsigned short* __restrict__ aggb,
        const unsigned short* __restrict__ B1sw, const float* __restrict__ b1v,
        const unsigned short* __restrict__ B2sw, const float* __restrict__ b2v,
        const unsigned short* __restrict__ B3sw, const float* __restrict__ b3v,
        unsigned short* __restrict__ hb, unsigned short* __restrict__ xfb_next,
        float* __restrict__ s_out, int M, int last) {
    __shared__ __align__(16) unsigned short frag[8192];         // 16 KB
    __shared__ __align__(16) unsigned short stg[64 * STG_STR];  // 17.5 KB
    int tid = threadIdx.x;
    int m0 = blockIdx.x * 64;

    for (int i = tid; i < 1024; i += 256) {
        int ks = i >> 8, w_ = (i >> 6) & 3, ln_ = i & 63;
        int row = m0 + w_ * 16 + (ln_ & 15);
        int kb = ks * 32 + (ln_ >> 4) * 8;
        uint4 v = make_uint4(0, 0, 0, 0);
        if (row < M) v = *(const uint4*)(aggb + (size_t)row * 128 + kb);
        *(uint4*)(frag + swz(i) * 8) = v;
    }
    __syncthreads();

    int w = tid >> 6, ln = tid & 63;
    int quad = ln >> 4, l15 = ln & 15;

    f32x4 acc[8] = {};
#pragma unroll
    for (int ks = 0; ks < 4; ++ks) {
        bf16x8 af = *(const bf16x8*)(frag + swz((ks * 4 + w) * 64 + ln) * 8);
#pragma unroll
        for (int j = 0; j < 8; ++j) {
            bf16x8 bf = *(const bf16x8*)(B1sw + (((ks * 8 + j) * 64) + ln) * 8);
            acc[j] = __builtin_amdgcn_mfma_f32_16x16x32_bf16(af, bf, acc[j], 0, 0, 0);
        }
    }

#pragma unroll
    for (int j = 0; j < 8; ++j) {
        int col = j * 16 + l15;
        float bv = b1v[col];
        int ks2 = j >> 1;
        int quad2 = (col >> 3) & 3;
        int jj = l15 & 7;
        int cbase = (ks2 * 4 + w) * 64 + quad2 * 16 + quad * 4;
#pragma unroll
        for (int r = 0; r < 4; ++r) {
            float s = sspf(acc[j][r] + bv);
            frag[swz(cbase + r) * 8 + jj] = f2bf(s);
        }
    }

    f32x4 acc2[8] = {};
#pragma unroll
    for (int ks = 0; ks < 4; ++ks) {
        bf16x8 af = *(const bf16x8*)(frag + swz((ks * 4 + w) * 64 + ln) * 8);
#pragma unroll
        for (int j = 0; j < 8; ++j) {
            bf16x8 bf = *(const bf16x8*)(B2sw + (((ks * 8 + j) * 64) + ln) * 8);
            acc2[j] = __builtin_amdgcn_mfma_f32_16x16x32_bf16(af, bf, acc2[j], 0, 0, 0);
        }
    }

#pragma unroll
    for (int j = 0; j < 8; ++j) {
        int col = j * 16 + l15;
        float bv = b2v[col];
#pragma unroll
        for (int r = 0; r < 4; ++r)
            stg[(w * 16 + quad * 4 + r) * STG_STR + col] = f2bf(acc2[j][r] + bv);
    }
    __syncthreads();

    for (int i = tid; i < 2048; i += 256) {
        int row = i >> 5, c4 = (i & 31) * 4;
        int grow = m0 + row;
        ushort4 xv = *(const ushort4*)(stg + row * STG_STR + c4);
        unsigned short t4[4];
        if (grow < M) {
            unsigned short* hp = hb + (size_t)grow * 128 + c4;
            ushort4 hv = *(const ushort4*)hp;
            t4[0] = f2bf(bf2f(hv.x) + bf2f(xv.x));
            t4[1] = f2bf(bf2f(hv.y) + bf2f(xv.y));
            t4[2] = f2bf(bf2f(hv.z) + bf2f(xv.z));
            t4[3] = f2bf(bf2f(hv.w) + bf2f(xv.w));
            *(uint2*)hp = *(const uint2*)t4;
        } else {
            t4[0] = t4[1] = t4[2] = t4[3] = 0;
        }
        int w_ = row >> 4, l15_ = row & 15;
        int ks = c4 >> 5, q_ = (c4 >> 3) & 3, jj = c4 & 7;
        int c = (ks * 4 + w_) * 64 + q_ * 16 + l15_;
        *(uint2*)(frag + swz(c) * 8 + jj) = *(const uint2*)t4;
    }
    __syncthreads();

    f32x4 acc3[8] = {};
#pragma unroll
    for (int ks = 0; ks < 4; ++ks) {
        bf16x8 af = *(const bf16x8*)(frag + swz((ks * 4 + w) * 64 + ln) * 8);
#pragma unroll
        for (int j = 0; j < 8; ++j) {
            bf16x8 bf = *(const bf16x8*)(B3sw + (((ks * 8 + j) * 64) + ln) * 8);
            acc3[j] = __builtin_amdgcn_mfma_f32_16x16x32_bf16(af, bf, acc3[j], 0, 0, 0);
        }
    }

#pragma unroll
    for (int j = 0; j < 8; ++j) {
        int col = j * 16 + l15;
        float bv = last ? b3v[col] : 0.f;
#pragma unroll
        for (int r = 0; r < 4; ++r) {
            float v = acc3[j][r] + bv;
            if (last) v = sspf(v);
            stg[(w * 16 + quad * 4 + r) * STG_STR + col] = f2bf(v);
        }
    }
    __syncthreads();

    for (int i = tid; i < 2048; i += 256) {
        int row = i >> 5, c4 = (i & 31) * 4;
        int grow = m0 + row;
        if (grow >= M) continue;
        ushort4 s4 = *(const ushort4*)(stg + row * STG_STR + c4);
        if (last) {
            float4 v;
            v.x = bf2f(s4.x); v.y = bf2f(s4.y); v.z = bf2f(s4.z); v.w = bf2f(s4.w);
            *(float4*)(s_out + (size_t)grow * 128 + c4) = v;
        } else {
            *(uint2*)(xfb_next + (size_t)grow * 128 + c4) = *(const uint2*)&s4;
        }
    }
}

// ---------------------------------------------------------------- atom -> mol sum
#define MR_ATOMS 32
__global__ __launch_bounds__(128) void mol_reduce(
        const float* __restrict__ s, const int* __restrict__ a2c,
        const int* __restrict__ c2m, float* __restrict__ mols,
        int* __restrict__ cnt, int N) {
    int f = threadIdx.x;
    int a0 = blockIdx.x * MR_ATOMS;
    int a1 = min(a0 + MR_ATOMS, N);
    float sum = 0.f;
    int cur = -1, run = 0;
    for (int a = a0; a < a1; ++a) {
        int m = c2m[a2c[a]];
        if (m != cur) {
            if (cur >= 0) {
                unsafeAtomicAdd(&mols[(size_t)cur * H_DIM + f], sum);
                if (f == 0) atomicAdd(&cnt[cur], run);
            }
            cur = m; sum = 0.f; run = 0;
        }
        sum += s[(size_t)a * H_DIM + f];
        ++run;
    }
    if (cur >= 0) {
        unsafeAtomicAdd(&mols[(size_t)cur * H_DIM + f], sum);
        if (f == 0) atomicAdd(&cnt[cur], run);
    }
}

// ---------------------------------------------------------------- head
__global__ __launch_bounds__(128) void head_kernel(
        const float* __restrict__ mols, const int* __restrict__ cnt,
        const float* __restrict__ l2w, const float* __restrict__ l2b,
        const float* __restrict__ hw1, const float* __restrict__ hb1,
        const float* __restrict__ hw2, const float* __restrict__ hb2,
        float* __restrict__ out) {
    int m = blockIdx.x, f = threadIdx.x;
    __shared__ float me[H_DIM];
    __shared__ float u[H_DIM / 2];
    const float* ms = mols + (size_t)m * H_DIM;
    float acc = l2b[f] * (float)cnt[m];
#pragma unroll 16
    for (int k = 0; k < H_DIM; ++k) acc += ms[k] * l2w[k * H_DIM + f];
    me[f] = acc;
    __syncthreads();
    if (f < 64) {
        float a2 = hb1[f];
#pragma unroll 16
        for (int k = 0; k < H_DIM; ++k) a2 += me[k] * hw1[k * 64 + f];
        u[f] = sspf(a2);
    }
    __syncthreads();
    if (f == 0) {
        float o = hb2[0];
#pragma unroll 16
        for (int j = 0; j < 64; ++j) o += u[j] * hw2[j];
        out[m] = o;
    }
}

// ---------------------------------------------------------------- launch
extern "C" void kernel_launch(void* const* d_in, const int* in_sizes, int n_in,
                              void* d_out, int out_size, void* d_ws, size_t ws_size,
                              hipStream_t stream) {
    const int*   z   = (const int*)d_in[0];
    const float* pos = (const float*)d_in[1];
    const int*   er  = (const int*)d_in[2];
    const int*   ec  = (const int*)d_in[3];
    const int*   a2c = (const int*)d_in[4];
    const int*   c2m = (const int*)d_in[5];
    const float* emb = (const float*)d_in[6];
    const float* w1  = (const float*)d_in[7];
    const float* b1  = (const float*)d_in[8];
    const float* w2  = (const float*)d_in[9];
    const float* b2  = (const float*)d_in[10];
    const float* c1w = (const float*)d_in[11];
    const float* c2w = (const float*)d_in[12];
    const float* c2b = (const float*)d_in[13];
    const float* iw  = (const float*)d_in[14];
    const float* ib  = (const float*)d_in[15];
    const float* l1w = (const float*)d_in[16];
    const float* l1b = (const float*)d_in[17];
    const float* l2w = (const float*)d_in[18];
    const float* l2b = (const float*)d_in[19];
    const float* hw1 = (const float*)d_in[20];
    const float* hb1 = (const float*)d_in[21];
    const float* hw2 = (const float*)d_in[22];
    const float* hb2 = (const float*)d_in[23];

    const int N  = in_sizes[0];
    const int E  = in_sizes[2];
    const int NM = out_size;
    float* out = (float*)d_out;

    // workspace layout (~66 MB)
    char* wsp = (char*)d_ws;
    uint2* ebuf = (uint2*)wsp;            wsp += (size_t)E * 8;
    unsigned int* tab2 = (unsigned int*)wsp;  wsp += (size_t)L_LAYERS * TBL * NF_DIM * 4;
    unsigned short* wbt = (unsigned short*)wsp;  wsp += (size_t)19 * 16384 * 2;
    unsigned short* hb  = (unsigned short*)wsp;  wsp += (size_t)N * H_DIM * 2;
    unsigned short* xfb = (unsigned short*)wsp;  wsp += (size_t)N * H_DIM * 2;
    unsigned short* aggb = (unsigned short*)wsp; wsp += (size_t)N * H_DIM * 2;
    float* sbuf = (float*)wsp;            wsp += (size_t)N * H_DIM * 4;
    float* mols = (float*)wsp;            wsp += (size_t)NM * H_DIM * 4;
    int*   cnt_m = (int*)wsp;             wsp += (size_t)NM * 4;
    int*   ccnt  = (int*)wsp;             wsp += (size_t)N * 4;
    int*   row_start = (int*)wsp;         wsp += (size_t)(N + 1) * 4;
    int*   rank  = (int*)wsp;             wsp += (size_t)E * 4;
    int*   bsums = (int*)wsp;             wsp += 256 * 4;
    int*   excl  = (int*)wsp;

    // --- CSR build (rank-based, atomic-free scatter) ---
    hipMemsetAsync(ccnt, 0, (size_t)N * sizeof(int), stream);
    count_kernel<<<(E + 255) / 256, 256, 0, stream>>>(ec, ccnt, rank, E);
    int nb = (N + SCAN_B - 1) / SCAN_B;
    scan1<<<nb, SCAN_B, 0, stream>>>(ccnt, excl, bsums, N);
    scan2<<<1, SCAN_B, 0, stream>>>(bsums, nb);
    scan3<<<nb, SCAN_B, 0, stream>>>(excl, bsums, row_start, N, E);
    build_edges<<<(E + 255) / 256, 256, 0, stream>>>(
        er, ec, pos, row_start, rank, ebuf, E);

    build_tables<<<L_LAYERS * (TBL / T_PER), 128, 0, stream>>>(w1, b1, w2, b2, tab2);
    embed_kernel<<<(N * H_DIM + 255) / 256, 256, 0, stream>>>(z, emb, hb, N);
    prep_wt_all<<<19, 256, 0, stream>>>(c1w, c2w, iw, l1w, wbt);

    int gblocks = (N + 63) / 64;
    gemm_l0<<<gblocks, 256, 0, stream>>>(hb, wbt, xfb, N);

    for (int l = 0; l < L_LAYERS; ++l) {
        edge_agg<<<(N + 7) / 8, 256, 0, stream>>>(
            ebuf, row_start, xfb, tab2 + (size_t)l * TBL * NF_DIM, aggb, N);
        int last = (l == L_LAYERS - 1);
        const unsigned short* B3 = last ? wbt + (size_t)18 * 16384
                                        : wbt + (size_t)(l + 1) * 16384;
        fused_layer<<<gblocks, 256, 0, stream>>>(
            aggb,
            wbt + (size_t)(6 + l) * 16384,  c2b + (size_t)l * H_DIM,
            wbt + (size_t)(12 + l) * 16384, ib + (size_t)l * H_DIM,
            B3, l1b, hb, xfb, sbuf, N, last);
    }

    hipMemsetAsync(mols, 0, (size_t)NM * H_DIM * sizeof(float) + NM * sizeof(int), stream);
    mol_reduce<<<(N + MR_ATOMS - 1) / MR_ATOMS, 128, 0, stream>>>(
        sbuf, a2c, c2m, mols, cnt_m, N);
    head_kernel<<<NM, 128, 0, stream>>>(mols, cnt_m, l2w, l2b, hw1, hb1, hw2, hb2, out);
}

// Round 11
// 639.884 us; speedup vs baseline: 11.2901x; 1.0564x over previous
//
#include <hip/hip_runtime.h>
#include <hip/hip_bf16.h>
#include <hip/hip_fp16.h>
#include <math.h>

#define H_DIM   128
#define NF_DIM  128
#define G_DIM   50
#define L_LAYERS 6
#define TBL     4096       // nearest-neighbor grid; h/2/sigma ~ 0.77% rel err
#define DMAX    12.8f
#define CUTOFF_C 10.0f
#define COEFF_C (-0.5f * 49.0f * 49.0f / 100.0f)
#define SCAN_B  256
#define T_PER   16
#define STG_STR 140

typedef __bf16 bf16x8 __attribute__((ext_vector_type(8)));
typedef float  f32x4  __attribute__((ext_vector_type(4)));

__device__ __forceinline__ float sspf(float x) {
    float e = __expf(-fabsf(x));
    return fmaxf(x, 0.0f) + __logf(1.0f + e) - 0.69314718055994530942f;
}

__device__ __forceinline__ unsigned short f2bf(float f) {
    unsigned int u = __float_as_uint(f);
    u = (u + 0x7fffu + ((u >> 16) & 1u)) >> 16;   // RNE
    return (unsigned short)u;
}

__device__ __forceinline__ float bf2f(unsigned short u) {
    return __uint_as_float(((unsigned int)u) << 16);
}

// XOR bank-swizzle for 16B A-frag chunks (c < 1024)
__device__ __forceinline__ int swz(int c) {
    return c ^ ((c >> 3) & 7) ^ ((c >> 8) & 3);
}

// ---------------------------------------------------------------- filter tables
// Single bf16 rows (nearest-neighbor lookup): tabb[t][f] = bf16(W_t[f])
__global__ __launch_bounds__(128) void build_tables(
        const float* __restrict__ w1, const float* __restrict__ b1,
        const float* __restrict__ w2, const float* __restrict__ b2,
        unsigned short* __restrict__ tabb) {
    int l  = blockIdx.x / (TBL / T_PER);
    int t0 = (blockIdx.x % (TBL / T_PER)) * T_PER;
    int f  = threadIdx.x;  // 128
    __shared__ float sW1[G_DIM * 128];
    __shared__ float gs[T_PER][G_DIM + 2];
    __shared__ float sy[T_PER][130];
    for (int i = f; i < G_DIM * 128; i += 128)
        sW1[i] = w1[(size_t)l * G_DIM * 128 + i];
    if (f < G_DIM) {
        float o = f * (CUTOFF_C / (G_DIM - 1));
#pragma unroll
        for (int u = 0; u < T_PER; ++u) {
            float dt = (t0 + u) * (DMAX / (TBL - 1));
            float dd = dt - o;
            gs[u][f] = __expf(COEFF_C * dd * dd);
        }
    }
    __syncthreads();
    float y[T_PER];
    float bb = b1[l * 128 + f];
#pragma unroll
    for (int u = 0; u < T_PER; ++u) y[u] = bb;
    for (int g = 0; g < G_DIM; ++g) {
        float wv = sW1[g * 128 + f];
#pragma unroll
        for (int u = 0; u < T_PER; ++u) y[u] += gs[u][g] * wv;
    }
#pragma unroll
    for (int u = 0; u < T_PER; ++u) sy[u][f] = sspf(y[u]);
    __syncthreads();
    float acc[T_PER];
    float b2v = b2[l * 128 + f];
#pragma unroll
    for (int u = 0; u < T_PER; ++u) acc[u] = b2v;
    const float* W2 = w2 + (size_t)l * 16384;
    for (int k = 0; k < 128; ++k) {
        float wv = W2[k * 128 + f];
#pragma unroll
        for (int u = 0; u < T_PER; ++u) acc[u] += sy[u][k] * wv;
    }
#pragma unroll
    for (int u = 0; u < T_PER; ++u)
        tabb[((size_t)l * TBL + t0 + u) * 128 + f] = f2bf(acc[u]);
}

// ---------------------------------------------------------------- embedding (bf16 h)
__global__ __launch_bounds__(256) void embed_kernel(
        const int* __restrict__ z, const float* __restrict__ emb,
        unsigned short* __restrict__ hb, int N) {
    int idx = blockIdx.x * blockDim.x + threadIdx.x;
    if (idx >= N * H_DIM) return;
    int n = idx >> 7, f = idx & 127;
    hb[idx] = f2bf(emb[z[n] * H_DIM + f]);
}

// ---------------------------------------------------------------- weight prep (all 19)
__global__ __launch_bounds__(256) void prep_wt_all(
        const float* __restrict__ c1w, const float* __restrict__ c2w,
        const float* __restrict__ iw, const float* __restrict__ l1w,
        unsigned short* __restrict__ Bsw) {
    int m = blockIdx.x;   // 0..18
    const float* src = (m < 6)  ? c1w + (size_t)m * 16384
                     : (m < 12) ? c2w + (size_t)(m - 6) * 16384
                     : (m < 18) ? iw  + (size_t)(m - 12) * 16384
                                : l1w;
    unsigned short* dst = Bsw + (size_t)m * 16384;
    for (int i = threadIdx.x; i < 16384; i += 256) {
        int jj = i & 7, lane = (i >> 3) & 63, j = (i >> 9) & 7, ks = i >> 12;
        int n = j * 16 + (lane & 15);
        int k = ks * 32 + ((lane >> 4) & 3) * 8 + jj;
        dst[i] = f2bf(src[k * 128 + n]);
    }
}

// ---------------------------------------------------------------- CSR build
__global__ __launch_bounds__(256) void count_kernel(
        const int* __restrict__ ec, int* __restrict__ cnt,
        int* __restrict__ rank, int E) {
    int e = blockIdx.x * blockDim.x + threadIdx.x;
    if (e < E) rank[e] = atomicAdd(&cnt[ec[e]], 1);
}

__global__ __launch_bounds__(SCAN_B) void scan1(
        const int* __restrict__ cnt, int* __restrict__ excl,
        int* __restrict__ bsums, int N) {
    __shared__ int s[SCAN_B];
    int i = blockIdx.x * SCAN_B + threadIdx.x;
    int v = (i < N) ? cnt[i] : 0;
    s[threadIdx.x] = v;
    __syncthreads();
    for (int off = 1; off < SCAN_B; off <<= 1) {
        int t = (threadIdx.x >= off) ? s[threadIdx.x - off] : 0;
        __syncthreads();
        s[threadIdx.x] += t;
        __syncthreads();
    }
    if (i < N) excl[i] = s[threadIdx.x] - v;
    if (threadIdx.x == SCAN_B - 1) bsums[blockIdx.x] = s[SCAN_B - 1];
}

__global__ __launch_bounds__(SCAN_B) void scan2(int* __restrict__ bsums, int nb) {
    __shared__ int s[SCAN_B];
    int v = (threadIdx.x < nb) ? bsums[threadIdx.x] : 0;
    s[threadIdx.x] = v;
    __syncthreads();
    for (int off = 1; off < SCAN_B; off <<= 1) {
        int t = (threadIdx.x >= off) ? s[threadIdx.x - off] : 0;
        __syncthreads();
        s[threadIdx.x] += t;
        __syncthreads();
    }
    if (threadIdx.x < nb) bsums[threadIdx.x] = s[threadIdx.x] - v;
}

__global__ __launch_bounds__(SCAN_B) void scan3(
        const int* __restrict__ excl, const int* __restrict__ bsums,
        int* __restrict__ row_start, int N, int E) {
    int i = blockIdx.x * SCAN_B + threadIdx.x;
    if (i < N) row_start[i] = excl[i] + bsums[blockIdx.x];
    if (i == 0) row_start[N] = E;
}

// 8-byte edge record {row|(i0<<17), fp32 C}; slot = row_start[col]+rank[e]
__global__ __launch_bounds__(256) void build_edges(
        const int* __restrict__ er, const int* __restrict__ ec,
        const float* __restrict__ pos, const int* __restrict__ row_start,
        const int* __restrict__ rank, uint2* __restrict__ ebuf, int E) {
    int e = blockIdx.x * blockDim.x + threadIdx.x;
    if (e >= E) return;
    int r = er[e], c = ec[e];
    float dx = pos[r * 3 + 0] - pos[c * 3 + 0];
    float dy = pos[r * 3 + 1] - pos[c * 3 + 1];
    float dz = pos[r * 3 + 2] - pos[c * 3 + 2];
    float d = sqrtf(dx * dx + dy * dy + dz * dz);
    float C = 0.5f * (cosf(d * (3.14159265358979323846f / CUTOFF_C)) + 1.0f);
    float t = fminf(d, DMAX) * ((TBL - 1) / DMAX);
    int i0 = (int)(t + 0.5f);          // nearest grid point
    if (i0 > TBL - 1) i0 = TBL - 1;
    ebuf[row_start[c] + rank[e]] =
        make_uint2((unsigned)r | ((unsigned)i0 << 17), __float_as_uint(C));
}

// ---------------------------------------------------------------- edge gather
__device__ __forceinline__ void edge_acc(
        unsigned ex, unsigned ey, const unsigned short* __restrict__ tabb,
        const unsigned short* __restrict__ xfb, int f4, float4& acc) {
    int r = ex & 0x1ffff, i0 = ex >> 17;
    float C = __uint_as_float(ey);
    const ushort4 tw = *(const ushort4*)(tabb + (size_t)i0 * 128 + f4);
    const ushort4 xu = *(const ushort4*)(xfb + (size_t)r * 128 + f4);
    acc.x = fmaf(bf2f(xu.x) * bf2f(tw.x), C, acc.x);
    acc.y = fmaf(bf2f(xu.y) * bf2f(tw.y), C, acc.y);
    acc.z = fmaf(bf2f(xu.z) * bf2f(tw.z), C, acc.z);
    acc.w = fmaf(bf2f(xu.w) * bf2f(tw.w), C, acc.w);
}

// 32 lanes/atom, 4 edges in flight (two uint4 record-pair loads, 4 accums)
__global__ __launch_bounds__(256) void edge_agg(
        const uint2* __restrict__ ebuf, const int* __restrict__ row_start,
        const unsigned short* __restrict__ xfb, const unsigned short* __restrict__ tabb,
        unsigned short* __restrict__ aggb, int N) {
    int tid = threadIdx.x;
    int atom = blockIdx.x * 8 + (tid >> 5);
    if (atom >= N) return;
    int f4 = (tid & 31) * 4;
    float4 a0 = make_float4(0.f, 0.f, 0.f, 0.f);
    float4 a1 = make_float4(0.f, 0.f, 0.f, 0.f);
    float4 a2 = make_float4(0.f, 0.f, 0.f, 0.f);
    float4 a3 = make_float4(0.f, 0.f, 0.f, 0.f);
    int j0 = row_start[atom], j1 = row_start[atom + 1];
    int j = j0;
    if (j < j1 && (j & 1)) {   // align to even for uint4 pair loads
        uint2 ed = ebuf[j];
        edge_acc(ed.x, ed.y, tabb, xfb, f4, a0);
        ++j;
    }
    for (; j + 3 < j1; j += 4) {
        uint4 e0 = *(const uint4*)(ebuf + j);
        uint4 e1 = *(const uint4*)(ebuf + j + 2);
        edge_acc(e0.x, e0.y, tabb, xfb, f4, a0);
        edge_acc(e0.z, e0.w, tabb, xfb, f4, a1);
        edge_acc(e1.x, e1.y, tabb, xfb, f4, a2);
        edge_acc(e1.z, e1.w, tabb, xfb, f4, a3);
    }
    if (j + 1 < j1) {
        uint4 e0 = *(const uint4*)(ebuf + j);
        edge_acc(e0.x, e0.y, tabb, xfb, f4, a0);
        edge_acc(e0.z, e0.w, tabb, xfb, f4, a1);
        j += 2;
    }
    if (j < j1) {
        uint2 ed = ebuf[j];
        edge_acc(ed.x, ed.y, tabb, xfb, f4, a0);
    }
    a0.x += a1.x + a2.x + a3.x;
    a0.y += a1.y + a2.y + a3.y;
    a0.z += a1.z + a2.z + a3.z;
    a0.w += a1.w + a2.w + a3.w;
    unsigned short o[4] = {f2bf(a0.x), f2bf(a0.y), f2bf(a0.z), f2bf(a0.w)};
    *(uint2*)(aggb + (size_t)atom * 128 + f4) = *(const uint2*)o;
}

// ---------------------------------------------------------------- layer-0 GEMM
__global__ __launch_bounds__(256, 4) void gemm_l0(
        const unsigned short* __restrict__ hb, const unsigned short* __restrict__ Bsw,
        unsigned short* __restrict__ xfb, int M) {
    __shared__ __align__(16) unsigned short frag[8192];
    __shared__ __align__(16) unsigned short stg[64 * STG_STR];
    int tid = threadIdx.x;
    int m0 = blockIdx.x * 64;
    for (int i = tid; i < 1024; i += 256) {
        int ks = i >> 8, w_ = (i >> 6) & 3, ln_ = i & 63;
        int row = m0 + w_ * 16 + (ln_ & 15);
        int kb = ks * 32 + (ln_ >> 4) * 8;
        uint4 v = make_uint4(0, 0, 0, 0);
        if (row < M) v = *(const uint4*)(hb + (size_t)row * 128 + kb);
        *(uint4*)(frag + swz(i) * 8) = v;
    }
    __syncthreads();
    int w = tid >> 6, ln = tid & 63;
    int quad = ln >> 4, l15 = ln & 15;
    f32x4 acc[8] = {};
#pragma unroll
    for (int ks = 0; ks < 4; ++ks) {
        bf16x8 af = *(const bf16x8*)(frag + swz((ks * 4 + w) * 64 + ln) * 8);
#pragma unroll
        for (int j = 0; j < 8; ++j) {
            bf16x8 bf = *(const bf16x8*)(Bsw + (((ks * 8 + j) * 64) + ln) * 8);
            acc[j] = __builtin_amdgcn_mfma_f32_16x16x32_bf16(af, bf, acc[j], 0, 0, 0);
        }
    }
#pragma unroll
    for (int j = 0; j < 8; ++j) {
        int col = j * 16 + l15;
#pragma unroll
        for (int r = 0; r < 4; ++r)
            stg[(w * 16 + quad * 4 + r) * STG_STR + col] = f2bf(acc[j][r]);
    }
    __syncthreads();
    for (int i = tid; i < 2048; i += 256) {
        int row = i >> 5, c4 = (i & 31) * 4;
        int grow = m0 + row;
        if (grow >= M) continue;
        ushort4 s4 = *(const ushort4*)(stg + row * STG_STR + c4);
        *(uint2*)(xfb + (size_t)grow * 128 + c4) = *(const uint2*)&s4;
    }
}

// ---------------------------------------------------------------- fused layer
__global__ __launch_bounds__(256, 4) void fused_layer(
        const unsigned short* __restrict__ aggb,
        const unsigned short* __restrict__ B1sw, const float* __restrict__ b1v,
        const unsigned short* __restrict__ B2sw, const float* __restrict__ b2v,
        const unsigned short* __restrict__ B3sw, const float* __restrict__ b3v,
        unsigned short* __restrict__ hb, unsigned short* __restrict__ xfb_next,
        float* __restrict__ s_out, int M, int last) {
    __shared__ __align__(16) unsigned short frag[8192];         // 16 KB
    __shared__ __align__(16) unsigned short stg[64 * STG_STR];  // 17.5 KB
    int tid = threadIdx.x;
    int m0 = blockIdx.x * 64;

    for (int i = tid; i < 1024; i += 256) {
        int ks = i >> 8, w_ = (i >> 6) & 3, ln_ = i & 63;
        int row = m0 + w_ * 16 + (ln_ & 15);
        int kb = ks * 32 + (ln_ >> 4) * 8;
        uint4 v = make_uint4(0, 0, 0, 0);
        if (row < M) v = *(const uint4*)(aggb + (size_t)row * 128 + kb);
        *(uint4*)(frag + swz(i) * 8) = v;
    }
    __syncthreads();

    int w = tid >> 6, ln = tid & 63;
    int quad = ln >> 4, l15 = ln & 15;

    f32x4 acc[8] = {};
#pragma unroll
    for (int ks = 0; ks < 4; ++ks) {
        bf16x8 af = *(const bf16x8*)(frag + swz((ks * 4 + w) * 64 + ln) * 8);
#pragma unroll
        for (int j = 0; j < 8; ++j) {
            bf16x8 bf = *(const bf16x8*)(B1sw + (((ks * 8 + j) * 64) + ln) * 8);
            acc[j] = __builtin_amdgcn_mfma_f32_16x16x32_bf16(af, bf, acc[j], 0, 0, 0);
        }
    }

#pragma unroll
    for (int j = 0; j < 8; ++j) {
        int col = j * 16 + l15;
        float bv = b1v[col];
        int ks2 = j >> 1;
        int quad2 = (col >> 3) & 3;
        int jj = l15 & 7;
        int cbase = (ks2 * 4 + w) * 64 + quad2 * 16 + quad * 4;
#pragma unroll
        for (int r = 0; r < 4; ++r) {
            float s = sspf(acc[j][r] + bv);
            frag[swz(cbase + r) * 8 + jj] = f2bf(s);
        }
    }

    f32x4 acc2[8] = {};
#pragma unroll
    for (int ks = 0; ks < 4; ++ks) {
        bf16x8 af = *(const bf16x8*)(frag + swz((ks * 4 + w) * 64 + ln) * 8);
#pragma unroll
        for (int j = 0; j < 8; ++j) {
            bf16x8 bf = *(const bf16x8*)(B2sw + (((ks * 8 + j) * 64) + ln) * 8);
            acc2[j] = __builtin_amdgcn_mfma_f32_16x16x32_bf16(af, bf, acc2[j], 0, 0, 0);
        }
    }

#pragma unroll
    for (int j = 0; j < 8; ++j) {
        int col = j * 16 + l15;
        float bv = b2v[col];
#pragma unroll
        for (int r = 0; r < 4; ++r)
            stg[(w * 16 + quad * 4 + r) * STG_STR + col] = f2bf(acc2[j][r] + bv);
    }
    __syncthreads();

    for (int i = tid; i < 2048; i += 256) {
        int row = i >> 5, c4 = (i & 31) * 4;
        int grow = m0 + row;
        ushort4 xv = *(const ushort4*)(stg + row * STG_STR + c4);
        unsigned short t4[4];
        if (grow < M) {
            unsigned short* hp = hb + (size_t)grow * 128 + c4;
            ushort4 hv = *(const ushort4*)hp;
            t4[0] = f2bf(bf2f(hv.x) + bf2f(xv.x));
            t4[1] = f2bf(bf2f(hv.y) + bf2f(xv.y));
            t4[2] = f2bf(bf2f(hv.z) + bf2f(xv.z));
            t4[3] = f2bf(bf2f(hv.w) + bf2f(xv.w));
            *(uint2*)hp = *(const uint2*)t4;
        } else {
            t4[0] = t4[1] = t4[2] = t4[3] = 0;
        }
        int w_ = row >> 4, l15_ = row & 15;
        int ks = c4 >> 5, q_ = (c4 >> 3) & 3, jj = c4 & 7;
        int c = (ks * 4 + w_) * 64 + q_ * 16 + l15_;
        *(uint2*)(frag + swz(c) * 8 + jj) = *(const uint2*)t4;
    }
    __syncthreads();

    f32x4 acc3[8] = {};
#pragma unroll
    for (int ks = 0; ks < 4; ++ks) {
        bf16x8 af = *(const bf16x8*)(frag + swz((ks * 4 + w) * 64 + ln) * 8);
#pragma unroll
        for (int j = 0; j < 8; ++j) {
            bf16x8 bf = *(const bf16x8*)(B3sw + (((ks * 8 + j) * 64) + ln) * 8);
            acc3[j] = __builtin_amdgcn_mfma_f32_16x16x32_bf16(af, bf, acc3[j], 0, 0, 0);
        }
    }

#pragma unroll
    for (int j = 0; j < 8; ++j) {
        int col = j * 16 + l15;
        float bv = last ? b3v[col] : 0.f;
#pragma unroll
        for (int r = 0; r < 4; ++r) {
            float v = acc3[j][r] + bv;
            if (last) v = sspf(v);
            stg[(w * 16 + quad * 4 + r) * STG_STR + col] = f2bf(v);
        }
    }
    __syncthreads();

    for (int i = tid; i < 2048; i += 256) {
        int row = i >> 5, c4 = (i & 31) * 4;
        int grow = m0 + row;
        if (grow >= M) continue;
        ushort4 s4 = *(const ushort4*)(stg + row * STG_STR + c4);
        if (last) {
            float4 v;
            v.x = bf2f(s4.x); v.y = bf2f(s4.y); v.z = bf2f(s4.z); v.w = bf2f(s4.w);
            *(float4*)(s_out + (size_t)grow * 128 + c4) = v;
        } else {
            *(uint2*)(xfb_next + (size_t)grow * 128 + c4) = *(const uint2*)&s4;
        }
    }
}

// ---------------------------------------------------------------- atom -> mol sum
#define MR_ATOMS 32
__global__ __launch_bounds__(128) void mol_reduce(
        const float* __restrict__ s, const int* __restrict__ a2c,
        const int* __restrict__ c2m, float* __restrict__ mols,
        int* __restrict__ cnt, int N) {
    int f = threadIdx.x;
    int a0 = blockIdx.x * MR_ATOMS;
    int a1 = min(a0 + MR_ATOMS, N);
    float sum = 0.f;
    int cur = -1, run = 0;
    for (int a = a0; a < a1; ++a) {
        int m = c2m[a2c[a]];
        if (m != cur) {
            if (cur >= 0) {
                unsafeAtomicAdd(&mols[(size_t)cur * H_DIM + f], sum);
                if (f == 0) atomicAdd(&cnt[cur], run);
            }
            cur = m; sum = 0.f; run = 0;
        }
        sum += s[(size_t)a * H_DIM + f];
        ++run;
    }
    if (cur >= 0) {
        unsafeAtomicAdd(&mols[(size_t)cur * H_DIM + f], sum);
        if (f == 0) atomicAdd(&cnt[cur], run);
    }
}

// ---------------------------------------------------------------- head
__global__ __launch_bounds__(128) void head_kernel(
        const float* __restrict__ mols, const int* __restrict__ cnt,
        const float* __restrict__ l2w, const float* __restrict__ l2b,
        const float* __restrict__ hw1, const float* __restrict__ hb1,
        const float* __restrict__ hw2, const float* __restrict__ hb2,
        float* __restrict__ out) {
    int m = blockIdx.x, f = threadIdx.x;
    __shared__ float me[H_DIM];
    __shared__ float u[H_DIM / 2];
    const float* ms = mols + (size_t)m * H_DIM;
    float acc = l2b[f] * (float)cnt[m];
#pragma unroll 16
    for (int k = 0; k < H_DIM; ++k) acc += ms[k] * l2w[k * H_DIM + f];
    me[f] = acc;
    __syncthreads();
    if (f < 64) {
        float a2 = hb1[f];
#pragma unroll 16
        for (int k = 0; k < H_DIM; ++k) a2 += me[k] * hw1[k * 64 + f];
        u[f] = sspf(a2);
    }
    __syncthreads();
    if (f == 0) {
        float o = hb2[0];
#pragma unroll 16
        for (int j = 0; j < 64; ++j) o += u[j] * hw2[j];
        out[m] = o;
    }
}

// ---------------------------------------------------------------- launch
extern "C" void kernel_launch(void* const* d_in, const int* in_sizes, int n_in,
                              void* d_out, int out_size, void* d_ws, size_t ws_size,
                              hipStream_t stream) {
    const int*   z   = (const int*)d_in[0];
    const float* pos = (const float*)d_in[1];
    const int*   er  = (const int*)d_in[2];
    const int*   ec  = (const int*)d_in[3];
    const int*   a2c = (const int*)d_in[4];
    const int*   c2m = (const int*)d_in[5];
    const float* emb = (const float*)d_in[6];
    const float* w1  = (const float*)d_in[7];
    const float* b1  = (const float*)d_in[8];
    const float* w2  = (const float*)d_in[9];
    const float* b2  = (const float*)d_in[10];
    const float* c1w = (const float*)d_in[11];
    const float* c2w = (const float*)d_in[12];
    const float* c2b = (const float*)d_in[13];
    const float* iw  = (const float*)d_in[14];
    const float* ib  = (const float*)d_in[15];
    const float* l1w = (const float*)d_in[16];
    const float* l1b = (const float*)d_in[17];
    const float* l2w = (const float*)d_in[18];
    const float* l2b = (const float*)d_in[19];
    const float* hw1 = (const float*)d_in[20];
    const float* hb1 = (const float*)d_in[21];
    const float* hw2 = (const float*)d_in[22];
    const float* hb2 = (const float*)d_in[23];

    const int N  = in_sizes[0];
    const int E  = in_sizes[2];
    const int NM = out_size;
    float* out = (float*)d_out;

    // workspace layout (~66 MB)
    char* wsp = (char*)d_ws;
    uint2* ebuf = (uint2*)wsp;            wsp += (size_t)E * 8;
    unsigned short* tabb = (unsigned short*)wsp;  wsp += (size_t)L_LAYERS * TBL * NF_DIM * 2;
    unsigned short* wbt = (unsigned short*)wsp;  wsp += (size_t)19 * 16384 * 2;
    unsigned short* hb  = (unsigned short*)wsp;  wsp += (size_t)N * H_DIM * 2;
    unsigned short* xfb = (unsigned short*)wsp;  wsp += (size_t)N * H_DIM * 2;
    unsigned short* aggb = (unsigned short*)wsp; wsp += (size_t)N * H_DIM * 2;
    float* sbuf = (float*)wsp;            wsp += (size_t)N * H_DIM * 4;
    float* mols = (float*)wsp;            wsp += (size_t)NM * H_DIM * 4;
    int*   cnt_m = (int*)wsp;             wsp += (size_t)NM * 4;
    int*   ccnt  = (int*)wsp;             wsp += (size_t)N * 4;
    int*   row_start = (int*)wsp;         wsp += (size_t)(N + 1) * 4;
    int*   rank  = (int*)wsp;             wsp += (size_t)E * 4;
    int*   bsums = (int*)wsp;             wsp += 256 * 4;
    int*   excl  = (int*)wsp;

    // --- CSR build (rank-based, atomic-free scatter) ---
    hipMemsetAsync(ccnt, 0, (size_t)N * sizeof(int), stream);
    count_kernel<<<(E + 255) / 256, 256, 0, stream>>>(ec, ccnt, rank, E);
    int nb = (N + SCAN_B - 1) / SCAN_B;
    scan1<<<nb, SCAN_B, 0, stream>>>(ccnt, excl, bsums, N);
    scan2<<<1, SCAN_B, 0, stream>>>(bsums, nb);
    scan3<<<nb, SCAN_B, 0, stream>>>(excl, bsums, row_start, N, E);
    build_edges<<<(E + 255) / 256, 256, 0, stream>>>(
        er, ec, pos, row_start, rank, ebuf, E);

    build_tables<<<L_LAYERS * (TBL / T_PER), 128, 0, stream>>>(w1, b1, w2, b2, tabb);
    embed_kernel<<<(N * H_DIM + 255) / 256, 256, 0, stream>>>(z, emb, hb, N);
    prep_wt_all<<<19, 256, 0, stream>>>(c1w, c2w, iw, l1w, wbt);

    int gblocks = (N + 63) / 64;
    gemm_l0<<<gblocks, 256, 0, stream>>>(hb, wbt, xfb, N);

    for (int l = 0; l < L_LAYERS; ++l) {
        edge_agg<<<(N + 7) / 8, 256, 0, stream>>>(
            ebuf, row_start, xfb, tabb + (size_t)l * TBL * NF_DIM, aggb, N);
        int last = (l == L_LAYERS - 1);
        const unsigned short* B3 = last ? wbt + (size_t)18 * 16384
                                        : wbt + (size_t)(l + 1) * 16384;
        fused_layer<<<gblocks, 256, 0, stream>>>(
            aggb,
            wbt + (size_t)(6 + l) * 16384,  c2b + (size_t)l * H_DIM,
            wbt + (size_t)(12 + l) * 16384, ib + (size_t)l * H_DIM,
            B3, l1b, hb, xfb, sbuf, N, last);
    }

    hipMemsetAsync(mols, 0, (size_t)NM * H_DIM * sizeof(float) + NM * sizeof(int), stream);
    mol_reduce<<<(N + MR_ATOMS - 1) / MR_ATOMS, 128, 0, stream>>>(
        sbuf, a2c, c2m, mols, cnt_m, N);
    head_kernel<<<NM, 128, 0, stream>>>(mols, cnt_m, l2w, l2b, hw1, hb1, hw2, hb2, out);
}

// Round 12
// 618.943 us; speedup vs baseline: 11.6721x; 1.0338x over previous
//
#include <hip/hip_runtime.h>
#include <hip/hip_bf16.h>
#include <hip/hip_fp16.h>
#include <math.h>

#define H_DIM   128
#define NF_DIM  128
#define G_DIM   50
#define L_LAYERS 6
#define TBL     4096       // nearest-neighbor grid; h/2/sigma ~ 0.77% rel err
#define DMAX    12.8f
#define CUTOFF_C 10.0f
#define COEFF_C (-0.5f * 49.0f * 49.0f / 100.0f)
#define SCAN_B  256
#define T_PER   16
#define STG_STR 140

typedef __bf16 bf16x8 __attribute__((ext_vector_type(8)));
typedef float  f32x4  __attribute__((ext_vector_type(4)));

__device__ __forceinline__ float sspf(float x) {
    float e = __expf(-fabsf(x));
    return fmaxf(x, 0.0f) + __logf(1.0f + e) - 0.69314718055994530942f;
}

__device__ __forceinline__ unsigned short f2bf(float f) {
    unsigned int u = __float_as_uint(f);
    u = (u + 0x7fffu + ((u >> 16) & 1u)) >> 16;   // RNE
    return (unsigned short)u;
}

__device__ __forceinline__ float bf2f(unsigned short u) {
    return __uint_as_float(((unsigned int)u) << 16);
}

// XOR bank-swizzle for 16B A-frag chunks (c < 1024)
__device__ __forceinline__ int swz(int c) {
    return c ^ ((c >> 3) & 7) ^ ((c >> 8) & 3);
}

// ---------------------------------------------------------------- table phase 1
// syb[l][t][f] = bf16( ssp( g(d_t) @ W1[l] + b1[l] ) )   (K=50 VALU part only)
__global__ __launch_bounds__(128) void bt_sy(
        const float* __restrict__ w1, const float* __restrict__ b1,
        unsigned short* __restrict__ syb) {
    int l  = blockIdx.x / (TBL / T_PER);
    int t0 = (blockIdx.x % (TBL / T_PER)) * T_PER;
    int f  = threadIdx.x;  // 128
    __shared__ float sW1[G_DIM * 128];       // 25.6 KB
    __shared__ float gs[T_PER][G_DIM + 2];
    for (int i = f; i < G_DIM * 128; i += 128)
        sW1[i] = w1[(size_t)l * G_DIM * 128 + i];
    if (f < G_DIM) {
        float o = f * (CUTOFF_C / (G_DIM - 1));
#pragma unroll
        for (int u = 0; u < T_PER; ++u) {
            float dt = (t0 + u) * (DMAX / (TBL - 1));
            float dd = dt - o;
            gs[u][f] = __expf(COEFF_C * dd * dd);
        }
    }
    __syncthreads();
    float y[T_PER];
    float bb = b1[l * 128 + f];
#pragma unroll
    for (int u = 0; u < T_PER; ++u) y[u] = bb;
    for (int g = 0; g < G_DIM; ++g) {
        float wv = sW1[g * 128 + f];
#pragma unroll
        for (int u = 0; u < T_PER; ++u) y[u] += gs[u][g] * wv;
    }
#pragma unroll
    for (int u = 0; u < T_PER; ++u)
        syb[((size_t)l * TBL + t0 + u) * 128 + f] = f2bf(sspf(y[u]));
}

// ---------------------------------------------------------------- table phase 2
// tabb[l][t][:] = syb[l][t][:] @ W2[l] + b2[l]   (MFMA; 64 rows/block)
__global__ __launch_bounds__(256, 4) void bt_gemm(
        const unsigned short* __restrict__ syb, const unsigned short* __restrict__ w2sw,
        const float* __restrict__ b2, unsigned short* __restrict__ tabb) {
    int l  = blockIdx.x >> 6;           // 64 blocks per layer (TBL/64)
    int m0 = (blockIdx.x & 63) * 64;
    const unsigned short* A = syb + (size_t)l * TBL * 128;
    const unsigned short* Bsw = w2sw + (size_t)l * 16384;
    const float* bias = b2 + l * 128;
    unsigned short* outp = tabb + (size_t)l * TBL * 128;

    __shared__ __align__(16) unsigned short frag[8192];
    __shared__ __align__(16) unsigned short stg[64 * STG_STR];
    int tid = threadIdx.x;
    for (int i = tid; i < 1024; i += 256) {
        int ks = i >> 8, w_ = (i >> 6) & 3, ln_ = i & 63;
        int row = m0 + w_ * 16 + (ln_ & 15);
        int kb = ks * 32 + (ln_ >> 4) * 8;
        uint4 v = *(const uint4*)(A + (size_t)row * 128 + kb);
        *(uint4*)(frag + swz(i) * 8) = v;
    }
    __syncthreads();
    int w = tid >> 6, ln = tid & 63;
    int quad = ln >> 4, l15 = ln & 15;
    f32x4 acc[8] = {};
#pragma unroll
    for (int ks = 0; ks < 4; ++ks) {
        bf16x8 af = *(const bf16x8*)(frag + swz((ks * 4 + w) * 64 + ln) * 8);
#pragma unroll
        for (int j = 0; j < 8; ++j) {
            bf16x8 bf = *(const bf16x8*)(Bsw + (((ks * 8 + j) * 64) + ln) * 8);
            acc[j] = __builtin_amdgcn_mfma_f32_16x16x32_bf16(af, bf, acc[j], 0, 0, 0);
        }
    }
#pragma unroll
    for (int j = 0; j < 8; ++j) {
        int col = j * 16 + l15;
        float bv = bias[col];
#pragma unroll
        for (int r = 0; r < 4; ++r)
            stg[(w * 16 + quad * 4 + r) * STG_STR + col] = f2bf(acc[j][r] + bv);
    }
    __syncthreads();
    for (int i = tid; i < 2048; i += 256) {
        int row = i >> 5, c4 = (i & 31) * 4;
        ushort4 s4 = *(const ushort4*)(stg + row * STG_STR + c4);
        *(uint2*)(outp + (size_t)(m0 + row) * 128 + c4) = *(const uint2*)&s4;
    }
}

// ---------------------------------------------------------------- embedding (bf16 h)
__global__ __launch_bounds__(256) void embed_kernel(
        const int* __restrict__ z, const float* __restrict__ emb,
        unsigned short* __restrict__ hb, int N) {
    int idx = blockIdx.x * blockDim.x + threadIdx.x;
    if (idx >= N * H_DIM) return;
    int n = idx >> 7, f = idx & 127;
    hb[idx] = f2bf(emb[z[n] * H_DIM + f]);
}

// ---------------------------------------------------------------- weight prep (25)
// 0..5 c1w, 6..11 c2w, 12..17 iw, 18 l1w, 19..24 mlp_w2 (for bt_gemm)
__global__ __launch_bounds__(256) void prep_wt_all(
        const float* __restrict__ c1w, const float* __restrict__ c2w,
        const float* __restrict__ iw, const float* __restrict__ l1w,
        const float* __restrict__ w2, unsigned short* __restrict__ Bsw) {
    int m = blockIdx.x;   // 0..24
    const float* src = (m < 6)  ? c1w + (size_t)m * 16384
                     : (m < 12) ? c2w + (size_t)(m - 6) * 16384
                     : (m < 18) ? iw  + (size_t)(m - 12) * 16384
                     : (m == 18) ? l1w
                                 : w2 + (size_t)(m - 19) * 16384;
    unsigned short* dst = Bsw + (size_t)m * 16384;
    for (int i = threadIdx.x; i < 16384; i += 256) {
        int jj = i & 7, lane = (i >> 3) & 63, j = (i >> 9) & 7, ks = i >> 12;
        int n = j * 16 + (lane & 15);
        int k = ks * 32 + ((lane >> 4) & 3) * 8 + jj;
        dst[i] = f2bf(src[k * 128 + n]);
    }
}

// ---------------------------------------------------------------- CSR build
__global__ __launch_bounds__(256) void count_kernel(
        const int* __restrict__ ec, int* __restrict__ cnt,
        int* __restrict__ rank, int E) {
    int e = blockIdx.x * blockDim.x + threadIdx.x;
    if (e < E) rank[e] = atomicAdd(&cnt[ec[e]], 1);
}

__global__ __launch_bounds__(SCAN_B) void scan1(
        const int* __restrict__ cnt, int* __restrict__ excl,
        int* __restrict__ bsums, int N) {
    __shared__ int s[SCAN_B];
    int i = blockIdx.x * SCAN_B + threadIdx.x;
    int v = (i < N) ? cnt[i] : 0;
    s[threadIdx.x] = v;
    __syncthreads();
    for (int off = 1; off < SCAN_B; off <<= 1) {
        int t = (threadIdx.x >= off) ? s[threadIdx.x - off] : 0;
        __syncthreads();
        s[threadIdx.x] += t;
        __syncthreads();
    }
    if (i < N) excl[i] = s[threadIdx.x] - v;
    if (threadIdx.x == SCAN_B - 1) bsums[blockIdx.x] = s[SCAN_B - 1];
}

__global__ __launch_bounds__(SCAN_B) void scan2(int* __restrict__ bsums, int nb) {
    __shared__ int s[SCAN_B];
    int v = (threadIdx.x < nb) ? bsums[threadIdx.x] : 0;
    s[threadIdx.x] = v;
    __syncthreads();
    for (int off = 1; off < SCAN_B; off <<= 1) {
        int t = (threadIdx.x >= off) ? s[threadIdx.x - off] : 0;
        __syncthreads();
        s[threadIdx.x] += t;
        __syncthreads();
    }
    if (threadIdx.x < nb) bsums[threadIdx.x] = s[threadIdx.x] - v;
}

__global__ __launch_bounds__(SCAN_B) void scan3(
        const int* __restrict__ excl, const int* __restrict__ bsums,
        int* __restrict__ row_start, int N, int E) {
    int i = blockIdx.x * SCAN_B + threadIdx.x;
    if (i < N) row_start[i] = excl[i] + bsums[blockIdx.x];
    if (i == 0) row_start[N] = E;
}

// 8-byte edge record {row|(i0<<17), fp32 C}; slot = row_start[col]+rank[e]
__global__ __launch_bounds__(256) void build_edges(
        const int* __restrict__ er, const int* __restrict__ ec,
        const float* __restrict__ pos, const int* __restrict__ row_start,
        const int* __restrict__ rank, uint2* __restrict__ ebuf, int E) {
    int e = blockIdx.x * blockDim.x + threadIdx.x;
    if (e >= E) return;
    int r = er[e], c = ec[e];
    float dx = pos[r * 3 + 0] - pos[c * 3 + 0];
    float dy = pos[r * 3 + 1] - pos[c * 3 + 1];
    float dz = pos[r * 3 + 2] - pos[c * 3 + 2];
    float d = sqrtf(dx * dx + dy * dy + dz * dz);
    float C = 0.5f * (cosf(d * (3.14159265358979323846f / CUTOFF_C)) + 1.0f);
    float t = fminf(d, DMAX) * ((TBL - 1) / DMAX);
    int i0 = (int)(t + 0.5f);          // nearest grid point
    if (i0 > TBL - 1) i0 = TBL - 1;
    ebuf[row_start[c] + rank[e]] =
        make_uint2((unsigned)r | ((unsigned)i0 << 17), __float_as_uint(C));
}

// ---------------------------------------------------------------- edge gather
__device__ __forceinline__ void edge_acc(
        unsigned ex, unsigned ey, const unsigned short* __restrict__ tabb,
        const unsigned short* __restrict__ xfb, int f4, float4& acc) {
    int r = ex & 0x1ffff, i0 = ex >> 17;
    float C = __uint_as_float(ey);
    const ushort4 tw = *(const ushort4*)(tabb + (size_t)i0 * 128 + f4);
    const ushort4 xu = *(const ushort4*)(xfb + (size_t)r * 128 + f4);
    acc.x = fmaf(bf2f(xu.x) * bf2f(tw.x), C, acc.x);
    acc.y = fmaf(bf2f(xu.y) * bf2f(tw.y), C, acc.y);
    acc.z = fmaf(bf2f(xu.z) * bf2f(tw.z), C, acc.z);
    acc.w = fmaf(bf2f(xu.w) * bf2f(tw.w), C, acc.w);
}

// 32 lanes/atom, 4 edges in flight (two uint4 record-pair loads, 4 accums)
__global__ __launch_bounds__(256) void edge_agg(
        const uint2* __restrict__ ebuf, const int* __restrict__ row_start,
        const unsigned short* __restrict__ xfb, const unsigned short* __restrict__ tabb,
        unsigned short* __restrict__ aggb, int N) {
    int tid = threadIdx.x;
    int atom = blockIdx.x * 8 + (tid >> 5);
    if (atom >= N) return;
    int f4 = (tid & 31) * 4;
    float4 a0 = make_float4(0.f, 0.f, 0.f, 0.f);
    float4 a1 = make_float4(0.f, 0.f, 0.f, 0.f);
    float4 a2 = make_float4(0.f, 0.f, 0.f, 0.f);
    float4 a3 = make_float4(0.f, 0.f, 0.f, 0.f);
    int j0 = row_start[atom], j1 = row_start[atom + 1];
    int j = j0;
    if (j < j1 && (j & 1)) {
        uint2 ed = ebuf[j];
        edge_acc(ed.x, ed.y, tabb, xfb, f4, a0);
        ++j;
    }
    for (; j + 3 < j1; j += 4) {
        uint4 e0 = *(const uint4*)(ebuf + j);
        uint4 e1 = *(const uint4*)(ebuf + j + 2);
        edge_acc(e0.x, e0.y, tabb, xfb, f4, a0);
        edge_acc(e0.z, e0.w, tabb, xfb, f4, a1);
        edge_acc(e1.x, e1.y, tabb, xfb, f4, a2);
        edge_acc(e1.z, e1.w, tabb, xfb, f4, a3);
    }
    if (j + 1 < j1) {
        uint4 e0 = *(const uint4*)(ebuf + j);
        edge_acc(e0.x, e0.y, tabb, xfb, f4, a0);
        edge_acc(e0.z, e0.w, tabb, xfb, f4, a1);
        j += 2;
    }
    if (j < j1) {
        uint2 ed = ebuf[j];
        edge_acc(ed.x, ed.y, tabb, xfb, f4, a0);
    }
    a0.x += a1.x + a2.x + a3.x;
    a0.y += a1.y + a2.y + a3.y;
    a0.z += a1.z + a2.z + a3.z;
    a0.w += a1.w + a2.w + a3.w;
    unsigned short o[4] = {f2bf(a0.x), f2bf(a0.y), f2bf(a0.z), f2bf(a0.w)};
    *(uint2*)(aggb + (size_t)atom * 128 + f4) = *(const uint2*)o;
}

// ---------------------------------------------------------------- layer-0 GEMM
__global__ __launch_bounds__(256, 4) void gemm_l0(
        const unsigned short* __restrict__ hb, const unsigned short* __restrict__ Bsw,
        unsigned short* __restrict__ xfb, int M) {
    __shared__ __align__(16) unsigned short frag[8192];
    __shared__ __align__(16) unsigned short stg[64 * STG_STR];
    int tid = threadIdx.x;
    int m0 = blockIdx.x * 64;
    for (int i = tid; i < 1024; i += 256) {
        int ks = i >> 8, w_ = (i >> 6) & 3, ln_ = i & 63;
        int row = m0 + w_ * 16 + (ln_ & 15);
        int kb = ks * 32 + (ln_ >> 4) * 8;
        uint4 v = make_uint4(0, 0, 0, 0);
        if (row < M) v = *(const uint4*)(hb + (size_t)row * 128 + kb);
        *(uint4*)(frag + swz(i) * 8) = v;
    }
    __syncthreads();
    int w = tid >> 6, ln = tid & 63;
    int quad = ln >> 4, l15 = ln & 15;
    f32x4 acc[8] = {};
#pragma unroll
    for (int ks = 0; ks < 4; ++ks) {
        bf16x8 af = *(const bf16x8*)(frag + swz((ks * 4 + w) * 64 + ln) * 8);
#pragma unroll
        for (int j = 0; j < 8; ++j) {
            bf16x8 bf = *(const bf16x8*)(Bsw + (((ks * 8 + j) * 64) + ln) * 8);
            acc[j] = __builtin_amdgcn_mfma_f32_16x16x32_bf16(af, bf, acc[j], 0, 0, 0);
        }
    }
#pragma unroll
    for (int j = 0; j < 8; ++j) {
        int col = j * 16 + l15;
#pragma unroll
        for (int r = 0; r < 4; ++r)
            stg[(w * 16 + quad * 4 + r) * STG_STR + col] = f2bf(acc[j][r]);
    }
    __syncthreads();
    for (int i = tid; i < 2048; i += 256) {
        int row = i >> 5, c4 = (i & 31) * 4;
        int grow = m0 + row;
        if (grow >= M) continue;
        ushort4 s4 = *(const ushort4*)(stg + row * STG_STR + c4);
        *(uint2*)(xfb + (size_t)grow * 128 + c4) = *(const uint2*)&s4;
    }
}

// ---------------------------------------------------------------- fused layer
__global__ __launch_bounds__(256, 4) void fused_layer(
        const unsigned short* __restrict__ aggb,
        const unsigned short* __restrict__ B1sw, const float* __restrict__ b1v,
        const unsigned short* __restrict__ B2sw, const float* __restrict__ b2v,
        const unsigned short* __restrict__ B3sw, const float* __restrict__ b3v,
        unsigned short* __restrict__ hb, unsigned short* __restrict__ xfb_next,
        float* __restrict__ s_out, int M, int last) {
    __shared__ __align__(16) unsigned short frag[8192];         // 16 KB
    __shared__ __align__(16) unsigned short stg[64 * STG_STR];  // 17.5 KB
    int tid = threadIdx.x;
    int m0 = blockIdx.x * 64;

    for (int i = tid; i < 1024; i += 256) {
        int ks = i >> 8, w_ = (i >> 6) & 3, ln_ = i & 63;
        int row = m0 + w_ * 16 + (ln_ & 15);
        int kb = ks * 32 + (ln_ >> 4) * 8;
        uint4 v = make_uint4(0, 0, 0, 0);
        if (row < M) v = *(const uint4*)(aggb + (size_t)row * 128 + kb);
        *(uint4*)(frag + swz(i) * 8) = v;
    }
    __syncthreads();

    int w = tid >> 6, ln = tid & 63;
    int quad = ln >> 4, l15 = ln & 15;

    f32x4 acc[8] = {};
#pragma unroll
    for (int ks = 0; ks < 4; ++ks) {
        bf16x8 af = *(const bf16x8*)(frag + swz((ks * 4 + w) * 64 + ln) * 8);
#pragma unroll
        for (int j = 0; j < 8; ++j) {
            bf16x8 bf = *(const bf16x8*)(B1sw + (((ks * 8 + j) * 64) + ln) * 8);
            acc[j] = __builtin_amdgcn_mfma_f32_16x16x32_bf16(af, bf, acc[j], 0, 0, 0);
        }
    }

#pragma unroll
    for (int j = 0; j < 8; ++j) {
        int col = j * 16 + l15;
        float bv = b1v[col];
        int ks2 = j >> 1;
        int quad2 = (col >> 3) & 3;
        int jj = l15 & 7;
        int cbase = (ks2 * 4 + w) * 64 + quad2 * 16 + quad * 4;
#pragma unroll
        for (int r = 0; r < 4; ++r) {
            float s = sspf(acc[j][r] + bv);
            frag[swz(cbase + r) * 8 + jj] = f2bf(s);
        }
    }

    f32x4 acc2[8] = {};
#pragma unroll
    for (int ks = 0; ks < 4; ++ks) {
        bf16x8 af = *(const bf16x8*)(frag + swz((ks * 4 + w) * 64 + ln) * 8);
#pragma unroll
        for (int j = 0; j < 8; ++j) {
            bf16x8 bf = *(const bf16x8*)(B2sw + (((ks * 8 + j) * 64) + ln) * 8);
            acc2[j] = __builtin_amdgcn_mfma_f32_16x16x32_bf16(af, bf, acc2[j], 0, 0, 0);
        }
    }

#pragma unroll
    for (int j = 0; j < 8; ++j) {
        int col = j * 16 + l15;
        float bv = b2v[col];
#pragma unroll
        for (int r = 0; r < 4; ++r)
            stg[(w * 16 + quad * 4 + r) * STG_STR + col] = f2bf(acc2[j][r] + bv);
    }
    __syncthreads();

    for (int i = tid; i < 2048; i += 256) {
        int row = i >> 5, c4 = (i & 31) * 4;
        int grow = m0 + row;
        ushort4 xv = *(const ushort4*)(stg + row * STG_STR + c4);
        unsigned short t4[4];
        if (grow < M) {
            unsigned short* hp = hb + (size_t)grow * 128 + c4;
            ushort4 hv = *(const ushort4*)hp;
            t4[0] = f2bf(bf2f(hv.x) + bf2f(xv.x));
            t4[1] = f2bf(bf2f(hv.y) + bf2f(xv.y));
            t4[2] = f2bf(bf2f(hv.z) + bf2f(xv.z));
            t4[3] = f2bf(bf2f(hv.w) + bf2f(xv.w));
            *(uint2*)hp = *(const uint2*)t4;
        } else {
            t4[0] = t4[1] = t4[2] = t4[3] = 0;
        }
        int w_ = row >> 4, l15_ = row & 15;
        int ks = c4 >> 5, q_ = (c4 >> 3) & 3, jj = c4 & 7;
        int c = (ks * 4 + w_) * 64 + q_ * 16 + l15_;
        *(uint2*)(frag + swz(c) * 8 + jj) = *(const uint2*)t4;
    }
    __syncthreads();

    f32x4 acc3[8] = {};
#pragma unroll
    for (int ks = 0; ks < 4; ++ks) {
        bf16x8 af = *(const bf16x8*)(frag + swz((ks * 4 + w) * 64 + ln) * 8);
#pragma unroll
        for (int j = 0; j < 8; ++j) {
            bf16x8 bf = *(const bf16x8*)(B3sw + (((ks * 8 + j) * 64) + ln) * 8);
            acc3[j] = __builtin_amdgcn_mfma_f32_16x16x32_bf16(af, bf, acc3[j], 0, 0, 0);
        }
    }

#pragma unroll
    for (int j = 0; j < 8; ++j) {
        int col = j * 16 + l15;
        float bv = last ? b3v[col] : 0.f;
#pragma unroll
        for (int r = 0; r < 4; ++r) {
            float v = acc3[j][r] + bv;
            if (last) v = sspf(v);
            stg[(w * 16 + quad * 4 + r) * STG_STR + col] = f2bf(v);
        }
    }
    __syncthreads();

    for (int i = tid; i < 2048; i += 256) {
        int row = i >> 5, c4 = (i & 31) * 4;
        int grow = m0 + row;
        if (grow >= M) continue;
        ushort4 s4 = *(const ushort4*)(stg + row * STG_STR + c4);
        if (last) {
            float4 v;
            v.x = bf2f(s4.x); v.y = bf2f(s4.y); v.z = bf2f(s4.z); v.w = bf2f(s4.w);
            *(float4*)(s_out + (size_t)grow * 128 + c4) = v;
        } else {
            *(uint2*)(xfb_next + (size_t)grow * 128 + c4) = *(const uint2*)&s4;
        }
    }
}

// ---------------------------------------------------------------- atom -> mol sum
#define MR_ATOMS 32
__global__ __launch_bounds__(128) void mol_reduce(
        const float* __restrict__ s, const int* __restrict__ a2c,
        const int* __restrict__ c2m, float* __restrict__ mols,
        int* __restrict__ cnt, int N) {
    int f = threadIdx.x;
    int a0 = blockIdx.x * MR_ATOMS;
    int a1 = min(a0 + MR_ATOMS, N);
    float sum = 0.f;
    int cur = -1, run = 0;
    for (int a = a0; a < a1; ++a) {
        int m = c2m[a2c[a]];
        if (m != cur) {
            if (cur >= 0) {
                unsafeAtomicAdd(&mols[(size_t)cur * H_DIM + f], sum);
                if (f == 0) atomicAdd(&cnt[cur], run);
            }
            cur = m; sum = 0.f; run = 0;
        }
        sum += s[(size_t)a * H_DIM + f];
        ++run;
    }
    if (cur >= 0) {
        unsafeAtomicAdd(&mols[(size_t)cur * H_DIM + f], sum);
        if (f == 0) atomicAdd(&cnt[cur], run);
    }
}

// ---------------------------------------------------------------- head
__global__ __launch_bounds__(128) void head_kernel(
        const float* __restrict__ mols, const int* __restrict__ cnt,
        const float* __restrict__ l2w, const float* __restrict__ l2b,
        const float* __restrict__ hw1, const float* __restrict__ hb1,
        const float* __restrict__ hw2, const float* __restrict__ hb2,
        float* __restrict__ out) {
    int m = blockIdx.x, f = threadIdx.x;
    __shared__ float me[H_DIM];
    __shared__ float u[H_DIM / 2];
    const float* ms = mols + (size_t)m * H_DIM;
    float acc = l2b[f] * (float)cnt[m];
#pragma unroll 16
    for (int k = 0; k < H_DIM; ++k) acc += ms[k] * l2w[k * H_DIM + f];
    me[f] = acc;
    __syncthreads();
    if (f < 64) {
        float a2 = hb1[f];
#pragma unroll 16
        for (int k = 0; k < H_DIM; ++k) a2 += me[k] * hw1[k * 64 + f];
        u[f] = sspf(a2);
    }
    __syncthreads();
    if (f == 0) {
        float o = hb2[0];
#pragma unroll 16
        for (int j = 0; j < 64; ++j) o += u[j] * hw2[j];
        out[m] = o;
    }
}

// ---------------------------------------------------------------- launch
extern "C" void kernel_launch(void* const* d_in, const int* in_sizes, int n_in,
                              void* d_out, int out_size, void* d_ws, size_t ws_size,
                              hipStream_t stream) {
    const int*   z   = (const int*)d_in[0];
    const float* pos = (const float*)d_in[1];
    const int*   er  = (const int*)d_in[2];
    const int*   ec  = (const int*)d_in[3];
    const int*   a2c = (const int*)d_in[4];
    const int*   c2m = (const int*)d_in[5];
    const float* emb = (const float*)d_in[6];
    const float* w1  = (const float*)d_in[7];
    const float* b1  = (const float*)d_in[8];
    const float* w2  = (const float*)d_in[9];
    const float* b2  = (const float*)d_in[10];
    const float* c1w = (const float*)d_in[11];
    const float* c2w = (const float*)d_in[12];
    const float* c2b = (const float*)d_in[13];
    const float* iw  = (const float*)d_in[14];
    const float* ib  = (const float*)d_in[15];
    const float* l1w = (const float*)d_in[16];
    const float* l1b = (const float*)d_in[17];
    const float* l2w = (const float*)d_in[18];
    const float* l2b = (const float*)d_in[19];
    const float* hw1 = (const float*)d_in[20];
    const float* hb1 = (const float*)d_in[21];
    const float* hw2 = (const float*)d_in[22];
    const float* hb2 = (const float*)d_in[23];

    const int N  = in_sizes[0];
    const int E  = in_sizes[2];
    const int NM = out_size;
    float* out = (float*)d_out;

    // workspace layout (~73 MB)
    char* wsp = (char*)d_ws;
    uint2* ebuf = (uint2*)wsp;            wsp += (size_t)E * 8;
    unsigned short* tabb = (unsigned short*)wsp;  wsp += (size_t)L_LAYERS * TBL * NF_DIM * 2;
    unsigned short* syb  = (unsigned short*)wsp;  wsp += (size_t)L_LAYERS * TBL * NF_DIM * 2;
    unsigned short* wbt = (unsigned short*)wsp;  wsp += (size_t)25 * 16384 * 2;
    unsigned short* hb  = (unsigned short*)wsp;  wsp += (size_t)N * H_DIM * 2;
    unsigned short* xfb = (unsigned short*)wsp;  wsp += (size_t)N * H_DIM * 2;
    unsigned short* aggb = (unsigned short*)wsp; wsp += (size_t)N * H_DIM * 2;
    float* sbuf = (float*)wsp;            wsp += (size_t)N * H_DIM * 4;
    float* mols = (float*)wsp;            wsp += (size_t)NM * H_DIM * 4;
    int*   cnt_m = (int*)wsp;             wsp += (size_t)NM * 4;
    int*   ccnt  = (int*)wsp;             wsp += (size_t)N * 4;
    int*   row_start = (int*)wsp;         wsp += (size_t)(N + 1) * 4;
    int*   rank  = (int*)wsp;             wsp += (size_t)E * 4;
    int*   bsums = (int*)wsp;             wsp += 256 * 4;
    int*   excl  = (int*)wsp;

    // --- CSR build (rank-based, atomic-free scatter) ---
    hipMemsetAsync(ccnt, 0, (size_t)N * sizeof(int), stream);
    count_kernel<<<(E + 255) / 256, 256, 0, stream>>>(ec, ccnt, rank, E);
    int nb = (N + SCAN_B - 1) / SCAN_B;
    scan1<<<nb, SCAN_B, 0, stream>>>(ccnt, excl, bsums, N);
    scan2<<<1, SCAN_B, 0, stream>>>(bsums, nb);
    scan3<<<nb, SCAN_B, 0, stream>>>(excl, bsums, row_start, N, E);
    build_edges<<<(E + 255) / 256, 256, 0, stream>>>(
        er, ec, pos, row_start, rank, ebuf, E);

    // --- filter tables: VALU phase (K=50) then MFMA phase (K=128) ---
    bt_sy<<<L_LAYERS * (TBL / T_PER), 128, 0, stream>>>(w1, b1, syb);
    embed_kernel<<<(N * H_DIM + 255) / 256, 256, 0, stream>>>(z, emb, hb, N);
    prep_wt_all<<<25, 256, 0, stream>>>(c1w, c2w, iw, l1w, w2, wbt);
    bt_gemm<<<L_LAYERS * (TBL / 64), 256, 0, stream>>>(
        syb, wbt + (size_t)19 * 16384, b2, tabb);

    int gblocks = (N + 63) / 64;
    gemm_l0<<<gblocks, 256, 0, stream>>>(hb, wbt, xfb, N);

    for (int l = 0; l < L_LAYERS; ++l) {
        edge_agg<<<(N + 7) / 8, 256, 0, stream>>>(
            ebuf, row_start, xfb, tabb + (size_t)l * TBL * NF_DIM, aggb, N);
        int last = (l == L_LAYERS - 1);
        const unsigned short* B3 = last ? wbt + (size_t)18 * 16384
                                        : wbt + (size_t)(l + 1) * 16384;
        fused_layer<<<gblocks, 256, 0, stream>>>(
            aggb,
            wbt + (size_t)(6 + l) * 16384,  c2b + (size_t)l * H_DIM,
            wbt + (size_t)(12 + l) * 16384, ib + (size_t)l * H_DIM,
            B3, l1b, hb, xfb, sbuf, N, last);
    }

    hipMemsetAsync(mols, 0, (size_t)NM * H_DIM * sizeof(float) + NM * sizeof(int), stream);
    mol_reduce<<<(N + MR_ATOMS - 1) / MR_ATOMS, 128, 0, stream>>>(
        sbuf, a2c, c2m, mols, cnt_m, N);
    head_kernel<<<NM, 128, 0, stream>>>(mols, cnt_m, l2w, l2b, hw1, hb1, hw2, hb2, out);
}